// Round 6
// baseline (395.575 us; speedup 1.0000x reference)
//
#include <hip/hip_runtime.h>
#include <hip/hip_bf16.h>
#include <cstdint>

typedef __hip_bfloat16 bf16;
typedef __attribute__((ext_vector_type(8))) __bf16 bfrag;   // MFMA A/B operand (4 VGPRs)
typedef __attribute__((ext_vector_type(4))) float f32x4;    // MFMA C/D operand

#define B_    2
#define S_    1024
#define D_    768
#define H_    12
#define E_    8
#define DH_   64
#define DFF_  2048
#define CAP_  320            // ceil(1.25 * 2048 / 8)
#define CAPP_ 384            // CAP padded to 128-multiple for MFMA tiles
#define NTOK  (B_*S_)        // 2048
#define NTH   (NTOK*H_)      // 24576
#define QKLD  1536           // fused q|k row stride
#define NHE   (H_*E_)        // 96 (h,e) bins

// ---------------- async global->LDS 16B stage (per-lane global addr, lane-linear LDS) ----------------
__device__ __forceinline__ void stage16(const bf16* g, bf16* ldsLane){
#if __has_builtin(__builtin_amdgcn_global_load_lds)
  __builtin_amdgcn_global_load_lds((const __attribute__((address_space(1))) unsigned int*)g,
                                   (__attribute__((address_space(3))) unsigned int*)ldsLane, 16, 0, 0);
#else
  *(bfrag*)ldsLane = *(const bfrag*)g;
#endif
}

// ---------------- ALL weight prep: 64n x 128k tiles, XOR-swizzled LDS, 256B write runs ----------------
// job table by flat blockIdx.x:
//   [0,72)      Wq  768x768    -> WcatB rows 0..767     (12nx x 6ky)
//   [72,144)    Wk  768x768    -> WcatB rows 768..1535
//   [144,1680)  W1  e,768x2048 -> WT1[e] (2048x768)     (32nx x 6ky per e)
//   [1680,3216) W2  e,2048x768 -> WT2[e] (768x2048)     (12nx x 16ky per e)
//   [3216,3252) Wr  768x96     -> WrT fp32 (64k x 32n tiles)
// LDS t[128][64] flat (32 KB), logical (row,col) stored at col' = col ^ (((row>>3)&15)*4).
// Verified <=2-way banking on both phases; write phase: 16 lanes = one 256B output row.
__global__ __launch_bounds__(256)
void transp_all(const float* __restrict__ Wq, const float* __restrict__ Wk,
                const float* __restrict__ Wr, const float* __restrict__ W1,
                const float* __restrict__ W2,
                bf16* __restrict__ WcatB, float* __restrict__ WrT,
                bf16* __restrict__ WT1, bf16* __restrict__ WT2)
{
  __shared__ float t[128][64];
  int bid = blockIdx.x, tid = threadIdx.x;
  if (bid < 3216){
    const float* src; int N, K, bx, by; bf16* dst;
    if (bid < 72)      {                src = Wq; N=768;  K=768;  bx=bid%12; by=bid/12; dst=WcatB; }
    else if (bid <144) { int r=bid-72;  src = Wk; N=768;  K=768;  bx=r%12;   by=r/12;   dst=WcatB+(long)768*768; }
    else if (bid<1680) { int r=bid-144; int e=r/192; r-=e*192;
                         src = W1+(long)e*768*2048; N=2048; K=768;  bx=r%32; by=r/32;   dst=WT1+(long)e*2048*768; }
    else               { int r=bid-1680; int e=r/192; r-=e*192;
                         src = W2+(long)e*2048*768; N=768;  K=2048; bx=r%12; by=r/12;   dst=WT2+(long)e*768*2048; }
    int n0 = bx*64, k0 = by*128;
    int chunk = tid & 15, rgrp = tid >> 4;
#pragma unroll
    for (int rr=0; rr<8; rr++){
      int row = rr*16 + rgrp;
      float4 v = *(const float4*)(src + (long)(k0+row)*N + n0 + chunk*4);
      *(float4*)&t[row][((chunk ^ (row>>3)) & 15)*4] = v;
    }
    __syncthreads();
#pragma unroll
    for (int it=0; it<4; it++){
      int slot = it*256 + tid;
      int n = slot >> 4, kc = slot & 15;      // 16 lanes (kc 0..15) cover one full 128-bf16 output row
      union { bfrag f; bf16 h[8]; } o;
#pragma unroll
      for (int i=0;i<8;i++){
        int row = kc*8 + i;                   // (row>>3)&15 == kc
        o.h[i] = __float2bfloat16(t[row][n ^ (kc*4)]);
      }
      *(bfrag*)(dst + (long)(n0+n)*K + k0 + kc*8) = o.f;
    }
  } else {
    // Wr: 64k x 32n fp32 tiles (tiny: 36 blocks)
    int r = bid - 3216;
    int n0 = (r % 3)*32, k0 = (r / 3)*64;
    int chunk = tid & 7, row2 = tid >> 3;
#pragma unroll
    for (int rr=0; rr<2; rr++){
      int row = rr*32 + row2;
      float4 v = *(const float4*)(Wr + (long)(k0+row)*96 + n0 + chunk*4);
      *(float4*)&t[row][chunk*4] = v;
    }
    __syncthreads();
    int chunkw = tid & 15, ng = tid >> 4;
#pragma unroll
    for (int rr=0; rr<2; rr++){
      int n = rr*16 + ng;
      float4 o;
      o.x = t[chunkw*4+0][n]; o.y = t[chunkw*4+1][n];
      o.z = t[chunkw*4+2][n]; o.w = t[chunkw*4+3][n];
      *(float4*)(WrT + (long)(n0+n)*768 + k0 + chunkw*4) = o;
    }
  }
}

// ---------------- MFMA GEMM, 128x64 tile, xor-swizzled LDS, XCD-chunked swizzle, split-K, 2-phase dbuf ----------------
__global__ __launch_bounds__(256)
void gemm_bn64(const bf16* __restrict__ A, const bf16* __restrict__ Bt,
               void* __restrict__ C, void* __restrict__ C2,
               int M, int N, int K, long sA, long sB, long sC, int relu, int outBf, int kSplit)
{
  int nwg = gridDim.x*gridDim.y*gridDim.z;
  int bid = blockIdx.x + gridDim.x*(blockIdx.y + gridDim.y*blockIdx.z);
  int nid = (bid & 7)*(nwg >> 3) + (bid >> 3);        // bijective: nwg % 8 == 0 at all call sites
  int bx = nid % gridDim.x;
  int t1 = nid / gridDim.x;
  int by = t1 % gridDim.y;
  int bz = t1 / gridDim.y;
  int e  = bz / kSplit, kc = bz - e*kSplit;
  A  += (long)e*sA;
  Bt += (long)e*sB;
  int kLen = K / kSplit, kBase = kc*kLen;
  int m0 = by*128, n0 = bx*64;
  __shared__ bf16 As[2][128*32];   // 2 x 8 KB
  __shared__ bf16 Bs[2][64*32];    // 2 x 4 KB
  int tid = threadIdx.x;
  int w = tid >> 6, lane = tid & 63;
  int quad = lane >> 4, l16 = lane & 15;
  int wm = w*32;
  f32x4 acc[2][4] = {};
  int srow = (lane >> 2);          // row within 16-row chunk
  int gsw  = ((lane & 3) ^ (srow & 3))*8;   // swizzled col group (8 bf16)
  const bf16* aBase = A + (long)m0*K;
  const bf16* bBase = Bt + (long)n0*K;
  int xr = (l16 & 3);              // read-side swizzle key (row&3 == l16&3)
  int nIt = kLen >> 5;
  {
    int k0 = kBase;
#pragma unroll
    for (int j=0;j<2;j++){
      int c = w*2 + j, row = c*16 + srow;
      stage16(aBase + (long)row*K + k0 + gsw, As[0] + c*512 + lane*8);
    }
    int rowb = w*16 + srow;
    stage16(bBase + (long)rowb*K + k0 + gsw, Bs[0] + w*512 + lane*8);
  }
  int cur = 0;
  for (int it=0; it<nIt; ++it){
    __syncthreads();               // drains stage of buf[cur]
    if (it+1 < nIt){               // prefetch next k-step into buf[cur^1]
      int k0 = kBase + (it+1)*32;
      int nb = cur^1;
#pragma unroll
      for (int j=0;j<2;j++){
        int c = w*2 + j, row = c*16 + srow;
        stage16(aBase + (long)row*K + k0 + gsw, As[nb] + c*512 + lane*8);
      }
      int rowb = w*16 + srow;
      stage16(bBase + (long)rowb*K + k0 + gsw, Bs[nb] + w*512 + lane*8);
    }
    const bf16* Ac = As[cur];
    const bf16* Bc = Bs[cur];
    bfrag af[2], bfv[4];
#pragma unroll
    for (int t=0;t<2;t++) af[t]  = *(const bfrag*)(Ac + (wm + t*16 + l16)*32 + ((quad ^ xr)*8));
#pragma unroll
    for (int t=0;t<4;t++) bfv[t] = *(const bfrag*)(Bc + (t*16 + l16)*32 + ((quad ^ xr)*8));
#pragma unroll
    for (int ti=0;ti<2;ti++)
#pragma unroll
      for (int tj=0;tj<4;tj++)
        acc[ti][tj] = __builtin_amdgcn_mfma_f32_16x16x32_bf16(af[ti], bfv[tj], acc[ti][tj], 0, 0, 0);
    cur ^= 1;
  }
  long zoff = (long)e*sC;
  void* Cp = kc ? C2 : C;
  if (outBf){
    bf16* Cb = (bf16*)Cp + zoff;
#pragma unroll
    for (int ti=0;ti<2;ti++)
#pragma unroll
      for (int tj=0;tj<4;tj++)
#pragma unroll
        for (int r=0;r<4;r++){
          int row = m0 + wm + ti*16 + quad*4 + r;
          int col = n0 + tj*16 + l16;
          float v = acc[ti][tj][r];
          if (relu) v = fmaxf(v, 0.f);
          Cb[(long)row*N + col] = __float2bfloat16(v);
        }
  } else {
    float* Cf = (float*)Cp + zoff;
#pragma unroll
    for (int ti=0;ti<2;ti++)
#pragma unroll
      for (int tj=0;tj<4;tj++)
#pragma unroll
        for (int r=0;r<4;r++){
          int row = m0 + wm + ti*16 + quad*4 + r;
          int col = n0 + tj*16 + l16;
          float v = acc[ti][tj][r];
          if (relu) v = fmaxf(v, 0.f);
          Cf[(long)row*N + col] = v;
        }
  }
}

// ---------------- W1 GEMM with FUSED gather: A reg-staged from fp32 ln2 via token list ----------------
// M=CAPP per expert, N=DFF, K=768. Same LDS layout as gemm_bn64 (pre-swizzled source, linear LDS).
// Numerically identical to gather->Xg path: bf16 round AFTER scaling by w. Dead rows (>=cnt): w=0 -> zeros.
__global__ __launch_bounds__(256)
void gemm_ffn1(const float* __restrict__ ln2, const bf16* __restrict__ Bt, bf16* __restrict__ C,
               const int* __restrict__ lTok, const float* __restrict__ lW, const int* __restrict__ gCnt)
{
  int nwg = gridDim.x*gridDim.y*gridDim.z;   // 32*3*8 = 768
  int bid = blockIdx.x + gridDim.x*(blockIdx.y + gridDim.y*blockIdx.z);
  int nid = (bid & 7)*(nwg >> 3) + (bid >> 3);
  int bx = nid % gridDim.x;
  int t1 = nid / gridDim.x;
  int by = t1 % gridDim.y;
  int e  = t1 / gridDim.y;
  int m0 = by*128;
  const bf16* bBase = Bt + (long)e*2048*768 + (long)(bx*64)*768;
  __shared__ bf16 As[2][128*32];
  __shared__ bf16 Bs[2][64*32];
  int tid = threadIdx.x;
  int w = tid >> 6, lane = tid & 63;
  int quad = lane >> 4, l16 = lane & 15;
  int wm = w*32;
  f32x4 acc[2][4] = {};
  int srow = (lane >> 2);
  int gsw  = ((lane & 3) ^ (srow & 3))*8;
  int xr = (l16 & 3);
  int cnt = gCnt[e];
  int tokA[2]; float wA[2];
#pragma unroll
  for (int j=0;j<2;j++){
    int row = m0 + (w*2+j)*16 + srow;
    bool live = row < cnt;
    tokA[j] = live ? lTok[e*CAP_ + row] : 0;
    wA[j]   = live ? lW[e*CAP_ + row]   : 0.f;
  }
  const int nIt = 24;   // 768/32
  // prologue: buf 0
  {
#pragma unroll
    for (int j=0;j<2;j++){
      const float* src = ln2 + (long)tokA[j]*D_ + gsw;
      float4 a0 = *(const float4*)(src);
      float4 a1 = *(const float4*)(src+4);
      union { bfrag f; bf16 h[8]; } o;
      o.h[0]=__float2bfloat16(a0.x*wA[j]); o.h[1]=__float2bfloat16(a0.y*wA[j]);
      o.h[2]=__float2bfloat16(a0.z*wA[j]); o.h[3]=__float2bfloat16(a0.w*wA[j]);
      o.h[4]=__float2bfloat16(a1.x*wA[j]); o.h[5]=__float2bfloat16(a1.y*wA[j]);
      o.h[6]=__float2bfloat16(a1.z*wA[j]); o.h[7]=__float2bfloat16(a1.w*wA[j]);
      *(bfrag*)(As[0] + (w*2+j)*512 + lane*8) = o.f;
    }
    int rowb = w*16 + srow;
    stage16(bBase + (long)rowb*768 + gsw, Bs[0] + w*512 + lane*8);
  }
  int cur = 0;
  for (int it=0; it<nIt; ++it){
    __syncthreads();
    float4 a0[2], a1[2];
    if (it+1 < nIt){
      int k0 = (it+1)*32;
#pragma unroll
      for (int j=0;j<2;j++){           // issue A loads early: latency hides under MFMA below
        const float* src = ln2 + (long)tokA[j]*D_ + k0 + gsw;
        a0[j] = *(const float4*)(src);
        a1[j] = *(const float4*)(src+4);
      }
      int rowb = w*16 + srow;
      stage16(bBase + (long)rowb*768 + k0 + gsw, Bs[cur^1] + w*512 + lane*8);
    }
    const bf16* Ac = As[cur];
    const bf16* Bc = Bs[cur];
    bfrag af[2], bfv[4];
#pragma unroll
    for (int t=0;t<2;t++) af[t]  = *(const bfrag*)(Ac + (wm + t*16 + l16)*32 + ((quad ^ xr)*8));
#pragma unroll
    for (int t=0;t<4;t++) bfv[t] = *(const bfrag*)(Bc + (t*16 + l16)*32 + ((quad ^ xr)*8));
#pragma unroll
    for (int ti=0;ti<2;ti++)
#pragma unroll
      for (int tj=0;tj<4;tj++)
        acc[ti][tj] = __builtin_amdgcn_mfma_f32_16x16x32_bf16(af[ti], bfv[tj], acc[ti][tj], 0, 0, 0);
    if (it+1 < nIt){
      int nb = cur^1;
#pragma unroll
      for (int j=0;j<2;j++){
        union { bfrag f; bf16 h[8]; } o;
        o.h[0]=__float2bfloat16(a0[j].x*wA[j]); o.h[1]=__float2bfloat16(a0[j].y*wA[j]);
        o.h[2]=__float2bfloat16(a0[j].z*wA[j]); o.h[3]=__float2bfloat16(a0[j].w*wA[j]);
        o.h[4]=__float2bfloat16(a1[j].x*wA[j]); o.h[5]=__float2bfloat16(a1[j].y*wA[j]);
        o.h[6]=__float2bfloat16(a1[j].z*wA[j]); o.h[7]=__float2bfloat16(a1[j].w*wA[j]);
        *(bfrag*)(As[nb] + (w*2+j)*512 + lane*8) = o.f;
      }
    }
    cur ^= 1;
  }
  // epilogue: relu + bf16 to Hid[e]
  bf16* Cb = C + (long)e*CAPP_*DFF_;
#pragma unroll
  for (int ti=0;ti<2;ti++)
#pragma unroll
    for (int tj=0;tj<4;tj++)
#pragma unroll
      for (int r=0;r<4;r++){
        int row = m0 + wm + ti*16 + quad*4 + r;
        int col = bx*64 + tj*16 + l16;
        Cb[(long)row*DFF_ + col] = __float2bfloat16(fmaxf(acc[ti][tj][r], 0.f));
      }
}

// ---------------- LayerNorm: fp32 in -> fp32 out (+ optional bf16 copy, + optional fused gate logits) ----------------
__global__ __launch_bounds__(256)
void ln_kernel(const float* __restrict__ src, const float* __restrict__ g, const float* __restrict__ bb,
               float* __restrict__ dstF, bf16* __restrict__ dstB,
               const float* __restrict__ gateW, float* __restrict__ glog2)
{
  int row = blockIdx.x, tid = threadIdx.x;
  __shared__ float red[256];
  __shared__ float gsum[4][E_];
  float v[3];
#pragma unroll
  for (int j=0;j<3;j++) v[j] = src[(long)row*D_ + tid + j*256];
  float s = v[0]+v[1]+v[2];
  red[tid]=s; __syncthreads();
  for (int o=128;o>0;o>>=1){ if(tid<o) red[tid]+=red[tid+o]; __syncthreads(); }
  float mean = red[0]*(1.0f/D_);
  __syncthreads();
  float sq = 0.f;
#pragma unroll
  for (int j=0;j<3;j++){ float d=v[j]-mean; sq += d*d; }
  red[tid]=sq; __syncthreads();
  for (int o=128;o>0;o>>=1){ if(tid<o) red[tid]+=red[tid+o]; __syncthreads(); }
  float rstd = rsqrtf(red[0]*(1.0f/D_) + 1e-5f);
  float ov[3];
#pragma unroll
  for (int j=0;j<3;j++){
    int d = tid + j*256;
    float o = (v[j]-mean)*rstd*g[d] + bb[d];
    ov[j] = o;
    dstF[(long)row*D_+d] = o;
    if (dstB) dstB[(long)row*D_+d] = __float2bfloat16(o);
  }
  if (gateW){
    float gp[E_] = {};
#pragma unroll
    for (int j=0;j<3;j++){
      int d = tid + j*256;
      const float* gw = gateW + (long)d*E_;
#pragma unroll
      for (int e=0;e<E_;e++) gp[e] += ov[j]*gw[e];
    }
#pragma unroll
    for (int off=1; off<64; off<<=1)
#pragma unroll
      for (int e=0;e<E_;e++) gp[e] += __shfl_xor(gp[e], off);
    if ((tid & 63) == 0)
#pragma unroll
      for (int e=0;e<E_;e++) gsum[tid>>6][e] = gp[e];
    __syncthreads();
    if (tid < E_)
      glog2[(long)row*E_ + tid] = gsum[0][tid]+gsum[1][tid]+gsum[2][tid]+gsum[3][tid];
  }
}

// ---------------- router logits + argmax + (h,e) bin build ----------------
#define RTOK 4
__global__ __launch_bounds__(768)
void router_argmax(const float* __restrict__ ln1, const float* __restrict__ WrT,
                   int* __restrict__ eidx, int* __restrict__ gHist,
                   int* __restrict__ hCnt, int* __restrict__ hList)
{
  int tok0 = blockIdx.x*RTOK;
  int tid = threadIdx.x;
  int col = tid >> 3, seg = tid & 7;     // col 0..95 (= h*8+e), seg 0..7
  __shared__ float xrow[RTOK][D_];
  __shared__ float logits[RTOK][96];
  for (int i=tid; i<RTOK*D_; i+=768){
    int t = i / D_, dpos = i - t*D_;
    xrow[t][dpos] = ln1[(long)(tok0+t)*D_ + dpos];
  }
  __syncthreads();
  const float* wrow = WrT + (long)col*D_;
  float acc[RTOK] = {};
#pragma unroll
  for (int j=0;j<24;j++){
    int dbase = j*32 + seg*4;
    float4 w = *(const float4*)(wrow + dbase);
#pragma unroll
    for (int t=0;t<RTOK;t++){
      float4 xv = *(const float4*)(&xrow[t][dbase]);
      acc[t] += xv.x*w.x + xv.y*w.y + xv.z*w.z + xv.w*w.w;
    }
  }
#pragma unroll
  for (int off=1; off<8; off<<=1)
#pragma unroll
    for (int t=0;t<RTOK;t++) acc[t] += __shfl_xor(acc[t], off);
  if (seg == 0)
#pragma unroll
    for (int t=0;t<RTOK;t++) logits[t][col] = acc[t];
  __syncthreads();
  if (tid < RTOK*H_){
    int t = tid / H_, h = tid % H_;
    const float* p = &logits[t][h*8];
    float best = p[0]; int bi = 0;
#pragma unroll
    for (int e=1;e<8;e++){ float v=p[e]; if (v > best){ best=v; bi=e; } }
    int tok = tok0 + t;
    eidx[tok*H_ + h] = bi;
    atomicAdd(&gHist[h*E_ + bi], 1);
    int he = h*E_ + bi;
    int pos = atomicAdd(&hCnt[he], 1);
    hList[he*NTOK + pos] = tok;
  }
}

// ---------------- binned V projection: one (h,e) per block.x, W in LDS, stream bin tokens ----------------
__global__ __launch_bounds__(256)
void vsel_b(const float* __restrict__ ln1, const float* __restrict__ Wv,
            const int* __restrict__ hCnt, const int* __restrict__ hList,
            bf16* __restrict__ vT)
{
  int he = blockIdx.x;             // h*E + e
  int h = he >> 3;
  __shared__ float Ws[DH_*DH_];    // 16 KB
  __shared__ float xsh[4][DH_];
  int tid = threadIdx.x;
  const float* W = Wv + (long)he*DH_*DH_;
  for (int i=tid; i<DH_*DH_; i+=256) Ws[i] = W[i];
  int cnt = hCnt[he];
  __syncthreads();
  int w = tid >> 6, lane = tid & 63;
  const int* lst = hList + (long)he*NTOK;
  for (int i = blockIdx.y*4 + w; i < cnt; i += 32){
    int tok = lst[i];
    int b = tok >> 10, s = tok & 1023;
    xsh[w][lane] = ln1[(long)tok*D_ + h*DH_ + lane];
    float acc = 0.f;
#pragma unroll 8
    for (int d=0; d<DH_; d++) acc += xsh[w][d]*Ws[d*DH_ + lane];
    vT[((long)(b*H_+h)*DH_ + lane)*S_ + s] = __float2bfloat16(acc);
  }
}

// ---------------- attention pass 1 (MFMA flash stats), PAIRED bands (x & 15-x) for load balance ----------------
__global__ __launch_bounds__(256)
void attn_stats_mfma(const bf16* __restrict__ qkB, float* __restrict__ gM, float* __restrict__ gL)
{
  int h = blockIdx.y, b = blockIdx.z;
  int tid = threadIdx.x;
  int w = tid >> 6, lane = tid & 63;
  int quad = lane >> 4, l16 = lane & 15;
  int x7 = l16 & 7;                    // read-side swizzle key (row&7 == l16&7)
  __shared__ bf16 ldsQ[64*64];
  __shared__ bf16 ldsK[2][64*64];
  const bf16* kbase = qkB + ((long)(b*S_))*QKLD + 768 + h*DH_;
  for (int half=0; half<2; half++){
    int s0 = (half ? (S_/64 - 1 - blockIdx.x) : blockIdx.x)*64;   // bands x and 15-x: uniform 17 tiles
    __syncthreads();                 // protect LDS reuse across bands
    const bf16* qbase = qkB + ((long)(b*S_ + s0))*QKLD + h*DH_;
#pragma unroll
    for (int j=0;j<2;j++){
      int c = j*256 + tid;
      int row = c >> 3;
      int gs = ((c & 7) ^ (row & 7))*8;
      stage16(qbase + (long)row*QKLD + gs, ldsQ + c*8);
      stage16(kbase + (long)row*QKLD + gs, ldsK[0] + c*8);   // tt=0 prefetch
    }
    float m_ln[4] = {-1e30f,-1e30f,-1e30f,-1e30f};
    float l_ln[4] = {0.f,0.f,0.f,0.f};
    int ttEnd = s0 >> 6;
    int cur = 0;
    for (int tt=0; tt<=ttEnd; tt++){
      __syncthreads();               // drains stage of ldsK[cur]
      if (tt < ttEnd){
#pragma unroll
        for (int j=0;j<2;j++){
          int c = j*256 + tid;
          int row = c >> 3;
          int gs = ((c & 7) ^ (row & 7))*8;
          stage16(kbase + (long)((tt+1)*64 + row)*QKLD + gs, ldsK[cur^1] + c*8);
        }
      }
      const bf16* Kc = ldsK[cur];
      bfrag af0 = *(const bfrag*)(ldsQ + (w*16 + l16)*64 + ((quad     ^ x7)*8));
      bfrag af1 = *(const bfrag*)(ldsQ + (w*16 + l16)*64 + (((quad+4) ^ x7)*8));
      f32x4 cfr[4];
#pragma unroll
      for (int j=0;j<4;j++){
        bfrag b0 = *(const bfrag*)(Kc + (j*16 + l16)*64 + ((quad     ^ x7)*8));
        bfrag b1 = *(const bfrag*)(Kc + (j*16 + l16)*64 + (((quad+4) ^ x7)*8));
        f32x4 z = {};
        z = __builtin_amdgcn_mfma_f32_16x16x32_bf16(af0, b0, z, 0,0,0);
        z = __builtin_amdgcn_mfma_f32_16x16x32_bf16(af1, b1, z, 0,0,0);
        cfr[j] = z;
      }
      // lane-local online update; garbage from all-masked lanes flushed at the final reduce.
#pragma unroll
      for (int r=0;r<4;r++){
        int s_g = s0 + w*16 + quad*4 + r;
        float v0 = (tt*64      + l16 <= s_g) ? cfr[0][r]*0.125f : -1e30f;
        float v1 = (tt*64 + 16 + l16 <= s_g) ? cfr[1][r]*0.125f : -1e30f;
        float v2 = (tt*64 + 32 + l16 <= s_g) ? cfr[2][r]*0.125f : -1e30f;
        float v3 = (tt*64 + 48 + l16 <= s_g) ? cfr[3][r]*0.125f : -1e30f;
        float mt = fmaxf(fmaxf(v0,v1), fmaxf(v2,v3));
        float mn = fmaxf(m_ln[r], mt);
        l_ln[r] = l_ln[r]*__expf(m_ln[r]-mn)
                + ((__expf(v0-mn)+__expf(v1-mn)) + (__expf(v2-mn)+__expf(v3-mn)));
        m_ln[r] = mn;
      }
      cur ^= 1;
    }
    // deferred cross-lane reduction (once per band)
#pragma unroll
    for (int r=0;r<4;r++){
      float mf = m_ln[r];
#pragma unroll
      for (int mm=1; mm<16; mm<<=1) mf = fmaxf(mf, __shfl_xor(mf, mm));
      float lf = l_ln[r]*__expf(m_ln[r]-mf);
#pragma unroll
      for (int mm=1; mm<16; mm<<=1) lf += __shfl_xor(lf, mm);
      if (l16 == 0){
        long basei = ((long)(b*H_ + h))*S_ + s0 + w*16 + quad*4 + r;
        gM[basei] = mf; gL[basei] = lf;
      }
    }
  }
}

// ---------------- attention pass 2 (fused MFMA, transposed einsum), PAIRED bands + dbuf Q/V ----------------
__global__ __launch_bounds__(256)
void attn_pv(const bf16* __restrict__ qkB, const bf16* __restrict__ vT,
             const float* __restrict__ gM, const float* __restrict__ gL, float* __restrict__ aoH)
{
  int h = blockIdx.y, b = blockIdx.z;
  int bh = b*H_ + h;
  int tid = threadIdx.x;
  int w = tid >> 6, lane = tid & 63;
  int quad = lane >> 4, l16 = lane & 15;
  int x7 = l16 & 7;
  __shared__ bf16 ldsK[64*64];
  __shared__ bf16 ldsQ[2][64*64];
  __shared__ bf16 ldsV[2][64*64];
  __shared__ bf16 ldsS[64*72];        // +8 pad; wave-band-private
  __shared__ float smx[2][64], sli[2][64];
  const bf16* qbase = qkB + ((long)(b*S_))*QKLD + h*DH_;
  const bf16* vbase = vT + ((long)bh*DH_)*S_;
  for (int half=0; half<2; half++){
    int t0 = (half ? (S_/64 - 1 - blockIdx.x) : blockIdx.x)*64;   // paired bands: uniform 17 tiles/block
    __syncthreads();                 // protect LDS reuse across bands
    const bf16* kbase = qkB + ((long)(b*S_ + t0))*QKLD + 768 + h*DH_;
    int sb0 = t0 >> 6;
#pragma unroll
    for (int j=0;j<2;j++){
      int c = j*256 + tid;
      int row = c >> 3;
      int gs = ((c & 7) ^ (row & 7))*8;
      stage16(kbase + (long)row*QKLD + gs, ldsK + c*8);
      stage16(qbase + (long)(sb0*64 + row)*QKLD + gs, ldsQ[0] + c*8);
      stage16(vbase + (long)row*S_ + sb0*64 + gs, ldsV[0] + c*8);
    }
    if (tid < 64){
      smx[0][tid] = gM[(long)bh*S_ + sb0*64 + tid];
      sli[0][tid] = 1.0f / gL[(long)bh*S_ + sb0*64 + tid];
    }
    f32x4 accO[4] = {};
    int cur = 0;
    for (int sb = sb0; sb < S_/64; sb++){
      __syncthreads();
      if (sb+1 < S_/64){
        int nb = cur^1;
#pragma unroll
        for (int j=0;j<2;j++){
          int c = j*256 + tid;
          int row = c >> 3;
          int gs = ((c & 7) ^ (row & 7))*8;
          stage16(qbase + (long)((sb+1)*64 + row)*QKLD + gs, ldsQ[nb] + c*8);
          stage16(vbase + (long)row*S_ + (sb+1)*64 + gs, ldsV[nb] + c*8);
        }
        if (tid < 64){
          smx[nb][tid] = gM[(long)bh*S_ + (sb+1)*64 + tid];
          sli[nb][tid] = 1.0f / gL[(long)bh*S_ + (sb+1)*64 + tid];
        }
      }
      const bf16* Qc = ldsQ[cur];
      const bf16* Vc = ldsV[cur];
      bfrag af0 = *(const bfrag*)(ldsK + (w*16 + l16)*64 + ((quad     ^ x7)*8));
      bfrag af1 = *(const bfrag*)(ldsK + (w*16 + l16)*64 + (((quad+4) ^ x7)*8));
      f32x4 cs[4];
#pragma unroll
      for (int j=0;j<4;j++){
        bfrag b0 = *(const bfrag*)(Qc + (j*16 + l16)*64 + ((quad     ^ x7)*8));
        bfrag b1 = *(const bfrag*)(Qc + (j*16 + l16)*64 + (((quad+4) ^ x7)*8));
        f32x4 z = {};
        z = __builtin_amdgcn_mfma_f32_16x16x32_bf16(af0, b0, z, 0,0,0);
        z = __builtin_amdgcn_mfma_f32_16x16x32_bf16(af1, b1, z, 0,0,0);
        cs[j] = z;
      }
#pragma unroll
      for (int j=0;j<4;j++)
#pragma unroll
        for (int r=0;r<4;r++){
          int t_loc = w*16 + quad*4 + r;
          int s_loc = j*16 + l16;
          float wgt = ((t0 + t_loc) <= (sb*64 + s_loc))
                    ? __expf(cs[j][r]*0.125f - smx[cur][s_loc])*sli[cur][s_loc] : 0.f;
          ldsS[t_loc*72 + s_loc] = __float2bfloat16(wgt);
        }
      bfrag pa0 = *(const bfrag*)(ldsS + (w*16 + l16)*72 + quad*8);
      bfrag pa1 = *(const bfrag*)(ldsS + (w*16 + l16)*72 + 32 + quad*8);
#pragma unroll
      for (int j=0;j<4;j++){
        bfrag b0 = *(const bfrag*)(Vc + (j*16 + l16)*64 + ((quad     ^ x7)*8));
        bfrag b1 = *(const bfrag*)(Vc + (j*16 + l16)*64 + (((quad+4) ^ x7)*8));
        accO[j] = __builtin_amdgcn_mfma_f32_16x16x32_bf16(pa0, b0, accO[j], 0,0,0);
        accO[j] = __builtin_amdgcn_mfma_f32_16x16x32_bf16(pa1, b1, accO[j], 0,0,0);
      }
      cur ^= 1;
    }
#pragma unroll
    for (int j=0;j<4;j++)
#pragma unroll
      for (int r=0;r<4;r++){
        int t_loc = w*16 + quad*4 + r;
        int f = j*16 + l16;
        aoH[((long)bh*S_ + t0 + t_loc)*DH_ + f] = accO[j][r];
      }
  }
}

// ---------------- binned O projection + residual: one (h,e) per block.x, W in LDS ----------------
__global__ __launch_bounds__(256)
void oproj_b(const float* __restrict__ aoH, const float* __restrict__ Wo,
             const int* __restrict__ hCnt, const int* __restrict__ hList,
             const float* __restrict__ x, float* __restrict__ x1)
{
  int he = blockIdx.x;             // h*E + e
  int h = he >> 3;
  __shared__ float Ws[DH_*DH_];    // 16 KB
  __shared__ float xsh[4][DH_];
  int tid = threadIdx.x;
  const float* W = Wo + (long)he*DH_*DH_;
  for (int i=tid; i<DH_*DH_; i+=256) Ws[i] = W[i];
  int cnt = hCnt[he];
  __syncthreads();
  int w = tid >> 6, lane = tid & 63;
  const int* lst = hList + (long)he*NTOK;
  for (int i = blockIdx.y*4 + w; i < cnt; i += 32){
    int tok = lst[i];
    int b = tok >> 10, s = tok & 1023;
    xsh[w][lane] = aoH[((long)(b*H_+h)*S_ + s)*DH_ + lane];
    float acc = 0.f;
#pragma unroll 8
    for (int f=0; f<DH_; f++) acc += xsh[w][f]*Ws[f*DH_ + lane];
    long idx = (long)tok*D_ + h*DH_ + lane;
    x1[idx] = x[idx] + acc;
  }
}

// ---------------- MoE routing: top-2, PARALLEL capacity prefix-scan, lists, aux losses ----------------
__global__ __launch_bounds__(256)
void route_kernel(const float* __restrict__ glog2, const int* __restrict__ gHist,
                  int* __restrict__ gI0, int* __restrict__ gI1,
                  int* __restrict__ gPos0, int* __restrict__ gPos1,
                  int* __restrict__ listTok, float* __restrict__ listW,
                  int* __restrict__ gCnt, float* __restrict__ auxOut)
{
  __shared__ unsigned char sI0[NTOK], sI1[NTOK];
  __shared__ float sP0[NTOK], sP1[NTOK];
  __shared__ short sPos0[NTOK], sPos1[NTOK];
  __shared__ int   sScan[256*E_];
  __shared__ int   sHist[H_*E_];
  __shared__ float sImp[E_];
  __shared__ int   sCnt[E_];
  int tid = threadIdx.x;
  if (tid < E_) sImp[tid] = 0.f;
  if (tid < H_*E_) sHist[tid] = gHist[tid];
  for (int i=tid; i<NTOK; i+=256){
    const float* p = glog2 + (long)i*E_;
    float b0 = p[0]; int e0 = 0;
#pragma unroll
    for (int e=1;e<E_;e++){ float vv=p[e]; if (vv > b0){ b0=vv; e0=e; } }
    float b1v = -1e30f; int e1 = 0;
#pragma unroll
    for (int e=0;e<E_;e++){ if (e==e0) continue; float vv=p[e]; if (vv > b1v){ b1v=vv; e1=e; } }
    float ex = __expf(b1v - b0);
    float inv = 1.f/(1.f + ex);
    sI0[i] = (unsigned char)e0; sI1[i] = (unsigned char)e1;
    sP0[i] = inv; sP1[i] = ex*inv;
    gI0[i] = e0; gI1[i] = e1;
  }
  __syncthreads();
  {
    int myCnt[E_] = {};
#pragma unroll
    for (int j=0;j<16;j++){
      int i = tid*16 + j;
      int tok = i >> 1;
      int e = (i & 1) ? (int)sI1[tok] : (int)sI0[tok];
      myCnt[e]++;
    }
#pragma unroll
    for (int e=0;e<E_;e++) sScan[tid*E_+e] = myCnt[e];
    __syncthreads();
    for (int off=1; off<256; off<<=1){
      int v[E_];
      if (tid >= off){
#pragma unroll
        for (int e=0;e<E_;e++) v[e] = sScan[(tid-off)*E_+e];
      }
      __syncthreads();
      if (tid >= off){
#pragma unroll
        for (int e=0;e<E_;e++) sScan[tid*E_+e] += v[e];
      }
      __syncthreads();
    }
    int pref[E_];
#pragma unroll
    for (int e=0;e<E_;e++) pref[e] = tid ? sScan[(tid-1)*E_+e] : 0;
#pragma unroll
    for (int j=0;j<16;j++){
      int i = tid*16 + j;
      int tok = i >> 1;
      int e = (i & 1) ? (int)sI1[tok] : (int)sI0[tok];
      int pos = pref[e]++;
      short p = (pos < CAP_) ? (short)pos : (short)-1;
      if (i & 1) sPos1[tok] = p; else sPos0[tok] = p;
    }
    if (tid < E_){
      int cnt = sScan[255*E_ + tid];
      sCnt[tid] = cnt < CAP_ ? cnt : CAP_;
      gCnt[tid] = sCnt[tid];
    }
  }
  __syncthreads();
  for (int i=tid; i<NTOK; i+=256){
    int e0 = sI0[i], e1 = sI1[i];
    int p0i = sPos0[i], p1i = sPos1[i];
    float k0 = p0i >= 0 ? 1.f : 0.f, k1 = p1i >= 0 ? 1.f : 0.f;
    float p0 = sP0[i], p1 = sP1[i];
    float denom = p0*k0 + p1*k1 + 1e-9f;
    float w0 = p0*k0/denom, w1 = p1*k1/denom;
    if (p0i >= 0){ listTok[e0*CAP_+p0i] = i; listW[e0*CAP_+p0i] = w0; atomicAdd(&sImp[e0], w0); }
    if (p1i >= 0){ listTok[e1*CAP_+p1i] = i; listW[e1*CAP_+p1i] = w1; atomicAdd(&sImp[e1], w1); }
    gPos0[i] = p0i; gPos1[i] = p1i;
  }
  __syncthreads();
  if (tid == 0){
    float tot = 0.f;
    for (int i=0;i<H_*E_;i++) tot += (float)sHist[i]*(1.0f/NTOK)*0.01f;
    float a1 = 0.f;
    for (int i=0;i<H_*E_;i++){
      float p = ((float)sHist[i]*(1.0f/NTOK)*0.01f)/(tot + 1e-9f);
      a1 += p*p;
    }
    a1 *= (float)(H_*E_);
    float tcs = 0.f, ims = 0.f;
    for (int e=0;e<E_;e++){ tcs += (float)sCnt[e]; ims += sImp[e]; }
    float a2 = 0.f;
    for (int e=0;e<E_;e++) a2 += ((float)sCnt[e]/tcs)*(sImp[e]/ims);
    a2 *= (float)E_;
    auxOut[0] = a1 + a2;
  }
}

// ---------------- final combine: out = x1 + expert contributions (2 split-K slices, fp32) ----------------
__global__ __launch_bounds__(256)
void combine_kernel(const float* __restrict__ x1,
                    const float* __restrict__ Ya, const float* __restrict__ Yb,
                    const int* __restrict__ gI0, const int* __restrict__ gI1,
                    const int* __restrict__ gPos0, const int* __restrict__ gPos1,
                    float* __restrict__ out)
{
  int i = blockIdx.x;
  int tid = threadIdx.x;
  int p0 = gPos0[i], p1 = gPos1[i];
  int e0 = gI0[i],  e1 = gI1[i];
  long off0 = (long)(e0*CAPP_ + (p0 >= 0 ? p0 : 0))*D_;
  long off1 = (long)(e1*CAPP_ + (p1 >= 0 ? p1 : 0))*D_;
  const float* y0a = Ya + off0; const float* y0b = Yb + off0;
  const float* y1a = Ya + off1; const float* y1b = Yb + off1;
  for (int d=tid; d<D_; d+=256){
    float v = x1[(long)i*D_+d];
    if (p0 >= 0) v += y0a[d] + y0b[d];
    if (p1 >= 0) v += y1a[d] + y1b[d];
    out[(long)i*D_+d] = v;
  }
}

extern "C" void kernel_launch(void* const* d_in, const int* in_sizes, int n_in,
                              void* d_out, int out_size, void* d_ws, size_t ws_size,
                              hipStream_t stream)
{
  const float* x    = (const float*)d_in[0];
  const float* W_q  = (const float*)d_in[2];
  const float* W_k  = (const float*)d_in[3];
  const float* W_v  = (const float*)d_in[4];
  const float* W_o  = (const float*)d_in[5];
  const float* W_r  = (const float*)d_in[6];
  const float* g1   = (const float*)d_in[7];
  const float* b1   = (const float*)d_in[8];
  const float* g2   = (const float*)d_in[9];
  const float* b2   = (const float*)d_in[10];
  const float* gate = (const float*)d_in[11];
  const float* W1   = (const float*)d_in[12];
  const float* W2   = (const float*)d_in[13];
  float* out = (float*)d_out;

  float* wsf = (float*)d_ws;
  // ---- workspace layout (float slots) ----
  const long oX1   = 0;          // 1,572,864
  const long oLnF  = 1572864;    // fp32 2048x768; live through gemm_ffn1, then reused as split-K slice 1
  const long oLnB  = 3145728;    // bf16 2048x768
  const long oWcat = 3932160;    // bf16 1536x768 (ends 4521984)
  const long oWrT  = 4521984;    // fp32 96x768 = 73,728 (ends 4595712)
  const long oHist = 4595712;    // int 96 (attention (h,e) histogram)
  const long oHCnt = 4595808;    // int 96 ((h,e) bin counters) - adjacent: one memset covers both
  const long oGM   = 4718592;    // 24,576
  const long oGL   = 4743168;    // 24,576
  const long oEidx = 4767744;    // int 24,576
  const long oGlg2 = 4792320;    // 16,384
  const long oI0   = 4808704;
  const long oI1   = 4810752;
  const long oP0   = 4812800;
  const long oP1   = 4814848;
  const long oLT   = 4816896;
  const long oLW   = 4819456;
  const long oCnt  = 4822016;    // 8 ints
  const long SB    = 4822528;    // shared overlay region
  // attention view: qkB bf16 @SB (1.57M) | vT bf16 @+1,572,864 | aoH fp32 @+2,359,296 |
  //                 hList int @+3,932,160 (96*2048)
  // FFN view:       Hid @+7,471,104 | Yexp fp32 @+10,616,832   (Xg slot retired: gather fused into gemm_ffn1)
  const long oWT1  = SB + 12976128;      // bf16 8 x 2048x768 (6,291,456 fl) - dedicated, no overlay
  const long oWT2  = oWT1 + 6291456;     // bf16 8 x 768x2048 (6,291,456 fl)
  const long TOTAL = oWT2 + 6291456;     // 30,381,568 floats = 121.5 MB
  if (ws_size < (size_t)TOTAL*4) return;

  float* x1    = wsf + oX1;
  float* lnbF  = wsf + oLnF;
  bf16*  lnbB  = (bf16*)(wsf + oLnB);
  bf16*  WcatB = (bf16*)(wsf + oWcat);
  float* WrT   = wsf + oWrT;
  int*   gHist = (int*)(wsf + oHist);
  int*   hCnt  = (int*)(wsf + oHCnt);
  float* gM    = wsf + oGM;
  float* gL    = wsf + oGL;
  int*   eidx  = (int*)(wsf + oEidx);
  float* glog2 = wsf + oGlg2;
  int*   gI0   = (int*)(wsf + oI0);
  int*   gI1   = (int*)(wsf + oI1);
  int*   gPos0 = (int*)(wsf + oP0);
  int*   gPos1 = (int*)(wsf + oP1);
  int*   lTok  = (int*)(wsf + oLT);
  float* lW    = wsf + oLW;
  int*   gCnt  = (int*)(wsf + oCnt);
  bf16*  qkB   = (bf16*)(wsf + SB);
  bf16*  vT    = (bf16*)(wsf + SB + 1572864);
  float* aoH   = wsf + SB + 2359296;
  int*   hList = (int*)(wsf + SB + 3932160);
  bf16*  Hid   = (bf16*)(wsf + SB + 7471104);
  float* Yexp  = wsf + SB + 10616832;
  float* YexpB = wsf + oLnF;     // split-K slice 1: lnF region, dead once gemm_ffn1 completes
  bf16*  WT1   = (bf16*)(wsf + oWT1);
  bf16*  WT2   = (bf16*)(wsf + oWT2);

  // ---- counter zero (gHist + hCnt adjacent) + ALL weight prep in one dispatch ----
  hipMemsetAsync(gHist, 0, 2*NHE*sizeof(int), stream);
  transp_all<<<3252,256,0,stream>>>(W_q, W_k, W_r, W1, W2, WcatB, WrT, WT1, WT2);

  // ---- attention phase ----
  ln_kernel<<<NTOK,256,0,stream>>>(x, g1, b1, lnbF, lnbB, nullptr, nullptr);
  gemm_bn64<<<dim3(24,16,1),256,0,stream>>>(lnbB, WcatB, qkB, nullptr, 2048, QKLD, 768, 0,0,0, 0, 1, 1);
  router_argmax<<<NTOK/RTOK,768,0,stream>>>(lnbF, WrT, eidx, gHist, hCnt, hList);
  vsel_b<<<dim3(NHE,8,1),256,0,stream>>>(lnbF, W_v, hCnt, hList, vT);
  attn_stats_mfma<<<dim3(S_/128,H_,B_),256,0,stream>>>(qkB, gM, gL);
  attn_pv<<<dim3(S_/128,H_,B_),256,0,stream>>>(qkB, vT, gM, gL, aoH);
  oproj_b<<<dim3(NHE,8,1),256,0,stream>>>(aoH, W_o, hCnt, hList, x, x1);

  // ---- FFN phase (gather fused into W1 GEMM) ----
  ln_kernel<<<NTOK,256,0,stream>>>(x1, g2, b2, lnbF, nullptr, gate, glog2);  // fused gate logits
  route_kernel<<<1,256,0,stream>>>(glog2, gHist, gI0,gI1,gPos0,gPos1, lTok,lW,gCnt, out + (size_t)NTOK*D_);
  gemm_ffn1<<<dim3(32,3,8),256,0,stream>>>(lnbF, WT1, Hid, lTok, lW, gCnt);
  gemm_bn64<<<dim3(12,3,16),256,0,stream>>>(Hid, WT2, Yexp, YexpB, CAPP_, 768, 2048,
                                            (long)CAPP_*2048, (long)768*2048, (long)CAPP_*768, 0, 0, 2);
  combine_kernel<<<NTOK,256,0,stream>>>(x1, Yexp, YexpB, gI0,gI1,gPos0,gPos1, out);
}

// Round 8
// 382.155 us; speedup vs baseline: 1.0351x; 1.0351x over previous
//
#include <hip/hip_runtime.h>
#include <hip/hip_bf16.h>
#include <cstdint>

typedef __hip_bfloat16 bf16;
typedef __attribute__((ext_vector_type(8))) __bf16 bfrag;   // MFMA A/B operand (4 VGPRs)
typedef __attribute__((ext_vector_type(4))) float f32x4;    // MFMA C/D operand

#define B_    2
#define S_    1024
#define D_    768
#define H_    12
#define E_    8
#define DH_   64
#define DFF_  2048
#define CAP_  320            // ceil(1.25 * 2048 / 8)
#define CAPP_ 384            // CAP padded to 128-multiple for MFMA tiles
#define NTOK  (B_*S_)        // 2048
#define NTH   (NTOK*H_)      // 24576
#define QKLD  1536           // fused q|k row stride
#define NHE   (H_*E_)        // 96 (h,e) bins

// ---------------- async global->LDS 16B stage (per-lane global addr, lane-linear LDS) ----------------
__device__ __forceinline__ void stage16(const bf16* g, bf16* ldsLane){
#if __has_builtin(__builtin_amdgcn_global_load_lds)
  __builtin_amdgcn_global_load_lds((const __attribute__((address_space(1))) unsigned int*)g,
                                   (__attribute__((address_space(3))) unsigned int*)ldsLane, 16, 0, 0);
#else
  *(bfrag*)ldsLane = *(const bfrag*)g;
#endif
}

// ---------------- shared transpose tile body: 64n x 128k, XOR-swizzled LDS, 256B write runs ----------------
// t: 128x64 fp32 LDS tile. logical (row,col) stored at col' = col ^ (((row>>3)&15)*4).
__device__ __forceinline__ void transp_tile_bf16(const float* __restrict__ src, bf16* __restrict__ dst,
                                                 int N, int K, int n0, int k0, int tid, float (*t)[64])
{
  int chunk = tid & 15, rgrp = tid >> 4;
#pragma unroll
  for (int rr=0; rr<8; rr++){
    int row = rr*16 + rgrp;
    float4 v = *(const float4*)(src + (long)(k0+row)*N + n0 + chunk*4);
    *(float4*)&t[row][((chunk ^ (row>>3)) & 15)*4] = v;
  }
  __syncthreads();
#pragma unroll
  for (int it=0; it<4; it++){
    int slot = it*256 + tid;
    int n = slot >> 4, kc = slot & 15;      // 16 lanes (kc 0..15) cover one full 128-bf16 output row
    union { bfrag f; bf16 h[8]; } o;
#pragma unroll
    for (int i=0;i<8;i++){
      int row = kc*8 + i;                   // (row>>3)&15 == kc
      o.h[i] = __float2bfloat16(t[row][n ^ (kc*4)]);
    }
    *(bfrag*)(dst + (long)(n0+n)*K + k0 + kc*8) = o.f;
  }
}

// ---------------- Wq|Wk|Wr prep (needed immediately): 180 blocks ----------------
//   [0,72)    Wq 768x768 -> WcatB rows 0..767     (12nx x 6ky)
//   [72,144)  Wk 768x768 -> WcatB rows 768..1535
//   [144,180) Wr 768x96  -> WrT fp32 (64k x 32n tiles)
__global__ __launch_bounds__(256)
void transp_qkr(const float* __restrict__ Wq, const float* __restrict__ Wk,
                const float* __restrict__ Wr, bf16* __restrict__ WcatB, float* __restrict__ WrT)
{
  __shared__ float t[128][64];
  int bid = blockIdx.x, tid = threadIdx.x;
  if (bid < 144){
    const float* src; bf16* dst; int r;
    if (bid < 72){ src = Wq; dst = WcatB; r = bid; }
    else         { src = Wk; dst = WcatB + (long)768*768; r = bid - 72; }
    transp_tile_bf16(src, dst, 768, 768, (r%12)*64, (r/12)*128, tid, t);
  } else {
    int r = bid - 144;
    int n0 = (r % 3)*32, k0 = (r / 3)*64;
    int chunk = tid & 7, row2 = tid >> 3;
#pragma unroll
    for (int rr=0; rr<2; rr++){
      int row = rr*32 + row2;
      float4 v = *(const float4*)(Wr + (long)(k0+row)*96 + n0 + chunk*4);
      *(float4*)&t[row][chunk*4] = v;
    }
    __syncthreads();
    int chunkw = tid & 15, ng = tid >> 4;
#pragma unroll
    for (int rr=0; rr<2; rr++){
      int n = rr*16 + ng;
      float4 o;
      o.x = t[chunkw*4+0][n]; o.y = t[chunkw*4+1][n];
      o.z = t[chunkw*4+2][n]; o.w = t[chunkw*4+3][n];
      *(float4*)(WrT + (long)(n0+n)*768 + k0 + chunkw*4) = o;
    }
  }
}

// ---------------- MFMA GEMM, 128x64 tile, xor-swizzled LDS, XCD-chunked swizzle, split-K, 2-phase dbuf ----------------
__global__ __launch_bounds__(256)
void gemm_bn64(const bf16* __restrict__ A, const bf16* __restrict__ Bt,
               void* __restrict__ C, void* __restrict__ C2,
               int M, int N, int K, long sA, long sB, long sC, int relu, int outBf, int kSplit)
{
  int nwg = gridDim.x*gridDim.y*gridDim.z;
  int bid = blockIdx.x + gridDim.x*(blockIdx.y + gridDim.y*blockIdx.z);
  int nid = (bid & 7)*(nwg >> 3) + (bid >> 3);        // bijective: nwg % 8 == 0 at all call sites
  int bx = nid % gridDim.x;
  int t1 = nid / gridDim.x;
  int by = t1 % gridDim.y;
  int bz = t1 / gridDim.y;
  int e  = bz / kSplit, kc = bz - e*kSplit;
  A  += (long)e*sA;
  Bt += (long)e*sB;
  int kLen = K / kSplit, kBase = kc*kLen;
  int m0 = by*128, n0 = bx*64;
  __shared__ bf16 As[2][128*32];   // 2 x 8 KB
  __shared__ bf16 Bs[2][64*32];    // 2 x 4 KB
  int tid = threadIdx.x;
  int w = tid >> 6, lane = tid & 63;
  int quad = lane >> 4, l16 = lane & 15;
  int wm = w*32;
  f32x4 acc[2][4] = {};
  int srow = (lane >> 2);          // row within 16-row chunk
  int gsw  = ((lane & 3) ^ (srow & 3))*8;   // swizzled col group (8 bf16)
  const bf16* aBase = A + (long)m0*K;
  const bf16* bBase = Bt + (long)n0*K;
  int xr = (l16 & 3);              // read-side swizzle key (row&3 == l16&3)
  int nIt = kLen >> 5;
  {
    int k0 = kBase;
#pragma unroll
    for (int j=0;j<2;j++){
      int c = w*2 + j, row = c*16 + srow;
      stage16(aBase + (long)row*K + k0 + gsw, As[0] + c*512 + lane*8);
    }
    int rowb = w*16 + srow;
    stage16(bBase + (long)rowb*K + k0 + gsw, Bs[0] + w*512 + lane*8);
  }
  int cur = 0;
  for (int it=0; it<nIt; ++it){
    __syncthreads();               // drains stage of buf[cur]
    if (it+1 < nIt){               // prefetch next k-step into buf[cur^1]
      int k0 = kBase + (it+1)*32;
      int nb = cur^1;
#pragma unroll
      for (int j=0;j<2;j++){
        int c = w*2 + j, row = c*16 + srow;
        stage16(aBase + (long)row*K + k0 + gsw, As[nb] + c*512 + lane*8);
      }
      int rowb = w*16 + srow;
      stage16(bBase + (long)rowb*K + k0 + gsw, Bs[nb] + w*512 + lane*8);
    }
    const bf16* Ac = As[cur];
    const bf16* Bc = Bs[cur];
    bfrag af[2], bfv[4];
#pragma unroll
    for (int t=0;t<2;t++) af[t]  = *(const bfrag*)(Ac + (wm + t*16 + l16)*32 + ((quad ^ xr)*8));
#pragma unroll
    for (int t=0;t<4;t++) bfv[t] = *(const bfrag*)(Bc + (t*16 + l16)*32 + ((quad ^ xr)*8));
#pragma unroll
    for (int ti=0;ti<2;ti++)
#pragma unroll
      for (int tj=0;tj<4;tj++)
        acc[ti][tj] = __builtin_amdgcn_mfma_f32_16x16x32_bf16(af[ti], bfv[tj], acc[ti][tj], 0, 0, 0);
    cur ^= 1;
  }
  long zoff = (long)e*sC;
  void* Cp = kc ? C2 : C;
  if (outBf){
    bf16* Cb = (bf16*)Cp + zoff;
#pragma unroll
    for (int ti=0;ti<2;ti++)
#pragma unroll
      for (int tj=0;tj<4;tj++)
#pragma unroll
        for (int r=0;r<4;r++){
          int row = m0 + wm + ti*16 + quad*4 + r;
          int col = n0 + tj*16 + l16;
          float v = acc[ti][tj][r];
          if (relu) v = fmaxf(v, 0.f);
          Cb[(long)row*N + col] = __float2bfloat16(v);
        }
  } else {
    float* Cf = (float*)Cp + zoff;
#pragma unroll
    for (int ti=0;ti<2;ti++)
#pragma unroll
      for (int tj=0;tj<4;tj++)
#pragma unroll
        for (int r=0;r<4;r++){
          int row = m0 + wm + ti*16 + quad*4 + r;
          int col = n0 + tj*16 + l16;
          float v = acc[ti][tj][r];
          if (relu) v = fmaxf(v, 0.f);
          Cf[(long)row*N + col] = v;
        }
  }
}

// ---------------- W1 GEMM with FUSED gather: A reg-staged from fp32 ln2 via token list ----------------
__global__ __launch_bounds__(256)
void gemm_ffn1(const float* __restrict__ ln2, const bf16* __restrict__ Bt, bf16* __restrict__ C,
               const int* __restrict__ lTok, const float* __restrict__ lW, const int* __restrict__ gCnt)
{
  int nwg = gridDim.x*gridDim.y*gridDim.z;   // 32*3*8 = 768
  int bid = blockIdx.x + gridDim.x*(blockIdx.y + gridDim.y*blockIdx.z);
  int nid = (bid & 7)*(nwg >> 3) + (bid >> 3);
  int bx = nid % gridDim.x;
  int t1 = nid / gridDim.x;
  int by = t1 % gridDim.y;
  int e  = t1 / gridDim.y;
  int m0 = by*128;
  const bf16* bBase = Bt + (long)e*2048*768 + (long)(bx*64)*768;
  __shared__ bf16 As[2][128*32];
  __shared__ bf16 Bs[2][64*32];
  int tid = threadIdx.x;
  int w = tid >> 6, lane = tid & 63;
  int quad = lane >> 4, l16 = lane & 15;
  int wm = w*32;
  f32x4 acc[2][4] = {};
  int srow = (lane >> 2);
  int gsw  = ((lane & 3) ^ (srow & 3))*8;
  int xr = (l16 & 3);
  int cnt = gCnt[e];
  int tokA[2]; float wA[2];
#pragma unroll
  for (int j=0;j<2;j++){
    int row = m0 + (w*2+j)*16 + srow;
    bool live = row < cnt;
    tokA[j] = live ? lTok[e*CAP_ + row] : 0;
    wA[j]   = live ? lW[e*CAP_ + row]   : 0.f;
  }
  const int nIt = 24;   // 768/32
  {
#pragma unroll
    for (int j=0;j<2;j++){
      const float* src = ln2 + (long)tokA[j]*D_ + gsw;
      float4 a0 = *(const float4*)(src);
      float4 a1 = *(const float4*)(src+4);
      union { bfrag f; bf16 h[8]; } o;
      o.h[0]=__float2bfloat16(a0.x*wA[j]); o.h[1]=__float2bfloat16(a0.y*wA[j]);
      o.h[2]=__float2bfloat16(a0.z*wA[j]); o.h[3]=__float2bfloat16(a0.w*wA[j]);
      o.h[4]=__float2bfloat16(a1.x*wA[j]); o.h[5]=__float2bfloat16(a1.y*wA[j]);
      o.h[6]=__float2bfloat16(a1.z*wA[j]); o.h[7]=__float2bfloat16(a1.w*wA[j]);
      *(bfrag*)(As[0] + (w*2+j)*512 + lane*8) = o.f;
    }
    int rowb = w*16 + srow;
    stage16(bBase + (long)rowb*768 + gsw, Bs[0] + w*512 + lane*8);
  }
  int cur = 0;
  for (int it=0; it<nIt; ++it){
    __syncthreads();
    float4 a0[2], a1[2];
    if (it+1 < nIt){
      int k0 = (it+1)*32;
#pragma unroll
      for (int j=0;j<2;j++){           // issue A loads early: latency hides under MFMA below
        const float* src = ln2 + (long)tokA[j]*D_ + k0 + gsw;
        a0[j] = *(const float4*)(src);
        a1[j] = *(const float4*)(src+4);
      }
      int rowb = w*16 + srow;
      stage16(bBase + (long)rowb*768 + k0 + gsw, Bs[cur^1] + w*512 + lane*8);
    }
    const bf16* Ac = As[cur];
    const bf16* Bc = Bs[cur];
    bfrag af[2], bfv[4];
#pragma unroll
    for (int t=0;t<2;t++) af[t]  = *(const bfrag*)(Ac + (wm + t*16 + l16)*32 + ((quad ^ xr)*8));
#pragma unroll
    for (int t=0;t<4;t++) bfv[t] = *(const bfrag*)(Bc + (t*16 + l16)*32 + ((quad ^ xr)*8));
#pragma unroll
    for (int ti=0;ti<2;ti++)
#pragma unroll
      for (int tj=0;tj<4;tj++)
        acc[ti][tj] = __builtin_amdgcn_mfma_f32_16x16x32_bf16(af[ti], bfv[tj], acc[ti][tj], 0, 0, 0);
    if (it+1 < nIt){
      int nb = cur^1;
#pragma unroll
      for (int j=0;j<2;j++){
        union { bfrag f; bf16 h[8]; } o;
        o.h[0]=__float2bfloat16(a0[j].x*wA[j]); o.h[1]=__float2bfloat16(a0[j].y*wA[j]);
        o.h[2]=__float2bfloat16(a0[j].z*wA[j]); o.h[3]=__float2bfloat16(a0[j].w*wA[j]);
        o.h[4]=__float2bfloat16(a1[j].x*wA[j]); o.h[5]=__float2bfloat16(a1[j].y*wA[j]);
        o.h[6]=__float2bfloat16(a1[j].z*wA[j]); o.h[7]=__float2bfloat16(a1[j].w*wA[j]);
        *(bfrag*)(As[nb] + (w*2+j)*512 + lane*8) = o.f;
      }
    }
    cur ^= 1;
  }
  bf16* Cb = C + (long)e*CAPP_*DFF_;
#pragma unroll
  for (int ti=0;ti<2;ti++)
#pragma unroll
    for (int tj=0;tj<4;tj++)
#pragma unroll
      for (int r=0;r<4;r++){
        int row = m0 + wm + ti*16 + quad*4 + r;
        int col = bx*64 + tj*16 + l16;
        Cb[(long)row*DFF_ + col] = __float2bfloat16(fmaxf(acc[ti][tj][r], 0.f));
      }
}

// ---------------- LayerNorm: fp32 in -> fp32 out (+ optional bf16 copy, + optional fused gate logits) ----------------
__global__ __launch_bounds__(256)
void ln_kernel(const float* __restrict__ src, const float* __restrict__ g, const float* __restrict__ bb,
               float* __restrict__ dstF, bf16* __restrict__ dstB,
               const float* __restrict__ gateW, float* __restrict__ glog2)
{
  int row = blockIdx.x, tid = threadIdx.x;
  __shared__ float red[256];
  __shared__ float gsum[4][E_];
  float v[3];
#pragma unroll
  for (int j=0;j<3;j++) v[j] = src[(long)row*D_ + tid + j*256];
  float s = v[0]+v[1]+v[2];
  red[tid]=s; __syncthreads();
  for (int o=128;o>0;o>>=1){ if(tid<o) red[tid]+=red[tid+o]; __syncthreads(); }
  float mean = red[0]*(1.0f/D_);
  __syncthreads();
  float sq = 0.f;
#pragma unroll
  for (int j=0;j<3;j++){ float d=v[j]-mean; sq += d*d; }
  red[tid]=sq; __syncthreads();
  for (int o=128;o>0;o>>=1){ if(tid<o) red[tid]+=red[tid+o]; __syncthreads(); }
  float rstd = rsqrtf(red[0]*(1.0f/D_) + 1e-5f);
  float ov[3];
#pragma unroll
  for (int j=0;j<3;j++){
    int d = tid + j*256;
    float o = (v[j]-mean)*rstd*g[d] + bb[d];
    ov[j] = o;
    dstF[(long)row*D_+d] = o;
    if (dstB) dstB[(long)row*D_+d] = __float2bfloat16(o);
  }
  if (gateW){
    float gp[E_] = {};
#pragma unroll
    for (int j=0;j<3;j++){
      int d = tid + j*256;
      const float* gw = gateW + (long)d*E_;
#pragma unroll
      for (int e=0;e<E_;e++) gp[e] += ov[j]*gw[e];
    }
#pragma unroll
    for (int off=1; off<64; off<<=1)
#pragma unroll
      for (int e=0;e<E_;e++) gp[e] += __shfl_xor(gp[e], off);
    if ((tid & 63) == 0)
#pragma unroll
      for (int e=0;e<E_;e++) gsum[tid>>6][e] = gp[e];
    __syncthreads();
    if (tid < E_)
      glog2[(long)row*E_ + tid] = gsum[0][tid]+gsum[1][tid]+gsum[2][tid]+gsum[3][tid];
  }
}

// ---------------- router logits + argmax + (h,e) bin build ----------------
#define RTOK 4
__global__ __launch_bounds__(768)
void router_argmax(const float* __restrict__ ln1, const float* __restrict__ WrT,
                   int* __restrict__ eidx, int* __restrict__ gHist,
                   int* __restrict__ hCnt, int* __restrict__ hList)
{
  int tok0 = blockIdx.x*RTOK;
  int tid = threadIdx.x;
  int col = tid >> 3, seg = tid & 7;     // col 0..95 (= h*8+e), seg 0..7
  __shared__ float xrow[RTOK][D_];
  __shared__ float logits[RTOK][96];
  for (int i=tid; i<RTOK*D_; i+=768){
    int t = i / D_, dpos = i - t*D_;
    xrow[t][dpos] = ln1[(long)(tok0+t)*D_ + dpos];
  }
  __syncthreads();
  const float* wrow = WrT + (long)col*D_;
  float acc[RTOK] = {};
#pragma unroll
  for (int j=0;j<24;j++){
    int dbase = j*32 + seg*4;
    float4 w = *(const float4*)(wrow + dbase);
#pragma unroll
    for (int t=0;t<RTOK;t++){
      float4 xv = *(const float4*)(&xrow[t][dbase]);
      acc[t] += xv.x*w.x + xv.y*w.y + xv.z*w.z + xv.w*w.w;
    }
  }
#pragma unroll
  for (int off=1; off<8; off<<=1)
#pragma unroll
    for (int t=0;t<RTOK;t++) acc[t] += __shfl_xor(acc[t], off);
  if (seg == 0)
#pragma unroll
    for (int t=0;t<RTOK;t++) logits[t][col] = acc[t];
  __syncthreads();
  if (tid < RTOK*H_){
    int t = tid / H_, h = tid % H_;
    const float* p = &logits[t][h*8];
    float best = p[0]; int bi = 0;
#pragma unroll
    for (int e=1;e<8;e++){ float v=p[e]; if (v > best){ best=v; bi=e; } }
    int tok = tok0 + t;
    eidx[tok*H_ + h] = bi;
    atomicAdd(&gHist[h*E_ + bi], 1);
    int he = h*E_ + bi;
    int pos = atomicAdd(&hCnt[he], 1);
    hList[he*NTOK + pos] = tok;
  }
}

// ---------------- binned V projection: one (h,e) per block.x, W in LDS, stream bin tokens ----------------
__global__ __launch_bounds__(256)
void vsel_b(const float* __restrict__ ln1, const float* __restrict__ Wv,
            const int* __restrict__ hCnt, const int* __restrict__ hList,
            bf16* __restrict__ vT)
{
  int he = blockIdx.x;             // h*E + e
  int h = he >> 3;
  __shared__ float Ws[DH_*DH_];    // 16 KB
  __shared__ float xsh[4][DH_];
  int tid = threadIdx.x;
  const float* W = Wv + (long)he*DH_*DH_;
  for (int i=tid; i<DH_*DH_; i+=256) Ws[i] = W[i];
  int cnt = hCnt[he];
  __syncthreads();
  int w = tid >> 6, lane = tid & 63;
  const int* lst = hList + (long)he*NTOK;
  for (int i = blockIdx.y*4 + w; i < cnt; i += 32){
    int tok = lst[i];
    int b = tok >> 10, s = tok & 1023;
    xsh[w][lane] = ln1[(long)tok*D_ + h*DH_ + lane];
    float acc = 0.f;
#pragma unroll 8
    for (int d=0; d<DH_; d++) acc += xsh[w][d]*Ws[d*DH_ + lane];
    vT[((long)(b*H_+h)*DH_ + lane)*S_ + s] = __float2bfloat16(acc);
  }
}

// ---------------- attention pass 1 (MFMA flash stats) + HOSTED W1/W2 transpose blocks ----------------
// grid (8,12,34): z<2 = attention (b=z); z>=2 = transpose job flat=(z-2)*96+y*8+x in [0,3072):
//   flat<1536:  W1[e] 768x2048 -> WT1[e] (2048x768), 32nx x 6ky per e
//   flat>=1536: W2[e] 2048x768 -> WT2[e] (768x2048), 12nx x 16ky per e
// Memory-only transpose blocks co-schedule with the 192 latency-bound MFMA blocks -> transpose rides
// the idle CUs instead of costing serial wall time. LDS aliased via one 32KB char pool; the two ldsK
// buffers are addressed arithmetically (smem+8192+cur*8192) — local arrays of LDS pointers don't lower.
__global__ __launch_bounds__(256)
void attn_stats_mfma(const bf16* __restrict__ qkB, float* __restrict__ gM, float* __restrict__ gL,
                     const float* __restrict__ W1, const float* __restrict__ W2,
                     bf16* __restrict__ WT1, bf16* __restrict__ WT2)
{
  __shared__ __align__(16) char smem[32768];
  int tid = threadIdx.x;
  if (blockIdx.z >= 2){
    int flat = (blockIdx.z - 2)*96 + blockIdx.y*8 + blockIdx.x;   // 0..3071
    const float* src; int N, K, bx, by; bf16* dst;
    if (flat < 1536){ int e = flat/192, r = flat - e*192;
      src = W1 + (long)e*768*2048; N = 2048; K = 768;  bx = r % 32; by = r / 32;
      dst = WT1 + (long)e*2048*768;
    } else { int f2 = flat - 1536; int e = f2/192, r = f2 - e*192;
      src = W2 + (long)e*2048*768; N = 768;  K = 2048; bx = r % 12; by = r / 12;
      dst = WT2 + (long)e*768*2048;
    }
    transp_tile_bf16(src, dst, N, K, bx*64, by*128, tid, (float(*)[64])smem);
    return;
  }
  bf16* ldsQ = (bf16*)smem;                 // 8 KB; K buffers at +8192, +16384 (computed per-use)
  int h = blockIdx.y, b = blockIdx.z;
  int w = tid >> 6, lane = tid & 63;
  int quad = lane >> 4, l16 = lane & 15;
  int x7 = l16 & 7;                    // read-side swizzle key (row&7 == l16&7)
  const bf16* kbase = qkB + ((long)(b*S_))*QKLD + 768 + h*DH_;
  for (int half=0; half<2; half++){
    int s0 = (half ? (S_/64 - 1 - blockIdx.x) : blockIdx.x)*64;   // bands x and 15-x: uniform 17 tiles
    __syncthreads();                 // protect LDS reuse across bands
    const bf16* qbase = qkB + ((long)(b*S_ + s0))*QKLD + h*DH_;
#pragma unroll
    for (int j=0;j<2;j++){
      int c = j*256 + tid;
      int row = c >> 3;
      int gs = ((c & 7) ^ (row & 7))*8;
      stage16(qbase + (long)row*QKLD + gs, ldsQ + c*8);
      stage16(kbase + (long)row*QKLD + gs, (bf16*)(smem + 8192) + c*8);   // tt=0 prefetch -> buf 0
    }
    float m_ln[4] = {-1e30f,-1e30f,-1e30f,-1e30f};
    float l_ln[4] = {0.f,0.f,0.f,0.f};
    int ttEnd = s0 >> 6;
    int cur = 0;
    for (int tt=0; tt<=ttEnd; tt++){
      __syncthreads();               // drains stage of buf[cur]
      if (tt < ttEnd){
        bf16* Kn = (bf16*)(smem + 8192 + ((cur^1) << 13));
#pragma unroll
        for (int j=0;j<2;j++){
          int c = j*256 + tid;
          int row = c >> 3;
          int gs = ((c & 7) ^ (row & 7))*8;
          stage16(kbase + (long)((tt+1)*64 + row)*QKLD + gs, Kn + c*8);
        }
      }
      const bf16* Kc = (const bf16*)(smem + 8192 + (cur << 13));
      bfrag af0 = *(const bfrag*)(ldsQ + (w*16 + l16)*64 + ((quad     ^ x7)*8));
      bfrag af1 = *(const bfrag*)(ldsQ + (w*16 + l16)*64 + (((quad+4) ^ x7)*8));
      f32x4 cfr[4];
#pragma unroll
      for (int j=0;j<4;j++){
        bfrag b0 = *(const bfrag*)(Kc + (j*16 + l16)*64 + ((quad     ^ x7)*8));
        bfrag b1 = *(const bfrag*)(Kc + (j*16 + l16)*64 + (((quad+4) ^ x7)*8));
        f32x4 z = {};
        z = __builtin_amdgcn_mfma_f32_16x16x32_bf16(af0, b0, z, 0,0,0);
        z = __builtin_amdgcn_mfma_f32_16x16x32_bf16(af1, b1, z, 0,0,0);
        cfr[j] = z;
      }
      // lane-local online update; garbage from all-masked lanes flushed at the final reduce.
#pragma unroll
      for (int r=0;r<4;r++){
        int s_g = s0 + w*16 + quad*4 + r;
        float v0 = (tt*64      + l16 <= s_g) ? cfr[0][r]*0.125f : -1e30f;
        float v1 = (tt*64 + 16 + l16 <= s_g) ? cfr[1][r]*0.125f : -1e30f;
        float v2 = (tt*64 + 32 + l16 <= s_g) ? cfr[2][r]*0.125f : -1e30f;
        float v3 = (tt*64 + 48 + l16 <= s_g) ? cfr[3][r]*0.125f : -1e30f;
        float mt = fmaxf(fmaxf(v0,v1), fmaxf(v2,v3));
        float mn = fmaxf(m_ln[r], mt);
        l_ln[r] = l_ln[r]*__expf(m_ln[r]-mn)
                + ((__expf(v0-mn)+__expf(v1-mn)) + (__expf(v2-mn)+__expf(v3-mn)));
        m_ln[r] = mn;
      }
      cur ^= 1;
    }
    // deferred cross-lane reduction (once per band)
#pragma unroll
    for (int r=0;r<4;r++){
      float mf = m_ln[r];
#pragma unroll
      for (int mm=1; mm<16; mm<<=1) mf = fmaxf(mf, __shfl_xor(mf, mm));
      float lf = l_ln[r]*__expf(m_ln[r]-mf);
#pragma unroll
      for (int mm=1; mm<16; mm<<=1) lf += __shfl_xor(lf, mm);
      if (l16 == 0){
        long basei = ((long)(b*H_ + h))*S_ + s0 + w*16 + quad*4 + r;
        gM[basei] = mf; gL[basei] = lf;
      }
    }
  }
}

// ---------------- attention pass 2 (fused MFMA, transposed einsum), PAIRED bands + dbuf Q/V ----------------
__global__ __launch_bounds__(256)
void attn_pv(const bf16* __restrict__ qkB, const bf16* __restrict__ vT,
             const float* __restrict__ gM, const float* __restrict__ gL, float* __restrict__ aoH)
{
  int h = blockIdx.y, b = blockIdx.z;
  int bh = b*H_ + h;
  int tid = threadIdx.x;
  int w = tid >> 6, lane = tid & 63;
  int quad = lane >> 4, l16 = lane & 15;
  int x7 = l16 & 7;
  __shared__ bf16 ldsK[64*64];
  __shared__ bf16 ldsQ[2][64*64];
  __shared__ bf16 ldsV[2][64*64];
  __shared__ bf16 ldsS[64*72];        // +8 pad; wave-band-private
  __shared__ float smx[2][64], sli[2][64];
  const bf16* qbase = qkB + ((long)(b*S_))*QKLD + h*DH_;
  const bf16* vbase = vT + ((long)bh*DH_)*S_;
  for (int half=0; half<2; half++){
    int t0 = (half ? (S_/64 - 1 - blockIdx.x) : blockIdx.x)*64;   // paired bands: uniform 17 tiles/block
    __syncthreads();                 // protect LDS reuse across bands
    const bf16* kbase = qkB + ((long)(b*S_ + t0))*QKLD + 768 + h*DH_;
    int sb0 = t0 >> 6;
#pragma unroll
    for (int j=0;j<2;j++){
      int c = j*256 + tid;
      int row = c >> 3;
      int gs = ((c & 7) ^ (row & 7))*8;
      stage16(kbase + (long)row*QKLD + gs, ldsK + c*8);
      stage16(qbase + (long)(sb0*64 + row)*QKLD + gs, ldsQ[0] + c*8);
      stage16(vbase + (long)row*S_ + sb0*64 + gs, ldsV[0] + c*8);
    }
    if (tid < 64){
      smx[0][tid] = gM[(long)bh*S_ + sb0*64 + tid];
      sli[0][tid] = 1.0f / gL[(long)bh*S_ + sb0*64 + tid];
    }
    f32x4 accO[4] = {};
    int cur = 0;
    for (int sb = sb0; sb < S_/64; sb++){
      __syncthreads();
      if (sb+1 < S_/64){
        int nb = cur^1;
#pragma unroll
        for (int j=0;j<2;j++){
          int c = j*256 + tid;
          int row = c >> 3;
          int gs = ((c & 7) ^ (row & 7))*8;
          stage16(qbase + (long)((sb+1)*64 + row)*QKLD + gs, ldsQ[nb] + c*8);
          stage16(vbase + (long)row*S_ + (sb+1)*64 + gs, ldsV[nb] + c*8);
        }
        if (tid < 64){
          smx[nb][tid] = gM[(long)bh*S_ + (sb+1)*64 + tid];
          sli[nb][tid] = 1.0f / gL[(long)bh*S_ + (sb+1)*64 + tid];
        }
      }
      const bf16* Qc = ldsQ[cur];
      const bf16* Vc = ldsV[cur];
      bfrag af0 = *(const bfrag*)(ldsK + (w*16 + l16)*64 + ((quad     ^ x7)*8));
      bfrag af1 = *(const bfrag*)(ldsK + (w*16 + l16)*64 + (((quad+4) ^ x7)*8));
      f32x4 cs[4];
#pragma unroll
      for (int j=0;j<4;j++){
        bfrag b0 = *(const bfrag*)(Qc + (j*16 + l16)*64 + ((quad     ^ x7)*8));
        bfrag b1 = *(const bfrag*)(Qc + (j*16 + l16)*64 + (((quad+4) ^ x7)*8));
        f32x4 z = {};
        z = __builtin_amdgcn_mfma_f32_16x16x32_bf16(af0, b0, z, 0,0,0);
        z = __builtin_amdgcn_mfma_f32_16x16x32_bf16(af1, b1, z, 0,0,0);
        cs[j] = z;
      }
#pragma unroll
      for (int j=0;j<4;j++)
#pragma unroll
        for (int r=0;r<4;r++){
          int t_loc = w*16 + quad*4 + r;
          int s_loc = j*16 + l16;
          float wgt = ((t0 + t_loc) <= (sb*64 + s_loc))
                    ? __expf(cs[j][r]*0.125f - smx[cur][s_loc])*sli[cur][s_loc] : 0.f;
          ldsS[t_loc*72 + s_loc] = __float2bfloat16(wgt);
        }
      bfrag pa0 = *(const bfrag*)(ldsS + (w*16 + l16)*72 + quad*8);
      bfrag pa1 = *(const bfrag*)(ldsS + (w*16 + l16)*72 + 32 + quad*8);
#pragma unroll
      for (int j=0;j<4;j++){
        bfrag b0 = *(const bfrag*)(Vc + (j*16 + l16)*64 + ((quad     ^ x7)*8));
        bfrag b1 = *(const bfrag*)(Vc + (j*16 + l16)*64 + (((quad+4) ^ x7)*8));
        accO[j] = __builtin_amdgcn_mfma_f32_16x16x32_bf16(pa0, b0, accO[j], 0,0,0);
        accO[j] = __builtin_amdgcn_mfma_f32_16x16x32_bf16(pa1, b1, accO[j], 0,0,0);
      }
      cur ^= 1;
    }
#pragma unroll
    for (int j=0;j<4;j++)
#pragma unroll
      for (int r=0;r<4;r++){
        int t_loc = w*16 + quad*4 + r;
        int f = j*16 + l16;
        aoH[((long)bh*S_ + t0 + t_loc)*DH_ + f] = accO[j][r];
      }
  }
}

// ---------------- binned O projection + residual: one (h,e) per block.x, W in LDS ----------------
__global__ __launch_bounds__(256)
void oproj_b(const float* __restrict__ aoH, const float* __restrict__ Wo,
             const int* __restrict__ hCnt, const int* __restrict__ hList,
             const float* __restrict__ x, float* __restrict__ x1)
{
  int he = blockIdx.x;             // h*E + e
  int h = he >> 3;
  __shared__ float Ws[DH_*DH_];    // 16 KB
  __shared__ float xsh[4][DH_];
  int tid = threadIdx.x;
  const float* W = Wo + (long)he*DH_*DH_;
  for (int i=tid; i<DH_*DH_; i+=256) Ws[i] = W[i];
  int cnt = hCnt[he];
  __syncthreads();
  int w = tid >> 6, lane = tid & 63;
  const int* lst = hList + (long)he*NTOK;
  for (int i = blockIdx.y*4 + w; i < cnt; i += 32){
    int tok = lst[i];
    int b = tok >> 10, s = tok & 1023;
    xsh[w][lane] = aoH[((long)(b*H_+h)*S_ + s)*DH_ + lane];
    float acc = 0.f;
#pragma unroll 8
    for (int f=0; f<DH_; f++) acc += xsh[w][f]*Ws[f*DH_ + lane];
    long idx = (long)tok*D_ + h*DH_ + lane;
    x1[idx] = x[idx] + acc;
  }
}

// ---------------- MoE routing: top-2, PARALLEL capacity prefix-scan, lists, aux losses ----------------
__global__ __launch_bounds__(256)
void route_kernel(const float* __restrict__ glog2, const int* __restrict__ gHist,
                  int* __restrict__ gI0, int* __restrict__ gI1,
                  int* __restrict__ gPos0, int* __restrict__ gPos1,
                  int* __restrict__ listTok, float* __restrict__ listW,
                  int* __restrict__ gCnt, float* __restrict__ auxOut)
{
  __shared__ unsigned char sI0[NTOK], sI1[NTOK];
  __shared__ float sP0[NTOK], sP1[NTOK];
  __shared__ short sPos0[NTOK], sPos1[NTOK];
  __shared__ int   sScan[256*E_];
  __shared__ int   sHist[H_*E_];
  __shared__ float sImp[E_];
  __shared__ int   sCnt[E_];
  int tid = threadIdx.x;
  if (tid < E_) sImp[tid] = 0.f;
  if (tid < H_*E_) sHist[tid] = gHist[tid];
  for (int i=tid; i<NTOK; i+=256){
    const float* p = glog2 + (long)i*E_;
    float b0 = p[0]; int e0 = 0;
#pragma unroll
    for (int e=1;e<E_;e++){ float vv=p[e]; if (vv > b0){ b0=vv; e0=e; } }
    float b1v = -1e30f; int e1 = 0;
#pragma unroll
    for (int e=0;e<E_;e++){ if (e==e0) continue; float vv=p[e]; if (vv > b1v){ b1v=vv; e1=e; } }
    float ex = __expf(b1v - b0);
    float inv = 1.f/(1.f + ex);
    sI0[i] = (unsigned char)e0; sI1[i] = (unsigned char)e1;
    sP0[i] = inv; sP1[i] = ex*inv;
    gI0[i] = e0; gI1[i] = e1;
  }
  __syncthreads();
  {
    int myCnt[E_] = {};
#pragma unroll
    for (int j=0;j<16;j++){
      int i = tid*16 + j;
      int tok = i >> 1;
      int e = (i & 1) ? (int)sI1[tok] : (int)sI0[tok];
      myCnt[e]++;
    }
#pragma unroll
    for (int e=0;e<E_;e++) sScan[tid*E_+e] = myCnt[e];
    __syncthreads();
    for (int off=1; off<256; off<<=1){
      int v[E_];
      if (tid >= off){
#pragma unroll
        for (int e=0;e<E_;e++) v[e] = sScan[(tid-off)*E_+e];
      }
      __syncthreads();
      if (tid >= off){
#pragma unroll
        for (int e=0;e<E_;e++) sScan[tid*E_+e] += v[e];
      }
      __syncthreads();
    }
    int pref[E_];
#pragma unroll
    for (int e=0;e<E_;e++) pref[e] = tid ? sScan[(tid-1)*E_+e] : 0;
#pragma unroll
    for (int j=0;j<16;j++){
      int i = tid*16 + j;
      int tok = i >> 1;
      int e = (i & 1) ? (int)sI1[tok] : (int)sI0[tok];
      int pos = pref[e]++;
      short p = (pos < CAP_) ? (short)pos : (short)-1;
      if (i & 1) sPos1[tok] = p; else sPos0[tok] = p;
    }
    if (tid < E_){
      int cnt = sScan[255*E_ + tid];
      sCnt[tid] = cnt < CAP_ ? cnt : CAP_;
      gCnt[tid] = sCnt[tid];
    }
  }
  __syncthreads();
  for (int i=tid; i<NTOK; i+=256){
    int e0 = sI0[i], e1 = sI1[i];
    int p0i = sPos0[i], p1i = sPos1[i];
    float k0 = p0i >= 0 ? 1.f : 0.f, k1 = p1i >= 0 ? 1.f : 0.f;
    float p0 = sP0[i], p1 = sP1[i];
    float denom = p0*k0 + p1*k1 + 1e-9f;
    float w0 = p0*k0/denom, w1 = p1*k1/denom;
    if (p0i >= 0){ listTok[e0*CAP_+p0i] = i; listW[e0*CAP_+p0i] = w0; atomicAdd(&sImp[e0], w0); }
    if (p1i >= 0){ listTok[e1*CAP_+p1i] = i; listW[e1*CAP_+p1i] = w1; atomicAdd(&sImp[e1], w1); }
    gPos0[i] = p0i; gPos1[i] = p1i;
  }
  __syncthreads();
  if (tid == 0){
    float tot = 0.f;
    for (int i=0;i<H_*E_;i++) tot += (float)sHist[i]*(1.0f/NTOK)*0.01f;
    float a1 = 0.f;
    for (int i=0;i<H_*E_;i++){
      float p = ((float)sHist[i]*(1.0f/NTOK)*0.01f)/(tot + 1e-9f);
      a1 += p*p;
    }
    a1 *= (float)(H_*E_);
    float tcs = 0.f, ims = 0.f;
    for (int e=0;e<E_;e++){ tcs += (float)sCnt[e]; ims += sImp[e]; }
    float a2 = 0.f;
    for (int e=0;e<E_;e++) a2 += ((float)sCnt[e]/tcs)*(sImp[e]/ims);
    a2 *= (float)E_;
    auxOut[0] = a1 + a2;
  }
}

// ---------------- final combine: out = x1 + expert contributions (2 split-K slices, fp32) ----------------
__global__ __launch_bounds__(256)
void combine_kernel(const float* __restrict__ x1,
                    const float* __restrict__ Ya, const float* __restrict__ Yb,
                    const int* __restrict__ gI0, const int* __restrict__ gI1,
                    const int* __restrict__ gPos0, const int* __restrict__ gPos1,
                    float* __restrict__ out)
{
  int i = blockIdx.x;
  int tid = threadIdx.x;
  int p0 = gPos0[i], p1 = gPos1[i];
  int e0 = gI0[i],  e1 = gI1[i];
  long off0 = (long)(e0*CAPP_ + (p0 >= 0 ? p0 : 0))*D_;
  long off1 = (long)(e1*CAPP_ + (p1 >= 0 ? p1 : 0))*D_;
  const float* y0a = Ya + off0; const float* y0b = Yb + off0;
  const float* y1a = Ya + off1; const float* y1b = Yb + off1;
  for (int d=tid; d<D_; d+=256){
    float v = x1[(long)i*D_+d];
    if (p0 >= 0) v += y0a[d] + y0b[d];
    if (p1 >= 0) v += y1a[d] + y1b[d];
    out[(long)i*D_+d] = v;
  }
}

extern "C" void kernel_launch(void* const* d_in, const int* in_sizes, int n_in,
                              void* d_out, int out_size, void* d_ws, size_t ws_size,
                              hipStream_t stream)
{
  const float* x    = (const float*)d_in[0];
  const float* W_q  = (const float*)d_in[2];
  const float* W_k  = (const float*)d_in[3];
  const float* W_v  = (const float*)d_in[4];
  const float* W_o  = (const float*)d_in[5];
  const float* W_r  = (const float*)d_in[6];
  const float* g1   = (const float*)d_in[7];
  const float* b1   = (const float*)d_in[8];
  const float* g2   = (const float*)d_in[9];
  const float* b2   = (const float*)d_in[10];
  const float* gate = (const float*)d_in[11];
  const float* W1   = (const float*)d_in[12];
  const float* W2   = (const float*)d_in[13];
  float* out = (float*)d_out;

  float* wsf = (float*)d_ws;
  // ---- workspace layout (float slots) ----
  const long oX1   = 0;          // 1,572,864
  const long oLnF  = 1572864;    // fp32 2048x768; live through gemm_ffn1, then reused as split-K slice 1
  const long oLnB  = 3145728;    // bf16 2048x768
  const long oWcat = 3932160;    // bf16 1536x768 (ends 4521984)
  const long oWrT  = 4521984;    // fp32 96x768 = 73,728 (ends 4595712)
  const long oHist = 4595712;    // int 96 (attention (h,e) histogram)
  const long oHCnt = 4595808;    // int 96 ((h,e) bin counters) - adjacent: one memset covers both
  const long oGM   = 4718592;    // 24,576
  const long oGL   = 4743168;    // 24,576
  const long oEidx = 4767744;    // int 24,576
  const long oGlg2 = 4792320;    // 16,384
  const long oI0   = 4808704;
  const long oI1   = 4810752;
  const long oP0   = 4812800;
  const long oP1   = 4814848;
  const long oLT   = 4816896;
  const long oLW   = 4819456;
  const long oCnt  = 4822016;    // 8 ints
  const long SB    = 4822528;    // shared overlay region
  // attention view: qkB bf16 @SB (1.57M) | vT bf16 @+1,572,864 | aoH fp32 @+2,359,296 |
  //                 hList int @+3,932,160 (96*2048)
  // FFN view:       Hid @+7,471,104 | Yexp fp32 @+10,616,832
  const long oWT1  = SB + 12976128;      // bf16 8 x 2048x768 (6,291,456 fl) - dedicated, no overlay
  const long oWT2  = oWT1 + 6291456;     // bf16 8 x 768x2048 (6,291,456 fl)
  const long TOTAL = oWT2 + 6291456;     // 30,381,568 floats = 121.5 MB
  if (ws_size < (size_t)TOTAL*4) return;

  float* x1    = wsf + oX1;
  float* lnbF  = wsf + oLnF;
  bf16*  lnbB  = (bf16*)(wsf + oLnB);
  bf16*  WcatB = (bf16*)(wsf + oWcat);
  float* WrT   = wsf + oWrT;
  int*   gHist = (int*)(wsf + oHist);
  int*   hCnt  = (int*)(wsf + oHCnt);
  float* gM    = wsf + oGM;
  float* gL    = wsf + oGL;
  int*   eidx  = (int*)(wsf + oEidx);
  float* glog2 = wsf + oGlg2;
  int*   gI0   = (int*)(wsf + oI0);
  int*   gI1   = (int*)(wsf + oI1);
  int*   gPos0 = (int*)(wsf + oP0);
  int*   gPos1 = (int*)(wsf + oP1);
  int*   lTok  = (int*)(wsf + oLT);
  float* lW    = wsf + oLW;
  int*   gCnt  = (int*)(wsf + oCnt);
  bf16*  qkB   = (bf16*)(wsf + SB);
  bf16*  vT    = (bf16*)(wsf + SB + 1572864);
  float* aoH   = wsf + SB + 2359296;
  int*   hList = (int*)(wsf + SB + 3932160);
  bf16*  Hid   = (bf16*)(wsf + SB + 7471104);
  float* Yexp  = wsf + SB + 10616832;
  float* YexpB = wsf + oLnF;     // split-K slice 1: lnF region, dead once gemm_ffn1 completes
  bf16*  WT1   = (bf16*)(wsf + oWT1);
  bf16*  WT2   = (bf16*)(wsf + oWT2);

  // ---- counter zero + immediate-needs weight prep (Wq/Wk/Wr only; W1/W2 hosted in attn_stats) ----
  (void)hipMemsetAsync(gHist, 0, 2*NHE*sizeof(int), stream);
  transp_qkr<<<180,256,0,stream>>>(W_q, W_k, W_r, WcatB, WrT);

  // ---- attention phase ----
  ln_kernel<<<NTOK,256,0,stream>>>(x, g1, b1, lnbF, lnbB, nullptr, nullptr);
  gemm_bn64<<<dim3(24,16,1),256,0,stream>>>(lnbB, WcatB, qkB, nullptr, 2048, QKLD, 768, 0,0,0, 0, 1, 1);
  router_argmax<<<NTOK/RTOK,768,0,stream>>>(lnbF, WrT, eidx, gHist, hCnt, hList);
  vsel_b<<<dim3(NHE,8,1),256,0,stream>>>(lnbF, W_v, hCnt, hList, vT);
  // z 0..1 = attention; z 2..33 = hosted W1/W2 transposes (3072 blocks riding idle CUs)
  attn_stats_mfma<<<dim3(S_/128,H_,2+32),256,0,stream>>>(qkB, gM, gL, W1, W2, WT1, WT2);
  attn_pv<<<dim3(S_/128,H_,B_),256,0,stream>>>(qkB, vT, gM, gL, aoH);
  oproj_b<<<dim3(NHE,8,1),256,0,stream>>>(aoH, W_o, hCnt, hList, x, x1);

  // ---- FFN phase (gather fused into W1 GEMM; WT1/WT2 ready since attn_stats) ----
  ln_kernel<<<NTOK,256,0,stream>>>(x1, g2, b2, lnbF, nullptr, gate, glog2);  // fused gate logits
  route_kernel<<<1,256,0,stream>>>(glog2, gHist, gI0,gI1,gPos0,gPos1, lTok,lW,gCnt, out + (size_t)NTOK*D_);
  gemm_ffn1<<<dim3(32,3,8),256,0,stream>>>(lnbF, WT1, Hid, lTok, lW, gCnt);
  gemm_bn64<<<dim3(12,3,16),256,0,stream>>>(Hid, WT2, Yexp, YexpB, CAPP_, 768, 2048,
                                            (long)CAPP_*2048, (long)768*2048, (long)CAPP_*768, 0, 0, 2);
  combine_kernel<<<NTOK,256,0,stream>>>(x1, Yexp, YexpB, gI0,gI1,gPos0,gPos1, out);
}

// Round 9
// 381.440 us; speedup vs baseline: 1.0371x; 1.0019x over previous
//
#include <hip/hip_runtime.h>
#include <hip/hip_bf16.h>
#include <cstdint>

typedef __hip_bfloat16 bf16;
typedef __attribute__((ext_vector_type(8))) __bf16 bfrag;   // MFMA A/B operand (4 VGPRs)
typedef __attribute__((ext_vector_type(4))) float f32x4;    // MFMA C/D operand

#define B_    2
#define S_    1024
#define D_    768
#define H_    12
#define E_    8
#define DH_   64
#define DFF_  2048
#define CAP_  320            // ceil(1.25 * 2048 / 8)
#define CAPP_ 384            // CAP padded to 128-multiple for MFMA tiles
#define NTOK  (B_*S_)        // 2048
#define NTH   (NTOK*H_)      // 24576
#define QKLD  1536           // fused q|k row stride
#define NHE   (H_*E_)        // 96 (h,e) bins

// ---------------- async global->LDS 16B stage (per-lane global addr, lane-linear LDS) ----------------
__device__ __forceinline__ void stage16(const bf16* g, bf16* ldsLane){
#if __has_builtin(__builtin_amdgcn_global_load_lds)
  __builtin_amdgcn_global_load_lds((const __attribute__((address_space(1))) unsigned int*)g,
                                   (__attribute__((address_space(3))) unsigned int*)ldsLane, 16, 0, 0);
#else
  *(bfrag*)ldsLane = *(const bfrag*)g;
#endif
}

// ---------------- shared transpose tile body: 64n x 128k, XOR-swizzled LDS, 256B write runs ----------------
// t: 128x64 fp32 LDS tile. logical (row,col) stored at col' = col ^ (((row>>3)&15)*4).
__device__ __forceinline__ void transp_tile_bf16(const float* __restrict__ src, bf16* __restrict__ dst,
                                                 int N, int K, int n0, int k0, int tid, float (*t)[64])
{
  int chunk = tid & 15, rgrp = tid >> 4;
#pragma unroll
  for (int rr=0; rr<8; rr++){
    int row = rr*16 + rgrp;
    float4 v = *(const float4*)(src + (long)(k0+row)*N + n0 + chunk*4);
    *(float4*)&t[row][((chunk ^ (row>>3)) & 15)*4] = v;
  }
  __syncthreads();
#pragma unroll
  for (int it=0; it<4; it++){
    int slot = it*256 + tid;
    int n = slot >> 4, kc = slot & 15;      // 16 lanes (kc 0..15) cover one full 128-bf16 output row
    union { bfrag f; bf16 h[8]; } o;
#pragma unroll
    for (int i=0;i<8;i++){
      int row = kc*8 + i;                   // (row>>3)&15 == kc
      o.h[i] = __float2bfloat16(t[row][n ^ (kc*4)]);
    }
    *(bfrag*)(dst + (long)(n0+n)*K + k0 + kc*8) = o.f;
  }
}

// ---------------- Wq|Wk|Wr prep (needed immediately): 180 blocks ----------------
//   [0,72)    Wq 768x768 -> WcatB rows 0..767     (12nx x 6ky)
//   [72,144)  Wk 768x768 -> WcatB rows 768..1535
//   [144,180) Wr 768x96  -> WrT fp32 (64k x 32n tiles)
__global__ __launch_bounds__(256)
void transp_qkr(const float* __restrict__ Wq, const float* __restrict__ Wk,
                const float* __restrict__ Wr, bf16* __restrict__ WcatB, float* __restrict__ WrT)
{
  __shared__ float t[128][64];
  int bid = blockIdx.x, tid = threadIdx.x;
  if (bid < 144){
    const float* src; bf16* dst; int r;
    if (bid < 72){ src = Wq; dst = WcatB; r = bid; }
    else         { src = Wk; dst = WcatB + (long)768*768; r = bid - 72; }
    transp_tile_bf16(src, dst, 768, 768, (r%12)*64, (r/12)*128, tid, t);
  } else {
    int r = bid - 144;
    int n0 = (r % 3)*32, k0 = (r / 3)*64;
    int chunk = tid & 7, row2 = tid >> 3;
#pragma unroll
    for (int rr=0; rr<2; rr++){
      int row = rr*32 + row2;
      float4 v = *(const float4*)(Wr + (long)(k0+row)*96 + n0 + chunk*4);
      *(float4*)&t[row][chunk*4] = v;
    }
    __syncthreads();
    int chunkw = tid & 15, ng = tid >> 4;
#pragma unroll
    for (int rr=0; rr<2; rr++){
      int n = rr*16 + ng;
      float4 o;
      o.x = t[chunkw*4+0][n]; o.y = t[chunkw*4+1][n];
      o.z = t[chunkw*4+2][n]; o.w = t[chunkw*4+3][n];
      *(float4*)(WrT + (long)(n0+n)*768 + k0 + chunkw*4) = o;
    }
  }
}

// ---------------- MFMA GEMM, 128x64 tile, xor-swizzled LDS, XCD-chunked swizzle, split-K, 2-phase dbuf ----------------
__global__ __launch_bounds__(256)
void gemm_bn64(const bf16* __restrict__ A, const bf16* __restrict__ Bt,
               void* __restrict__ C, void* __restrict__ C2,
               int M, int N, int K, long sA, long sB, long sC, int relu, int outBf, int kSplit)
{
  int nwg = gridDim.x*gridDim.y*gridDim.z;
  int bid = blockIdx.x + gridDim.x*(blockIdx.y + gridDim.y*blockIdx.z);
  int nid = (bid & 7)*(nwg >> 3) + (bid >> 3);        // bijective: nwg % 8 == 0 at all call sites
  int bx = nid % gridDim.x;
  int t1 = nid / gridDim.x;
  int by = t1 % gridDim.y;
  int bz = t1 / gridDim.y;
  int e  = bz / kSplit, kc = bz - e*kSplit;
  A  += (long)e*sA;
  Bt += (long)e*sB;
  int kLen = K / kSplit, kBase = kc*kLen;
  int m0 = by*128, n0 = bx*64;
  __shared__ bf16 As[2][128*32];   // 2 x 8 KB
  __shared__ bf16 Bs[2][64*32];    // 2 x 4 KB
  int tid = threadIdx.x;
  int w = tid >> 6, lane = tid & 63;
  int quad = lane >> 4, l16 = lane & 15;
  int wm = w*32;
  f32x4 acc[2][4] = {};
  int srow = (lane >> 2);          // row within 16-row chunk
  int gsw  = ((lane & 3) ^ (srow & 3))*8;   // swizzled col group (8 bf16)
  const bf16* aBase = A + (long)m0*K;
  const bf16* bBase = Bt + (long)n0*K;
  int xr = (l16 & 3);              // read-side swizzle key (row&3 == l16&3)
  int nIt = kLen >> 5;
  {
    int k0 = kBase;
#pragma unroll
    for (int j=0;j<2;j++){
      int c = w*2 + j, row = c*16 + srow;
      stage16(aBase + (long)row*K + k0 + gsw, As[0] + c*512 + lane*8);
    }
    int rowb = w*16 + srow;
    stage16(bBase + (long)rowb*K + k0 + gsw, Bs[0] + w*512 + lane*8);
  }
  int cur = 0;
  for (int it=0; it<nIt; ++it){
    __syncthreads();               // drains stage of buf[cur]
    if (it+1 < nIt){               // prefetch next k-step into buf[cur^1]
      int k0 = kBase + (it+1)*32;
      int nb = cur^1;
#pragma unroll
      for (int j=0;j<2;j++){
        int c = w*2 + j, row = c*16 + srow;
        stage16(aBase + (long)row*K + k0 + gsw, As[nb] + c*512 + lane*8);
      }
      int rowb = w*16 + srow;
      stage16(bBase + (long)rowb*K + k0 + gsw, Bs[nb] + w*512 + lane*8);
    }
    const bf16* Ac = As[cur];
    const bf16* Bc = Bs[cur];
    bfrag af[2], bfv[4];
#pragma unroll
    for (int t=0;t<2;t++) af[t]  = *(const bfrag*)(Ac + (wm + t*16 + l16)*32 + ((quad ^ xr)*8));
#pragma unroll
    for (int t=0;t<4;t++) bfv[t] = *(const bfrag*)(Bc + (t*16 + l16)*32 + ((quad ^ xr)*8));
#pragma unroll
    for (int ti=0;ti<2;ti++)
#pragma unroll
      for (int tj=0;tj<4;tj++)
        acc[ti][tj] = __builtin_amdgcn_mfma_f32_16x16x32_bf16(af[ti], bfv[tj], acc[ti][tj], 0, 0, 0);
    cur ^= 1;
  }
  long zoff = (long)e*sC;
  void* Cp = kc ? C2 : C;
  if (outBf){
    bf16* Cb = (bf16*)Cp + zoff;
#pragma unroll
    for (int ti=0;ti<2;ti++)
#pragma unroll
      for (int tj=0;tj<4;tj++)
#pragma unroll
        for (int r=0;r<4;r++){
          int row = m0 + wm + ti*16 + quad*4 + r;
          int col = n0 + tj*16 + l16;
          float v = acc[ti][tj][r];
          if (relu) v = fmaxf(v, 0.f);
          Cb[(long)row*N + col] = __float2bfloat16(v);
        }
  } else {
    float* Cf = (float*)Cp + zoff;
#pragma unroll
    for (int ti=0;ti<2;ti++)
#pragma unroll
      for (int tj=0;tj<4;tj++)
#pragma unroll
        for (int r=0;r<4;r++){
          int row = m0 + wm + ti*16 + quad*4 + r;
          int col = n0 + tj*16 + l16;
          float v = acc[ti][tj][r];
          if (relu) v = fmaxf(v, 0.f);
          Cf[(long)row*N + col] = v;
        }
  }
}

// ---------------- W1 GEMM with FUSED gather: A reg-staged from fp32 ln2 via token list ----------------
__global__ __launch_bounds__(256)
void gemm_ffn1(const float* __restrict__ ln2, const bf16* __restrict__ Bt, bf16* __restrict__ C,
               const int* __restrict__ lTok, const float* __restrict__ lW, const int* __restrict__ gCnt)
{
  int nwg = gridDim.x*gridDim.y*gridDim.z;   // 32*3*8 = 768
  int bid = blockIdx.x + gridDim.x*(blockIdx.y + gridDim.y*blockIdx.z);
  int nid = (bid & 7)*(nwg >> 3) + (bid >> 3);
  int bx = nid % gridDim.x;
  int t1 = nid / gridDim.x;
  int by = t1 % gridDim.y;
  int e  = t1 / gridDim.y;
  int m0 = by*128;
  const bf16* bBase = Bt + (long)e*2048*768 + (long)(bx*64)*768;
  __shared__ bf16 As[2][128*32];
  __shared__ bf16 Bs[2][64*32];
  int tid = threadIdx.x;
  int w = tid >> 6, lane = tid & 63;
  int quad = lane >> 4, l16 = lane & 15;
  int wm = w*32;
  f32x4 acc[2][4] = {};
  int srow = (lane >> 2);
  int gsw  = ((lane & 3) ^ (srow & 3))*8;
  int xr = (l16 & 3);
  int cnt = gCnt[e];
  int tokA[2]; float wA[2];
#pragma unroll
  for (int j=0;j<2;j++){
    int row = m0 + (w*2+j)*16 + srow;
    bool live = row < cnt;
    tokA[j] = live ? lTok[e*CAP_ + row] : 0;
    wA[j]   = live ? lW[e*CAP_ + row]   : 0.f;
  }
  const int nIt = 24;   // 768/32
  {
#pragma unroll
    for (int j=0;j<2;j++){
      const float* src = ln2 + (long)tokA[j]*D_ + gsw;
      float4 a0 = *(const float4*)(src);
      float4 a1 = *(const float4*)(src+4);
      union { bfrag f; bf16 h[8]; } o;
      o.h[0]=__float2bfloat16(a0.x*wA[j]); o.h[1]=__float2bfloat16(a0.y*wA[j]);
      o.h[2]=__float2bfloat16(a0.z*wA[j]); o.h[3]=__float2bfloat16(a0.w*wA[j]);
      o.h[4]=__float2bfloat16(a1.x*wA[j]); o.h[5]=__float2bfloat16(a1.y*wA[j]);
      o.h[6]=__float2bfloat16(a1.z*wA[j]); o.h[7]=__float2bfloat16(a1.w*wA[j]);
      *(bfrag*)(As[0] + (w*2+j)*512 + lane*8) = o.f;
    }
    int rowb = w*16 + srow;
    stage16(bBase + (long)rowb*768 + gsw, Bs[0] + w*512 + lane*8);
  }
  int cur = 0;
  for (int it=0; it<nIt; ++it){
    __syncthreads();
    float4 a0[2], a1[2];
    if (it+1 < nIt){
      int k0 = (it+1)*32;
#pragma unroll
      for (int j=0;j<2;j++){           // issue A loads early: latency hides under MFMA below
        const float* src = ln2 + (long)tokA[j]*D_ + k0 + gsw;
        a0[j] = *(const float4*)(src);
        a1[j] = *(const float4*)(src+4);
      }
      int rowb = w*16 + srow;
      stage16(bBase + (long)rowb*768 + k0 + gsw, Bs[cur^1] + w*512 + lane*8);
    }
    const bf16* Ac = As[cur];
    const bf16* Bc = Bs[cur];
    bfrag af[2], bfv[4];
#pragma unroll
    for (int t=0;t<2;t++) af[t]  = *(const bfrag*)(Ac + (wm + t*16 + l16)*32 + ((quad ^ xr)*8));
#pragma unroll
    for (int t=0;t<4;t++) bfv[t] = *(const bfrag*)(Bc + (t*16 + l16)*32 + ((quad ^ xr)*8));
#pragma unroll
    for (int ti=0;ti<2;ti++)
#pragma unroll
      for (int tj=0;tj<4;tj++)
        acc[ti][tj] = __builtin_amdgcn_mfma_f32_16x16x32_bf16(af[ti], bfv[tj], acc[ti][tj], 0, 0, 0);
    if (it+1 < nIt){
      int nb = cur^1;
#pragma unroll
      for (int j=0;j<2;j++){
        union { bfrag f; bf16 h[8]; } o;
        o.h[0]=__float2bfloat16(a0[j].x*wA[j]); o.h[1]=__float2bfloat16(a0[j].y*wA[j]);
        o.h[2]=__float2bfloat16(a0[j].z*wA[j]); o.h[3]=__float2bfloat16(a0[j].w*wA[j]);
        o.h[4]=__float2bfloat16(a1[j].x*wA[j]); o.h[5]=__float2bfloat16(a1[j].y*wA[j]);
        o.h[6]=__float2bfloat16(a1[j].z*wA[j]); o.h[7]=__float2bfloat16(a1[j].w*wA[j]);
        *(bfrag*)(As[nb] + (w*2+j)*512 + lane*8) = o.f;
      }
    }
    cur ^= 1;
  }
  bf16* Cb = C + (long)e*CAPP_*DFF_;
#pragma unroll
  for (int ti=0;ti<2;ti++)
#pragma unroll
    for (int tj=0;tj<4;tj++)
#pragma unroll
      for (int r=0;r<4;r++){
        int row = m0 + wm + ti*16 + quad*4 + r;
        int col = bx*64 + tj*16 + l16;
        Cb[(long)row*DFF_ + col] = __float2bfloat16(fmaxf(acc[ti][tj][r], 0.f));
      }
}

// ---------------- LayerNorm: fp32 in -> fp32 out (+ optional bf16 copy, + optional fused gate logits) ----------------
__global__ __launch_bounds__(256)
void ln_kernel(const float* __restrict__ src, const float* __restrict__ g, const float* __restrict__ bb,
               float* __restrict__ dstF, bf16* __restrict__ dstB,
               const float* __restrict__ gateW, float* __restrict__ glog2)
{
  int row = blockIdx.x, tid = threadIdx.x;
  __shared__ float red[256];
  __shared__ float gsum[4][E_];
  float v[3];
#pragma unroll
  for (int j=0;j<3;j++) v[j] = src[(long)row*D_ + tid + j*256];
  float s = v[0]+v[1]+v[2];
  red[tid]=s; __syncthreads();
  for (int o=128;o>0;o>>=1){ if(tid<o) red[tid]+=red[tid+o]; __syncthreads(); }
  float mean = red[0]*(1.0f/D_);
  __syncthreads();
  float sq = 0.f;
#pragma unroll
  for (int j=0;j<3;j++){ float d=v[j]-mean; sq += d*d; }
  red[tid]=sq; __syncthreads();
  for (int o=128;o>0;o>>=1){ if(tid<o) red[tid]+=red[tid+o]; __syncthreads(); }
  float rstd = rsqrtf(red[0]*(1.0f/D_) + 1e-5f);
  float ov[3];
#pragma unroll
  for (int j=0;j<3;j++){
    int d = tid + j*256;
    float o = (v[j]-mean)*rstd*g[d] + bb[d];
    ov[j] = o;
    dstF[(long)row*D_+d] = o;
    if (dstB) dstB[(long)row*D_+d] = __float2bfloat16(o);
  }
  if (gateW){
    float gp[E_] = {};
#pragma unroll
    for (int j=0;j<3;j++){
      int d = tid + j*256;
      const float* gw = gateW + (long)d*E_;
#pragma unroll
      for (int e=0;e<E_;e++) gp[e] += ov[j]*gw[e];
    }
#pragma unroll
    for (int off=1; off<64; off<<=1)
#pragma unroll
      for (int e=0;e<E_;e++) gp[e] += __shfl_xor(gp[e], off);
    if ((tid & 63) == 0)
#pragma unroll
      for (int e=0;e<E_;e++) gsum[tid>>6][e] = gp[e];
    __syncthreads();
    if (tid < E_)
      glog2[(long)row*E_ + tid] = gsum[0][tid]+gsum[1][tid]+gsum[2][tid]+gsum[3][tid];
  }
}

// ---------------- router logits + argmax + (h,e) bin build ----------------
#define RTOK 4
__global__ __launch_bounds__(768)
void router_argmax(const float* __restrict__ ln1, const float* __restrict__ WrT,
                   int* __restrict__ eidx, int* __restrict__ gHist,
                   int* __restrict__ hCnt, int* __restrict__ hList)
{
  int tok0 = blockIdx.x*RTOK;
  int tid = threadIdx.x;
  int col = tid >> 3, seg = tid & 7;     // col 0..95 (= h*8+e), seg 0..7
  __shared__ float xrow[RTOK][D_];
  __shared__ float logits[RTOK][96];
  for (int i=tid; i<RTOK*D_; i+=768){
    int t = i / D_, dpos = i - t*D_;
    xrow[t][dpos] = ln1[(long)(tok0+t)*D_ + dpos];
  }
  __syncthreads();
  const float* wrow = WrT + (long)col*D_;
  float acc[RTOK] = {};
#pragma unroll
  for (int j=0;j<24;j++){
    int dbase = j*32 + seg*4;
    float4 w = *(const float4*)(wrow + dbase);
#pragma unroll
    for (int t=0;t<RTOK;t++){
      float4 xv = *(const float4*)(&xrow[t][dbase]);
      acc[t] += xv.x*w.x + xv.y*w.y + xv.z*w.z + xv.w*w.w;
    }
  }
#pragma unroll
  for (int off=1; off<8; off<<=1)
#pragma unroll
    for (int t=0;t<RTOK;t++) acc[t] += __shfl_xor(acc[t], off);
  if (seg == 0)
#pragma unroll
    for (int t=0;t<RTOK;t++) logits[t][col] = acc[t];
  __syncthreads();
  if (tid < RTOK*H_){
    int t = tid / H_, h = tid % H_;
    const float* p = &logits[t][h*8];
    float best = p[0]; int bi = 0;
#pragma unroll
    for (int e=1;e<8;e++){ float v=p[e]; if (v > best){ best=v; bi=e; } }
    int tok = tok0 + t;
    eidx[tok*H_ + h] = bi;
    atomicAdd(&gHist[h*E_ + bi], 1);
    int he = h*E_ + bi;
    int pos = atomicAdd(&hCnt[he], 1);
    hList[he*NTOK + pos] = tok;
  }
}

// ---------------- binned V projection: one (h,e) per block.x, W in LDS, stream bin tokens ----------------
__global__ __launch_bounds__(256)
void vsel_b(const float* __restrict__ ln1, const float* __restrict__ Wv,
            const int* __restrict__ hCnt, const int* __restrict__ hList,
            bf16* __restrict__ vT)
{
  int he = blockIdx.x;             // h*E + e
  int h = he >> 3;
  __shared__ float Ws[DH_*DH_];    // 16 KB
  __shared__ float xsh[4][DH_];
  int tid = threadIdx.x;
  const float* W = Wv + (long)he*DH_*DH_;
  for (int i=tid; i<DH_*DH_; i+=256) Ws[i] = W[i];
  int cnt = hCnt[he];
  __syncthreads();
  int w = tid >> 6, lane = tid & 63;
  const int* lst = hList + (long)he*NTOK;
  for (int i = blockIdx.y*4 + w; i < cnt; i += 32){
    int tok = lst[i];
    int b = tok >> 10, s = tok & 1023;
    xsh[w][lane] = ln1[(long)tok*D_ + h*DH_ + lane];
    float acc = 0.f;
#pragma unroll 8
    for (int d=0; d<DH_; d++) acc += xsh[w][d]*Ws[d*DH_ + lane];
    vT[((long)(b*H_+h)*DH_ + lane)*S_ + s] = __float2bfloat16(acc);
  }
}

// ---------------- attention pass 1 (MFMA flash stats) + HOSTED W1/W2 transpose blocks ----------------
__global__ __launch_bounds__(256)
void attn_stats_mfma(const bf16* __restrict__ qkB, float* __restrict__ gM, float* __restrict__ gL,
                     const float* __restrict__ W1, const float* __restrict__ W2,
                     bf16* __restrict__ WT1, bf16* __restrict__ WT2)
{
  __shared__ __align__(16) char smem[32768];
  int tid = threadIdx.x;
  if (blockIdx.z >= 2){
    int flat = (blockIdx.z - 2)*96 + blockIdx.y*8 + blockIdx.x;   // 0..3071
    const float* src; int N, K, bx, by; bf16* dst;
    if (flat < 1536){ int e = flat/192, r = flat - e*192;
      src = W1 + (long)e*768*2048; N = 2048; K = 768;  bx = r % 32; by = r / 32;
      dst = WT1 + (long)e*2048*768;
    } else { int f2 = flat - 1536; int e = f2/192, r = f2 - e*192;
      src = W2 + (long)e*2048*768; N = 768;  K = 2048; bx = r % 12; by = r / 12;
      dst = WT2 + (long)e*768*2048;
    }
    transp_tile_bf16(src, dst, N, K, bx*64, by*128, tid, (float(*)[64])smem);
    return;
  }
  bf16* ldsQ = (bf16*)smem;                 // 8 KB; K buffers at +8192, +16384 (computed per-use)
  int h = blockIdx.y, b = blockIdx.z;
  int w = tid >> 6, lane = tid & 63;
  int quad = lane >> 4, l16 = lane & 15;
  int x7 = l16 & 7;                    // read-side swizzle key (row&7 == l16&7)
  const bf16* kbase = qkB + ((long)(b*S_))*QKLD + 768 + h*DH_;
  for (int half=0; half<2; half++){
    int s0 = (half ? (S_/64 - 1 - blockIdx.x) : blockIdx.x)*64;   // bands x and 15-x: uniform 17 tiles
    __syncthreads();                 // protect LDS reuse across bands
    const bf16* qbase = qkB + ((long)(b*S_ + s0))*QKLD + h*DH_;
#pragma unroll
    for (int j=0;j<2;j++){
      int c = j*256 + tid;
      int row = c >> 3;
      int gs = ((c & 7) ^ (row & 7))*8;
      stage16(qbase + (long)row*QKLD + gs, ldsQ + c*8);
      stage16(kbase + (long)row*QKLD + gs, (bf16*)(smem + 8192) + c*8);   // tt=0 prefetch -> buf 0
    }
    float m_ln[4] = {-1e30f,-1e30f,-1e30f,-1e30f};
    float l_ln[4] = {0.f,0.f,0.f,0.f};
    int ttEnd = s0 >> 6;
    int cur = 0;
    for (int tt=0; tt<=ttEnd; tt++){
      __syncthreads();               // drains stage of buf[cur]
      if (tt < ttEnd){
        bf16* Kn = (bf16*)(smem + 8192 + ((cur^1) << 13));
#pragma unroll
        for (int j=0;j<2;j++){
          int c = j*256 + tid;
          int row = c >> 3;
          int gs = ((c & 7) ^ (row & 7))*8;
          stage16(kbase + (long)((tt+1)*64 + row)*QKLD + gs, Kn + c*8);
        }
      }
      const bf16* Kc = (const bf16*)(smem + 8192 + (cur << 13));
      bfrag af0 = *(const bfrag*)(ldsQ + (w*16 + l16)*64 + ((quad     ^ x7)*8));
      bfrag af1 = *(const bfrag*)(ldsQ + (w*16 + l16)*64 + (((quad+4) ^ x7)*8));
      f32x4 cfr[4];
#pragma unroll
      for (int j=0;j<4;j++){
        bfrag b0 = *(const bfrag*)(Kc + (j*16 + l16)*64 + ((quad     ^ x7)*8));
        bfrag b1 = *(const bfrag*)(Kc + (j*16 + l16)*64 + (((quad+4) ^ x7)*8));
        f32x4 z = {};
        z = __builtin_amdgcn_mfma_f32_16x16x32_bf16(af0, b0, z, 0,0,0);
        z = __builtin_amdgcn_mfma_f32_16x16x32_bf16(af1, b1, z, 0,0,0);
        cfr[j] = z;
      }
      // lane-local online update; garbage from all-masked lanes flushed at the final reduce.
#pragma unroll
      for (int r=0;r<4;r++){
        int s_g = s0 + w*16 + quad*4 + r;
        float v0 = (tt*64      + l16 <= s_g) ? cfr[0][r]*0.125f : -1e30f;
        float v1 = (tt*64 + 16 + l16 <= s_g) ? cfr[1][r]*0.125f : -1e30f;
        float v2 = (tt*64 + 32 + l16 <= s_g) ? cfr[2][r]*0.125f : -1e30f;
        float v3 = (tt*64 + 48 + l16 <= s_g) ? cfr[3][r]*0.125f : -1e30f;
        float mt = fmaxf(fmaxf(v0,v1), fmaxf(v2,v3));
        float mn = fmaxf(m_ln[r], mt);
        l_ln[r] = l_ln[r]*__expf(m_ln[r]-mn)
                + ((__expf(v0-mn)+__expf(v1-mn)) + (__expf(v2-mn)+__expf(v3-mn)));
        m_ln[r] = mn;
      }
      cur ^= 1;
    }
    // deferred cross-lane reduction (once per band)
#pragma unroll
    for (int r=0;r<4;r++){
      float mf = m_ln[r];
#pragma unroll
      for (int mm=1; mm<16; mm<<=1) mf = fmaxf(mf, __shfl_xor(mf, mm));
      float lf = l_ln[r]*__expf(m_ln[r]-mf);
#pragma unroll
      for (int mm=1; mm<16; mm<<=1) lf += __shfl_xor(lf, mm);
      if (l16 == 0){
        long basei = ((long)(b*H_ + h))*S_ + s0 + w*16 + quad*4 + r;
        gM[basei] = mf; gL[basei] = lf;
      }
    }
  }
}

// ---------------- attention pass 2 (fused MFMA, transposed einsum), PAIRED bands + dbuf Q/V ----------------
__global__ __launch_bounds__(256)
void attn_pv(const bf16* __restrict__ qkB, const bf16* __restrict__ vT,
             const float* __restrict__ gM, const float* __restrict__ gL, float* __restrict__ aoH)
{
  int h = blockIdx.y, b = blockIdx.z;
  int bh = b*H_ + h;
  int tid = threadIdx.x;
  int w = tid >> 6, lane = tid & 63;
  int quad = lane >> 4, l16 = lane & 15;
  int x7 = l16 & 7;
  __shared__ bf16 ldsK[64*64];
  __shared__ bf16 ldsQ[2][64*64];
  __shared__ bf16 ldsV[2][64*64];
  __shared__ bf16 ldsS[64*72];        // +8 pad; wave-band-private
  __shared__ float smx[2][64], sli[2][64];
  const bf16* qbase = qkB + ((long)(b*S_))*QKLD + h*DH_;
  const bf16* vbase = vT + ((long)bh*DH_)*S_;
  for (int half=0; half<2; half++){
    int t0 = (half ? (S_/64 - 1 - blockIdx.x) : blockIdx.x)*64;   // paired bands: uniform 17 tiles/block
    __syncthreads();                 // protect LDS reuse across bands
    const bf16* kbase = qkB + ((long)(b*S_ + t0))*QKLD + 768 + h*DH_;
    int sb0 = t0 >> 6;
#pragma unroll
    for (int j=0;j<2;j++){
      int c = j*256 + tid;
      int row = c >> 3;
      int gs = ((c & 7) ^ (row & 7))*8;
      stage16(kbase + (long)row*QKLD + gs, ldsK + c*8);
      stage16(qbase + (long)(sb0*64 + row)*QKLD + gs, ldsQ[0] + c*8);
      stage16(vbase + (long)row*S_ + sb0*64 + gs, ldsV[0] + c*8);
    }
    if (tid < 64){
      smx[0][tid] = gM[(long)bh*S_ + sb0*64 + tid];
      sli[0][tid] = 1.0f / gL[(long)bh*S_ + sb0*64 + tid];
    }
    f32x4 accO[4] = {};
    int cur = 0;
    for (int sb = sb0; sb < S_/64; sb++){
      __syncthreads();
      if (sb+1 < S_/64){
        int nb = cur^1;
#pragma unroll
        for (int j=0;j<2;j++){
          int c = j*256 + tid;
          int row = c >> 3;
          int gs = ((c & 7) ^ (row & 7))*8;
          stage16(qbase + (long)((sb+1)*64 + row)*QKLD + gs, ldsQ[nb] + c*8);
          stage16(vbase + (long)row*S_ + (sb+1)*64 + gs, ldsV[nb] + c*8);
        }
        if (tid < 64){
          smx[nb][tid] = gM[(long)bh*S_ + (sb+1)*64 + tid];
          sli[nb][tid] = 1.0f / gL[(long)bh*S_ + (sb+1)*64 + tid];
        }
      }
      const bf16* Qc = ldsQ[cur];
      const bf16* Vc = ldsV[cur];
      bfrag af0 = *(const bfrag*)(ldsK + (w*16 + l16)*64 + ((quad     ^ x7)*8));
      bfrag af1 = *(const bfrag*)(ldsK + (w*16 + l16)*64 + (((quad+4) ^ x7)*8));
      f32x4 cs[4];
#pragma unroll
      for (int j=0;j<4;j++){
        bfrag b0 = *(const bfrag*)(Qc + (j*16 + l16)*64 + ((quad     ^ x7)*8));
        bfrag b1 = *(const bfrag*)(Qc + (j*16 + l16)*64 + (((quad+4) ^ x7)*8));
        f32x4 z = {};
        z = __builtin_amdgcn_mfma_f32_16x16x32_bf16(af0, b0, z, 0,0,0);
        z = __builtin_amdgcn_mfma_f32_16x16x32_bf16(af1, b1, z, 0,0,0);
        cs[j] = z;
      }
#pragma unroll
      for (int j=0;j<4;j++)
#pragma unroll
        for (int r=0;r<4;r++){
          int t_loc = w*16 + quad*4 + r;
          int s_loc = j*16 + l16;
          float wgt = ((t0 + t_loc) <= (sb*64 + s_loc))
                    ? __expf(cs[j][r]*0.125f - smx[cur][s_loc])*sli[cur][s_loc] : 0.f;
          ldsS[t_loc*72 + s_loc] = __float2bfloat16(wgt);
        }
      bfrag pa0 = *(const bfrag*)(ldsS + (w*16 + l16)*72 + quad*8);
      bfrag pa1 = *(const bfrag*)(ldsS + (w*16 + l16)*72 + 32 + quad*8);
#pragma unroll
      for (int j=0;j<4;j++){
        bfrag b0 = *(const bfrag*)(Vc + (j*16 + l16)*64 + ((quad     ^ x7)*8));
        bfrag b1 = *(const bfrag*)(Vc + (j*16 + l16)*64 + (((quad+4) ^ x7)*8));
        accO[j] = __builtin_amdgcn_mfma_f32_16x16x32_bf16(pa0, b0, accO[j], 0,0,0);
        accO[j] = __builtin_amdgcn_mfma_f32_16x16x32_bf16(pa1, b1, accO[j], 0,0,0);
      }
      cur ^= 1;
    }
#pragma unroll
    for (int j=0;j<4;j++)
#pragma unroll
      for (int r=0;r<4;r++){
        int t_loc = w*16 + quad*4 + r;
        int f = j*16 + l16;
        aoH[((long)bh*S_ + t0 + t_loc)*DH_ + f] = accO[j][r];
      }
  }
}

// ---------------- binned O projection + residual: one (h,e) per block.x, W in LDS ----------------
__global__ __launch_bounds__(256)
void oproj_b(const float* __restrict__ aoH, const float* __restrict__ Wo,
             const int* __restrict__ hCnt, const int* __restrict__ hList,
             const float* __restrict__ x, float* __restrict__ x1)
{
  int he = blockIdx.x;             // h*E + e
  int h = he >> 3;
  __shared__ float Ws[DH_*DH_];    // 16 KB
  __shared__ float xsh[4][DH_];
  int tid = threadIdx.x;
  const float* W = Wo + (long)he*DH_*DH_;
  for (int i=tid; i<DH_*DH_; i+=256) Ws[i] = W[i];
  int cnt = hCnt[he];
  __syncthreads();
  int w = tid >> 6, lane = tid & 63;
  const int* lst = hList + (long)he*NTOK;
  for (int i = blockIdx.y*4 + w; i < cnt; i += 32){
    int tok = lst[i];
    int b = tok >> 10, s = tok & 1023;
    xsh[w][lane] = aoH[((long)(b*H_+h)*S_ + s)*DH_ + lane];
    float acc = 0.f;
#pragma unroll 8
    for (int f=0; f<DH_; f++) acc += xsh[w][f]*Ws[f*DH_ + lane];
    long idx = (long)tok*D_ + h*DH_ + lane;
    x1[idx] = x[idx] + acc;
  }
}

// ---------------- MoE routing: top-2, WAVE-SCAN capacity assignment (2 barriers, no LDS atomics) ----------------
// 1024 threads, 16 waves. Flat item order (token-major, slot-minor) identical to reference cumsum.
__global__ __launch_bounds__(1024)
void route_kernel(const float* __restrict__ glog2, const int* __restrict__ gHist,
                  int* __restrict__ gI0, int* __restrict__ gI1,
                  int* __restrict__ gPos0, int* __restrict__ gPos1,
                  int* __restrict__ listTok, float* __restrict__ listW,
                  int* __restrict__ gCnt, float* __restrict__ auxOut)
{
  __shared__ unsigned char sI0[NTOK], sI1[NTOK];
  __shared__ float sP0[NTOK], sP1[NTOK];
  __shared__ short sPos0[NTOK], sPos1[NTOK];
  __shared__ int   waveTot[16][E_];
  __shared__ float waveImp[16][E_];
  __shared__ float sImp[E_];
  __shared__ int   sHist[NHE];
  __shared__ int   sCnt[E_];
  int tid = threadIdx.x;
  int lane = tid & 63, wv = tid >> 6;
  if (tid < NHE) sHist[tid] = gHist[tid];
  // phase 1: top-2 per token (2 iterations)
  for (int i=tid; i<NTOK; i+=1024){
    const float* p = glog2 + (long)i*E_;
    float b0 = p[0]; int e0 = 0;
#pragma unroll
    for (int e=1;e<E_;e++){ float vv=p[e]; if (vv > b0){ b0=vv; e0=e; } }
    float b1v = -1e30f; int e1 = 0;
#pragma unroll
    for (int e=0;e<E_;e++){ if (e==e0) continue; float vv=p[e]; if (vv > b1v){ b1v=vv; e1=e; } }
    float ex = __expf(b1v - b0);
    float inv = 1.f/(1.f + ex);
    sI0[i] = (unsigned char)e0; sI1[i] = (unsigned char)e1;
    sP0[i] = inv; sP1[i] = ex*inv;
    gI0[i] = e0; gI1[i] = e1;
  }
  __syncthreads();
  // phase 2: per-thread counts of 4 flat items, wave shfl-scan, cross-wave prefix
  int myCnt[E_] = {};
  unsigned char ie[4];
  int base = tid*4;
#pragma unroll
  for (int j=0;j<4;j++){
    int i = base + j;
    int tok = i >> 1;
    int e = (i & 1) ? (int)sI1[tok] : (int)sI0[tok];
    ie[j] = (unsigned char)e;
#pragma unroll
    for (int ee=0;ee<E_;ee++) myCnt[ee] += (e == ee);
  }
  int inc[E_];
#pragma unroll
  for (int e=0;e<E_;e++) inc[e] = myCnt[e];
#pragma unroll
  for (int off=1; off<64; off<<=1){
#pragma unroll
    for (int e=0;e<E_;e++){
      int v = __shfl_up(inc[e], off);
      if (lane >= off) inc[e] += v;
    }
  }
  if (lane == 63)
#pragma unroll
    for (int e=0;e<E_;e++) waveTot[wv][e] = inc[e];
  __syncthreads();
  int pref[E_];
#pragma unroll
  for (int e=0;e<E_;e++) pref[e] = inc[e] - myCnt[e];
  for (int w2=0; w2<16; w2++){
    if (w2 < wv){
#pragma unroll
      for (int e=0;e<E_;e++) pref[e] += waveTot[w2][e];
    }
  }
#pragma unroll
  for (int j=0;j<4;j++){
    int i = base + j;
    int tok = i >> 1;
    int pos = 0;
#pragma unroll
    for (int ee=0;ee<E_;ee++) if (ie[j] == ee) pos = pref[ee]++;
    short p = (pos < CAP_) ? (short)pos : (short)-1;
    if (i & 1) sPos1[tok] = p; else sPos0[tok] = p;
  }
  if (tid < E_){
    int cnt = 0;
    for (int w2=0; w2<16; w2++) cnt += waveTot[w2][tid];
    sCnt[tid] = cnt < CAP_ ? cnt : CAP_;
    gCnt[tid] = sCnt[tid];
  }
  __syncthreads();
  // phase 3: lists + importance (register accum, wave reduce; no LDS atomics)
  float impLoc[E_] = {};
  for (int i=tid; i<NTOK; i+=1024){
    int e0 = sI0[i], e1 = sI1[i];
    int p0i = sPos0[i], p1i = sPos1[i];
    float k0 = p0i >= 0 ? 1.f : 0.f, k1 = p1i >= 0 ? 1.f : 0.f;
    float p0 = sP0[i], p1 = sP1[i];
    float denom = p0*k0 + p1*k1 + 1e-9f;
    float w0 = p0*k0/denom, w1 = p1*k1/denom;
    if (p0i >= 0){
      listTok[e0*CAP_+p0i] = i; listW[e0*CAP_+p0i] = w0;
#pragma unroll
      for (int ee=0;ee<E_;ee++) impLoc[ee] += (e0 == ee) ? w0 : 0.f;
    }
    if (p1i >= 0){
      listTok[e1*CAP_+p1i] = i; listW[e1*CAP_+p1i] = w1;
#pragma unroll
      for (int ee=0;ee<E_;ee++) impLoc[ee] += (e1 == ee) ? w1 : 0.f;
    }
    gPos0[i] = p0i; gPos1[i] = p1i;
  }
#pragma unroll
  for (int off=1; off<64; off<<=1)
#pragma unroll
    for (int e=0;e<E_;e++) impLoc[e] += __shfl_xor(impLoc[e], off);
  if (lane == 0)
#pragma unroll
    for (int e=0;e<E_;e++) waveImp[wv][e] = impLoc[e];
  __syncthreads();
  if (tid < E_){
    float s = 0.f;
    for (int w2=0; w2<16; w2++) s += waveImp[w2][tid];
    sImp[tid] = s;
  }
  __syncthreads();
  // phase 4: aux losses
  if (tid == 0){
    float tot = 0.f;
    for (int i=0;i<NHE;i++) tot += (float)sHist[i]*(1.0f/NTOK)*0.01f;
    float a1 = 0.f;
    for (int i=0;i<NHE;i++){
      float p = ((float)sHist[i]*(1.0f/NTOK)*0.01f)/(tot + 1e-9f);
      a1 += p*p;
    }
    a1 *= (float)(H_*E_);
    float tcs = 0.f, ims = 0.f;
    for (int e=0;e<E_;e++){ tcs += (float)sCnt[e]; ims += sImp[e]; }
    float a2 = 0.f;
    for (int e=0;e<E_;e++) a2 += ((float)sCnt[e]/tcs)*(sImp[e]/ims);
    a2 *= (float)E_;
    auxOut[0] = a1 + a2;
  }
}

// ---------------- final combine: out = x1 + expert contributions (2 split-K slices, fp32) ----------------
__global__ __launch_bounds__(256)
void combine_kernel(const float* __restrict__ x1,
                    const float* __restrict__ Ya, const float* __restrict__ Yb,
                    const int* __restrict__ gI0, const int* __restrict__ gI1,
                    const int* __restrict__ gPos0, const int* __restrict__ gPos1,
                    float* __restrict__ out)
{
  int i = blockIdx.x;
  int tid = threadIdx.x;
  int p0 = gPos0[i], p1 = gPos1[i];
  int e0 = gI0[i],  e1 = gI1[i];
  long off0 = (long)(e0*CAPP_ + (p0 >= 0 ? p0 : 0))*D_;
  long off1 = (long)(e1*CAPP_ + (p1 >= 0 ? p1 : 0))*D_;
  const float* y0a = Ya + off0; const float* y0b = Yb + off0;
  const float* y1a = Ya + off1; const float* y1b = Yb + off1;
  for (int d=tid; d<D_; d+=256){
    float v = x1[(long)i*D_+d];
    if (p0 >= 0) v += y0a[d] + y0b[d];
    if (p1 >= 0) v += y1a[d] + y1b[d];
    out[(long)i*D_+d] = v;
  }
}

extern "C" void kernel_launch(void* const* d_in, const int* in_sizes, int n_in,
                              void* d_out, int out_size, void* d_ws, size_t ws_size,
                              hipStream_t stream)
{
  const float* x    = (const float*)d_in[0];
  const float* W_q  = (const float*)d_in[2];
  const float* W_k  = (const float*)d_in[3];
  const float* W_v  = (const float*)d_in[4];
  const float* W_o  = (const float*)d_in[5];
  const float* W_r  = (const float*)d_in[6];
  const float* g1   = (const float*)d_in[7];
  const float* b1   = (const float*)d_in[8];
  const float* g2   = (const float*)d_in[9];
  const float* b2   = (const float*)d_in[10];
  const float* gate = (const float*)d_in[11];
  const float* W1   = (const float*)d_in[12];
  const float* W2   = (const float*)d_in[13];
  float* out = (float*)d_out;

  float* wsf = (float*)d_ws;
  // ---- workspace layout (float slots) ----
  const long oX1   = 0;          // 1,572,864
  const long oLnF  = 1572864;    // fp32 2048x768; live through gemm_ffn1, then reused as split-K slice 1
  const long oLnB  = 3145728;    // bf16 2048x768
  const long oWcat = 3932160;    // bf16 1536x768 (ends 4521984)
  const long oWrT  = 4521984;    // fp32 96x768 = 73,728 (ends 4595712)
  const long oHist = 4595712;    // int 96 (attention (h,e) histogram)
  const long oHCnt = 4595808;    // int 96 ((h,e) bin counters) - adjacent: one memset covers both
  const long oGM   = 4718592;    // 24,576
  const long oGL   = 4743168;    // 24,576
  const long oEidx = 4767744;    // int 24,576
  const long oGlg2 = 4792320;    // 16,384
  const long oI0   = 4808704;
  const long oI1   = 4810752;
  const long oP0   = 4812800;
  const long oP1   = 4814848;
  const long oLT   = 4816896;
  const long oLW   = 4819456;
  const long oCnt  = 4822016;    // 8 ints
  const long SB    = 4822528;    // shared overlay region
  // attention view: qkB bf16 @SB (1.57M) | vT bf16 @+1,572,864 | aoH fp32 @+2,359,296 |
  //                 hList int @+3,932,160 (96*2048)
  // FFN view:       Hid @+7,471,104 | Yexp fp32 @+10,616,832
  const long oWT1  = SB + 12976128;      // bf16 8 x 2048x768 (6,291,456 fl) - dedicated, no overlay
  const long oWT2  = oWT1 + 6291456;     // bf16 8 x 768x2048 (6,291,456 fl)
  const long TOTAL = oWT2 + 6291456;     // 30,381,568 floats = 121.5 MB
  if (ws_size < (size_t)TOTAL*4) return;

  float* x1    = wsf + oX1;
  float* lnbF  = wsf + oLnF;
  bf16*  lnbB  = (bf16*)(wsf + oLnB);
  bf16*  WcatB = (bf16*)(wsf + oWcat);
  float* WrT   = wsf + oWrT;
  int*   gHist = (int*)(wsf + oHist);
  int*   hCnt  = (int*)(wsf + oHCnt);
  float* gM    = wsf + oGM;
  float* gL    = wsf + oGL;
  int*   eidx  = (int*)(wsf + oEidx);
  float* glog2 = wsf + oGlg2;
  int*   gI0   = (int*)(wsf + oI0);
  int*   gI1   = (int*)(wsf + oI1);
  int*   gPos0 = (int*)(wsf + oP0);
  int*   gPos1 = (int*)(wsf + oP1);
  int*   lTok  = (int*)(wsf + oLT);
  float* lW    = wsf + oLW;
  int*   gCnt  = (int*)(wsf + oCnt);
  bf16*  qkB   = (bf16*)(wsf + SB);
  bf16*  vT    = (bf16*)(wsf + SB + 1572864);
  float* aoH   = wsf + SB + 2359296;
  int*   hList = (int*)(wsf + SB + 3932160);
  bf16*  Hid   = (bf16*)(wsf + SB + 7471104);
  float* Yexp  = wsf + SB + 10616832;
  float* YexpB = wsf + oLnF;     // split-K slice 1: lnF region, dead once gemm_ffn1 completes
  bf16*  WT1   = (bf16*)(wsf + oWT1);
  bf16*  WT2   = (bf16*)(wsf + oWT2);

  // ---- counter zero + immediate-needs weight prep (Wq/Wk/Wr only; W1/W2 hosted in attn_stats) ----
  (void)hipMemsetAsync(gHist, 0, 2*NHE*sizeof(int), stream);
  transp_qkr<<<180,256,0,stream>>>(W_q, W_k, W_r, WcatB, WrT);

  // ---- attention phase ----
  ln_kernel<<<NTOK,256,0,stream>>>(x, g1, b1, lnbF, lnbB, nullptr, nullptr);
  gemm_bn64<<<dim3(24,16,1),256,0,stream>>>(lnbB, WcatB, qkB, nullptr, 2048, QKLD, 768, 0,0,0, 0, 1, 1);
  router_argmax<<<NTOK/RTOK,768,0,stream>>>(lnbF, WrT, eidx, gHist, hCnt, hList);
  vsel_b<<<dim3(NHE,8,1),256,0,stream>>>(lnbF, W_v, hCnt, hList, vT);
  // z 0..1 = attention; z 2..33 = hosted W1/W2 transposes (3072 blocks riding idle CUs)
  attn_stats_mfma<<<dim3(S_/128,H_,2+32),256,0,stream>>>(qkB, gM, gL, W1, W2, WT1, WT2);
  attn_pv<<<dim3(S_/128,H_,B_),256,0,stream>>>(qkB, vT, gM, gL, aoH);
  oproj_b<<<dim3(NHE,8,1),256,0,stream>>>(aoH, W_o, hCnt, hList, x, x1);

  // ---- FFN phase (gather fused into W1 GEMM; WT1/WT2 ready since attn_stats) ----
  ln_kernel<<<NTOK,256,0,stream>>>(x1, g2, b2, lnbF, nullptr, gate, glog2);  // fused gate logits
  route_kernel<<<1,1024,0,stream>>>(glog2, gHist, gI0,gI1,gPos0,gPos1, lTok,lW,gCnt, out + (size_t)NTOK*D_);
  gemm_ffn1<<<dim3(32,3,8),256,0,stream>>>(lnbF, WT1, Hid, lTok, lW, gCnt);
  gemm_bn64<<<dim3(12,3,16),256,0,stream>>>(Hid, WT2, Yexp, YexpB, CAPP_, 768, 2048,
                                            (long)CAPP_*2048, (long)768*2048, (long)CAPP_*768, 0, 0, 2);
  combine_kernel<<<NTOK,256,0,stream>>>(x1, Yexp, YexpB, gI0,gI1,gPos0,gPos1, out);
}

// Round 10
// 378.472 us; speedup vs baseline: 1.0452x; 1.0078x over previous
//
#include <hip/hip_runtime.h>
#include <hip/hip_bf16.h>
#include <cstdint>

typedef __hip_bfloat16 bf16;
typedef __attribute__((ext_vector_type(8))) __bf16 bfrag;   // MFMA A/B operand (4 VGPRs)
typedef __attribute__((ext_vector_type(4))) float f32x4;    // MFMA C/D operand

#define B_    2
#define S_    1024
#define D_    768
#define H_    12
#define E_    8
#define DH_   64
#define DFF_  2048
#define CAP_  320            // ceil(1.25 * 2048 / 8)
#define CAPP_ 384            // CAP padded to 128-multiple for MFMA tiles
#define NTOK  (B_*S_)        // 2048
#define NTH   (NTOK*H_)      // 24576
#define QKLD  1536           // fused q|k row stride
#define NHE   (H_*E_)        // 96 (h,e) bins

// ---------------- async global->LDS 16B stage (per-lane global addr, lane-linear LDS) ----------------
__device__ __forceinline__ void stage16(const bf16* g, bf16* ldsLane){
#if __has_builtin(__builtin_amdgcn_global_load_lds)
  __builtin_amdgcn_global_load_lds((const __attribute__((address_space(1))) unsigned int*)g,
                                   (__attribute__((address_space(3))) unsigned int*)ldsLane, 16, 0, 0);
#else
  *(bfrag*)ldsLane = *(const bfrag*)g;
#endif
}

// ---------------- shared transpose tile body: 64n x 128k, XOR-swizzled LDS, 256B write runs ----------------
// t: 128x64 fp32 LDS tile. logical (row,col) stored at col' = col ^ (((row>>3)&15)*4).
__device__ __forceinline__ void transp_tile_bf16(const float* __restrict__ src, bf16* __restrict__ dst,
                                                 int N, int K, int n0, int k0, int tid, float (*t)[64])
{
  int chunk = tid & 15, rgrp = tid >> 4;
#pragma unroll
  for (int rr=0; rr<8; rr++){
    int row = rr*16 + rgrp;
    float4 v = *(const float4*)(src + (long)(k0+row)*N + n0 + chunk*4);
    *(float4*)&t[row][((chunk ^ (row>>3)) & 15)*4] = v;
  }
  __syncthreads();
#pragma unroll
  for (int it=0; it<4; it++){
    int slot = it*256 + tid;
    int n = slot >> 4, kc = slot & 15;      // 16 lanes (kc 0..15) cover one full 128-bf16 output row
    union { bfrag f; bf16 h[8]; } o;
#pragma unroll
    for (int i=0;i<8;i++){
      int row = kc*8 + i;                   // (row>>3)&15 == kc
      o.h[i] = __float2bfloat16(t[row][n ^ (kc*4)]);
    }
    *(bfrag*)(dst + (long)(n0+n)*K + k0 + kc*8) = o.f;
  }
}

// ---------------- Wq|Wk|Wr prep (needed immediately): 180 blocks ----------------
//   [0,72)    Wq 768x768 -> WcatB rows 0..767     (12nx x 6ky)
//   [72,144)  Wk 768x768 -> WcatB rows 768..1535
//   [144,180) Wr 768x96  -> WrT fp32 (64k x 32n tiles)
__global__ __launch_bounds__(256)
void transp_qkr(const float* __restrict__ Wq, const float* __restrict__ Wk,
                const float* __restrict__ Wr, bf16* __restrict__ WcatB, float* __restrict__ WrT)
{
  __shared__ float t[128][64];
  int bid = blockIdx.x, tid = threadIdx.x;
  if (bid < 144){
    const float* src; bf16* dst; int r;
    if (bid < 72){ src = Wq; dst = WcatB; r = bid; }
    else         { src = Wk; dst = WcatB + (long)768*768; r = bid - 72; }
    transp_tile_bf16(src, dst, 768, 768, (r%12)*64, (r/12)*128, tid, t);
  } else {
    int r = bid - 144;
    int n0 = (r % 3)*32, k0 = (r / 3)*64;
    int chunk = tid & 7, row2 = tid >> 3;
#pragma unroll
    for (int rr=0; rr<2; rr++){
      int row = rr*32 + row2;
      float4 v = *(const float4*)(Wr + (long)(k0+row)*96 + n0 + chunk*4);
      *(float4*)&t[row][chunk*4] = v;
    }
    __syncthreads();
    int chunkw = tid & 15, ng = tid >> 4;
#pragma unroll
    for (int rr=0; rr<2; rr++){
      int n = rr*16 + ng;
      float4 o;
      o.x = t[chunkw*4+0][n]; o.y = t[chunkw*4+1][n];
      o.z = t[chunkw*4+2][n]; o.w = t[chunkw*4+3][n];
      *(float4*)(WrT + (long)(n0+n)*768 + k0 + chunkw*4) = o;
    }
  }
}

// ---------------- MFMA GEMM, 128x64 tile, xor-swizzled LDS, XCD-chunked swizzle, split-K, 2-phase dbuf ----------------
__global__ __launch_bounds__(256)
void gemm_bn64(const bf16* __restrict__ A, const bf16* __restrict__ Bt,
               void* __restrict__ C, void* __restrict__ C2,
               int M, int N, int K, long sA, long sB, long sC, int relu, int outBf, int kSplit)
{
  int nwg = gridDim.x*gridDim.y*gridDim.z;
  int bid = blockIdx.x + gridDim.x*(blockIdx.y + gridDim.y*blockIdx.z);
  int nid = (bid & 7)*(nwg >> 3) + (bid >> 3);        // bijective: nwg % 8 == 0 at all call sites
  int bx = nid % gridDim.x;
  int t1 = nid / gridDim.x;
  int by = t1 % gridDim.y;
  int bz = t1 / gridDim.y;
  int e  = bz / kSplit, kc = bz - e*kSplit;
  A  += (long)e*sA;
  Bt += (long)e*sB;
  int kLen = K / kSplit, kBase = kc*kLen;
  int m0 = by*128, n0 = bx*64;
  __shared__ bf16 As[2][128*32];   // 2 x 8 KB
  __shared__ bf16 Bs[2][64*32];    // 2 x 4 KB
  int tid = threadIdx.x;
  int w = tid >> 6, lane = tid & 63;
  int quad = lane >> 4, l16 = lane & 15;
  int wm = w*32;
  f32x4 acc[2][4] = {};
  int srow = (lane >> 2);          // row within 16-row chunk
  int gsw  = ((lane & 3) ^ (srow & 3))*8;   // swizzled col group (8 bf16)
  const bf16* aBase = A + (long)m0*K;
  const bf16* bBase = Bt + (long)n0*K;
  int xr = (l16 & 3);              // read-side swizzle key (row&3 == l16&3)
  int nIt = kLen >> 5;
  {
    int k0 = kBase;
#pragma unroll
    for (int j=0;j<2;j++){
      int c = w*2 + j, row = c*16 + srow;
      stage16(aBase + (long)row*K + k0 + gsw, As[0] + c*512 + lane*8);
    }
    int rowb = w*16 + srow;
    stage16(bBase + (long)rowb*K + k0 + gsw, Bs[0] + w*512 + lane*8);
  }
  int cur = 0;
  for (int it=0; it<nIt; ++it){
    __syncthreads();               // drains stage of buf[cur]
    if (it+1 < nIt){               // prefetch next k-step into buf[cur^1]
      int k0 = kBase + (it+1)*32;
      int nb = cur^1;
#pragma unroll
      for (int j=0;j<2;j++){
        int c = w*2 + j, row = c*16 + srow;
        stage16(aBase + (long)row*K + k0 + gsw, As[nb] + c*512 + lane*8);
      }
      int rowb = w*16 + srow;
      stage16(bBase + (long)rowb*K + k0 + gsw, Bs[nb] + w*512 + lane*8);
    }
    const bf16* Ac = As[cur];
    const bf16* Bc = Bs[cur];
    bfrag af[2], bfv[4];
#pragma unroll
    for (int t=0;t<2;t++) af[t]  = *(const bfrag*)(Ac + (wm + t*16 + l16)*32 + ((quad ^ xr)*8));
#pragma unroll
    for (int t=0;t<4;t++) bfv[t] = *(const bfrag*)(Bc + (t*16 + l16)*32 + ((quad ^ xr)*8));
#pragma unroll
    for (int ti=0;ti<2;ti++)
#pragma unroll
      for (int tj=0;tj<4;tj++)
        acc[ti][tj] = __builtin_amdgcn_mfma_f32_16x16x32_bf16(af[ti], bfv[tj], acc[ti][tj], 0, 0, 0);
    cur ^= 1;
  }
  long zoff = (long)e*sC;
  void* Cp = kc ? C2 : C;
  if (outBf){
    bf16* Cb = (bf16*)Cp + zoff;
#pragma unroll
    for (int ti=0;ti<2;ti++)
#pragma unroll
      for (int tj=0;tj<4;tj++)
#pragma unroll
        for (int r=0;r<4;r++){
          int row = m0 + wm + ti*16 + quad*4 + r;
          int col = n0 + tj*16 + l16;
          float v = acc[ti][tj][r];
          if (relu) v = fmaxf(v, 0.f);
          Cb[(long)row*N + col] = __float2bfloat16(v);
        }
  } else {
    float* Cf = (float*)Cp + zoff;
#pragma unroll
    for (int ti=0;ti<2;ti++)
#pragma unroll
      for (int tj=0;tj<4;tj++)
#pragma unroll
        for (int r=0;r<4;r++){
          int row = m0 + wm + ti*16 + quad*4 + r;
          int col = n0 + tj*16 + l16;
          float v = acc[ti][tj][r];
          if (relu) v = fmaxf(v, 0.f);
          Cf[(long)row*N + col] = v;
        }
  }
}

// ---------------- W1 GEMM with FUSED gather: A reg-staged from fp32 ln2 via token list ----------------
__global__ __launch_bounds__(256)
void gemm_ffn1(const float* __restrict__ ln2, const bf16* __restrict__ Bt, bf16* __restrict__ C,
               const int* __restrict__ lTok, const float* __restrict__ lW, const int* __restrict__ gCnt)
{
  int nwg = gridDim.x*gridDim.y*gridDim.z;   // 32*3*8 = 768
  int bid = blockIdx.x + gridDim.x*(blockIdx.y + gridDim.y*blockIdx.z);
  int nid = (bid & 7)*(nwg >> 3) + (bid >> 3);
  int bx = nid % gridDim.x;
  int t1 = nid / gridDim.x;
  int by = t1 % gridDim.y;
  int e  = t1 / gridDim.y;
  int m0 = by*128;
  const bf16* bBase = Bt + (long)e*2048*768 + (long)(bx*64)*768;
  __shared__ bf16 As[2][128*32];
  __shared__ bf16 Bs[2][64*32];
  int tid = threadIdx.x;
  int w = tid >> 6, lane = tid & 63;
  int quad = lane >> 4, l16 = lane & 15;
  int wm = w*32;
  f32x4 acc[2][4] = {};
  int srow = (lane >> 2);
  int gsw  = ((lane & 3) ^ (srow & 3))*8;
  int xr = (l16 & 3);
  int cnt = gCnt[e];
  int tokA[2]; float wA[2];
#pragma unroll
  for (int j=0;j<2;j++){
    int row = m0 + (w*2+j)*16 + srow;
    bool live = row < cnt;
    tokA[j] = live ? lTok[e*CAP_ + row] : 0;
    wA[j]   = live ? lW[e*CAP_ + row]   : 0.f;
  }
  const int nIt = 24;   // 768/32
  {
#pragma unroll
    for (int j=0;j<2;j++){
      const float* src = ln2 + (long)tokA[j]*D_ + gsw;
      float4 a0 = *(const float4*)(src);
      float4 a1 = *(const float4*)(src+4);
      union { bfrag f; bf16 h[8]; } o;
      o.h[0]=__float2bfloat16(a0.x*wA[j]); o.h[1]=__float2bfloat16(a0.y*wA[j]);
      o.h[2]=__float2bfloat16(a0.z*wA[j]); o.h[3]=__float2bfloat16(a0.w*wA[j]);
      o.h[4]=__float2bfloat16(a1.x*wA[j]); o.h[5]=__float2bfloat16(a1.y*wA[j]);
      o.h[6]=__float2bfloat16(a1.z*wA[j]); o.h[7]=__float2bfloat16(a1.w*wA[j]);
      *(bfrag*)(As[0] + (w*2+j)*512 + lane*8) = o.f;
    }
    int rowb = w*16 + srow;
    stage16(bBase + (long)rowb*768 + gsw, Bs[0] + w*512 + lane*8);
  }
  int cur = 0;
  for (int it=0; it<nIt; ++it){
    __syncthreads();
    float4 a0[2], a1[2];
    if (it+1 < nIt){
      int k0 = (it+1)*32;
#pragma unroll
      for (int j=0;j<2;j++){           // issue A loads early: latency hides under MFMA below
        const float* src = ln2 + (long)tokA[j]*D_ + k0 + gsw;
        a0[j] = *(const float4*)(src);
        a1[j] = *(const float4*)(src+4);
      }
      int rowb = w*16 + srow;
      stage16(bBase + (long)rowb*768 + k0 + gsw, Bs[cur^1] + w*512 + lane*8);
    }
    const bf16* Ac = As[cur];
    const bf16* Bc = Bs[cur];
    bfrag af[2], bfv[4];
#pragma unroll
    for (int t=0;t<2;t++) af[t]  = *(const bfrag*)(Ac + (wm + t*16 + l16)*32 + ((quad ^ xr)*8));
#pragma unroll
    for (int t=0;t<4;t++) bfv[t] = *(const bfrag*)(Bc + (t*16 + l16)*32 + ((quad ^ xr)*8));
#pragma unroll
    for (int ti=0;ti<2;ti++)
#pragma unroll
      for (int tj=0;tj<4;tj++)
        acc[ti][tj] = __builtin_amdgcn_mfma_f32_16x16x32_bf16(af[ti], bfv[tj], acc[ti][tj], 0, 0, 0);
    if (it+1 < nIt){
      int nb = cur^1;
#pragma unroll
      for (int j=0;j<2;j++){
        union { bfrag f; bf16 h[8]; } o;
        o.h[0]=__float2bfloat16(a0[j].x*wA[j]); o.h[1]=__float2bfloat16(a0[j].y*wA[j]);
        o.h[2]=__float2bfloat16(a0[j].z*wA[j]); o.h[3]=__float2bfloat16(a0[j].w*wA[j]);
        o.h[4]=__float2bfloat16(a1[j].x*wA[j]); o.h[5]=__float2bfloat16(a1[j].y*wA[j]);
        o.h[6]=__float2bfloat16(a1[j].z*wA[j]); o.h[7]=__float2bfloat16(a1[j].w*wA[j]);
        *(bfrag*)(As[nb] + (w*2+j)*512 + lane*8) = o.f;
      }
    }
    cur ^= 1;
  }
  bf16* Cb = C + (long)e*CAPP_*DFF_;
#pragma unroll
  for (int ti=0;ti<2;ti++)
#pragma unroll
    for (int tj=0;tj<4;tj++)
#pragma unroll
      for (int r=0;r<4;r++){
        int row = m0 + wm + ti*16 + quad*4 + r;
        int col = bx*64 + tj*16 + l16;
        Cb[(long)row*DFF_ + col] = __float2bfloat16(fmaxf(acc[ti][tj][r], 0.f));
      }
}

// ---------------- LayerNorm: fp32 in -> fp32 out (+ optional bf16 copy, + optional fused gate logits) ----------------
__global__ __launch_bounds__(256)
void ln_kernel(const float* __restrict__ src, const float* __restrict__ g, const float* __restrict__ bb,
               float* __restrict__ dstF, bf16* __restrict__ dstB,
               const float* __restrict__ gateW, float* __restrict__ glog2)
{
  int row = blockIdx.x, tid = threadIdx.x;
  __shared__ float red[256];
  __shared__ float gsum[4][E_];
  float v[3];
#pragma unroll
  for (int j=0;j<3;j++) v[j] = src[(long)row*D_ + tid + j*256];
  float s = v[0]+v[1]+v[2];
  red[tid]=s; __syncthreads();
  for (int o=128;o>0;o>>=1){ if(tid<o) red[tid]+=red[tid+o]; __syncthreads(); }
  float mean = red[0]*(1.0f/D_);
  __syncthreads();
  float sq = 0.f;
#pragma unroll
  for (int j=0;j<3;j++){ float d=v[j]-mean; sq += d*d; }
  red[tid]=sq; __syncthreads();
  for (int o=128;o>0;o>>=1){ if(tid<o) red[tid]+=red[tid+o]; __syncthreads(); }
  float rstd = rsqrtf(red[0]*(1.0f/D_) + 1e-5f);
  float ov[3];
#pragma unroll
  for (int j=0;j<3;j++){
    int d = tid + j*256;
    float o = (v[j]-mean)*rstd*g[d] + bb[d];
    ov[j] = o;
    dstF[(long)row*D_+d] = o;
    if (dstB) dstB[(long)row*D_+d] = __float2bfloat16(o);
  }
  if (gateW){
    float gp[E_] = {};
#pragma unroll
    for (int j=0;j<3;j++){
      int d = tid + j*256;
      const float* gw = gateW + (long)d*E_;
#pragma unroll
      for (int e=0;e<E_;e++) gp[e] += ov[j]*gw[e];
    }
#pragma unroll
    for (int off=1; off<64; off<<=1)
#pragma unroll
      for (int e=0;e<E_;e++) gp[e] += __shfl_xor(gp[e], off);
    if ((tid & 63) == 0)
#pragma unroll
      for (int e=0;e<E_;e++) gsum[tid>>6][e] = gp[e];
    __syncthreads();
    if (tid < E_)
      glog2[(long)row*E_ + tid] = gsum[0][tid]+gsum[1][tid]+gsum[2][tid]+gsum[3][tid];
  }
}

// ---------------- router logits + argmax + (h,e) bin build ----------------
#define RTOK 4
__global__ __launch_bounds__(768)
void router_argmax(const float* __restrict__ ln1, const float* __restrict__ WrT,
                   int* __restrict__ eidx, int* __restrict__ gHist,
                   int* __restrict__ hCnt, int* __restrict__ hList)
{
  int tok0 = blockIdx.x*RTOK;
  int tid = threadIdx.x;
  int col = tid >> 3, seg = tid & 7;     // col 0..95 (= h*8+e), seg 0..7
  __shared__ float xrow[RTOK][D_];
  __shared__ float logits[RTOK][96];
  for (int i=tid; i<RTOK*D_; i+=768){
    int t = i / D_, dpos = i - t*D_;
    xrow[t][dpos] = ln1[(long)(tok0+t)*D_ + dpos];
  }
  __syncthreads();
  const float* wrow = WrT + (long)col*D_;
  float acc[RTOK] = {};
#pragma unroll
  for (int j=0;j<24;j++){
    int dbase = j*32 + seg*4;
    float4 w = *(const float4*)(wrow + dbase);
#pragma unroll
    for (int t=0;t<RTOK;t++){
      float4 xv = *(const float4*)(&xrow[t][dbase]);
      acc[t] += xv.x*w.x + xv.y*w.y + xv.z*w.z + xv.w*w.w;
    }
  }
#pragma unroll
  for (int off=1; off<8; off<<=1)
#pragma unroll
    for (int t=0;t<RTOK;t++) acc[t] += __shfl_xor(acc[t], off);
  if (seg == 0)
#pragma unroll
    for (int t=0;t<RTOK;t++) logits[t][col] = acc[t];
  __syncthreads();
  if (tid < RTOK*H_){
    int t = tid / H_, h = tid % H_;
    const float* p = &logits[t][h*8];
    float best = p[0]; int bi = 0;
#pragma unroll
    for (int e=1;e<8;e++){ float v=p[e]; if (v > best){ best=v; bi=e; } }
    int tok = tok0 + t;
    eidx[tok*H_ + h] = bi;
    atomicAdd(&gHist[h*E_ + bi], 1);
    int he = h*E_ + bi;
    int pos = atomicAdd(&hCnt[he], 1);
    hList[he*NTOK + pos] = tok;
  }
}

// ---------------- binned V projection: one (h,e) per block.x, W in LDS, stream bin tokens ----------------
__global__ __launch_bounds__(256)
void vsel_b(const float* __restrict__ ln1, const float* __restrict__ Wv,
            const int* __restrict__ hCnt, const int* __restrict__ hList,
            bf16* __restrict__ vT)
{
  int he = blockIdx.x;             // h*E + e
  int h = he >> 3;
  __shared__ float Ws[DH_*DH_];    // 16 KB
  __shared__ float xsh[4][DH_];
  int tid = threadIdx.x;
  const float* W = Wv + (long)he*DH_*DH_;
  for (int i=tid; i<DH_*DH_; i+=256) Ws[i] = W[i];
  int cnt = hCnt[he];
  __syncthreads();
  int w = tid >> 6, lane = tid & 63;
  const int* lst = hList + (long)he*NTOK;
  for (int i = blockIdx.y*4 + w; i < cnt; i += 32){
    int tok = lst[i];
    int b = tok >> 10, s = tok & 1023;
    xsh[w][lane] = ln1[(long)tok*D_ + h*DH_ + lane];
    float acc = 0.f;
#pragma unroll 8
    for (int d=0; d<DH_; d++) acc += xsh[w][d]*Ws[d*DH_ + lane];
    vT[((long)(b*H_+h)*DH_ + lane)*S_ + s] = __float2bfloat16(acc);
  }
}

// ---------------- attention pass 1 (MFMA flash stats) + HOSTED W1 transpose blocks ----------------
// grid (8,12,18): z<2 = attention (b=z); z>=2 = W1 tile flat=(z-2)*96+y*8+x in [0,1536):
//   W1[e] 768x2048 -> WT1[e] (2048x768), 32nx x 6ky per e.  (~50 MB rides the idle CUs.)
__global__ __launch_bounds__(256)
void attn_stats_mfma(const bf16* __restrict__ qkB, float* __restrict__ gM, float* __restrict__ gL,
                     const float* __restrict__ W1, bf16* __restrict__ WT1)
{
  __shared__ __align__(16) char smem[32768];
  int tid = threadIdx.x;
  if (blockIdx.z >= 2){
    int flat = (blockIdx.z - 2)*96 + blockIdx.y*8 + blockIdx.x;   // 0..1535
    int e = flat/192, r = flat - e*192;
    transp_tile_bf16(W1 + (long)e*768*2048, WT1 + (long)e*2048*768, 2048, 768,
                     (r % 32)*64, (r / 32)*128, tid, (float(*)[64])smem);
    return;
  }
  bf16* ldsQ = (bf16*)smem;                 // 8 KB; K buffers at +8192, +16384 (computed per-use)
  int h = blockIdx.y, b = blockIdx.z;
  int w = tid >> 6, lane = tid & 63;
  int quad = lane >> 4, l16 = lane & 15;
  int x7 = l16 & 7;                    // read-side swizzle key (row&7 == l16&7)
  const bf16* kbase = qkB + ((long)(b*S_))*QKLD + 768 + h*DH_;
  for (int half=0; half<2; half++){
    int s0 = (half ? (S_/64 - 1 - blockIdx.x) : blockIdx.x)*64;   // bands x and 15-x: uniform 17 tiles
    __syncthreads();                 // protect LDS reuse across bands
    const bf16* qbase = qkB + ((long)(b*S_ + s0))*QKLD + h*DH_;
#pragma unroll
    for (int j=0;j<2;j++){
      int c = j*256 + tid;
      int row = c >> 3;
      int gs = ((c & 7) ^ (row & 7))*8;
      stage16(qbase + (long)row*QKLD + gs, ldsQ + c*8);
      stage16(kbase + (long)row*QKLD + gs, (bf16*)(smem + 8192) + c*8);   // tt=0 prefetch -> buf 0
    }
    float m_ln[4] = {-1e30f,-1e30f,-1e30f,-1e30f};
    float l_ln[4] = {0.f,0.f,0.f,0.f};
    int ttEnd = s0 >> 6;
    int cur = 0;
    for (int tt=0; tt<=ttEnd; tt++){
      __syncthreads();               // drains stage of buf[cur]
      if (tt < ttEnd){
        bf16* Kn = (bf16*)(smem + 8192 + ((cur^1) << 13));
#pragma unroll
        for (int j=0;j<2;j++){
          int c = j*256 + tid;
          int row = c >> 3;
          int gs = ((c & 7) ^ (row & 7))*8;
          stage16(kbase + (long)((tt+1)*64 + row)*QKLD + gs, Kn + c*8);
        }
      }
      const bf16* Kc = (const bf16*)(smem + 8192 + (cur << 13));
      bfrag af0 = *(const bfrag*)(ldsQ + (w*16 + l16)*64 + ((quad     ^ x7)*8));
      bfrag af1 = *(const bfrag*)(ldsQ + (w*16 + l16)*64 + (((quad+4) ^ x7)*8));
      f32x4 cfr[4];
#pragma unroll
      for (int j=0;j<4;j++){
        bfrag b0 = *(const bfrag*)(Kc + (j*16 + l16)*64 + ((quad     ^ x7)*8));
        bfrag b1 = *(const bfrag*)(Kc + (j*16 + l16)*64 + (((quad+4) ^ x7)*8));
        f32x4 z = {};
        z = __builtin_amdgcn_mfma_f32_16x16x32_bf16(af0, b0, z, 0,0,0);
        z = __builtin_amdgcn_mfma_f32_16x16x32_bf16(af1, b1, z, 0,0,0);
        cfr[j] = z;
      }
      // lane-local online update; garbage from all-masked lanes flushed at the final reduce.
#pragma unroll
      for (int r=0;r<4;r++){
        int s_g = s0 + w*16 + quad*4 + r;
        float v0 = (tt*64      + l16 <= s_g) ? cfr[0][r]*0.125f : -1e30f;
        float v1 = (tt*64 + 16 + l16 <= s_g) ? cfr[1][r]*0.125f : -1e30f;
        float v2 = (tt*64 + 32 + l16 <= s_g) ? cfr[2][r]*0.125f : -1e30f;
        float v3 = (tt*64 + 48 + l16 <= s_g) ? cfr[3][r]*0.125f : -1e30f;
        float mt = fmaxf(fmaxf(v0,v1), fmaxf(v2,v3));
        float mn = fmaxf(m_ln[r], mt);
        l_ln[r] = l_ln[r]*__expf(m_ln[r]-mn)
                + ((__expf(v0-mn)+__expf(v1-mn)) + (__expf(v2-mn)+__expf(v3-mn)));
        m_ln[r] = mn;
      }
      cur ^= 1;
    }
    // deferred cross-lane reduction (once per band)
#pragma unroll
    for (int r=0;r<4;r++){
      float mf = m_ln[r];
#pragma unroll
      for (int mm=1; mm<16; mm<<=1) mf = fmaxf(mf, __shfl_xor(mf, mm));
      float lf = l_ln[r]*__expf(m_ln[r]-mf);
#pragma unroll
      for (int mm=1; mm<16; mm<<=1) lf += __shfl_xor(lf, mm);
      if (l16 == 0){
        long basei = ((long)(b*H_ + h))*S_ + s0 + w*16 + quad*4 + r;
        gM[basei] = mf; gL[basei] = lf;
      }
    }
  }
}

// ---------------- attention pass 2 (fused MFMA, transposed einsum) + HOSTED W2 transpose blocks ----------------
// grid (8,12,18): z<2 = attention (b=z); z>=2 = W2 tile flat=(z-2)*96+y*8+x in [0,1536):
//   W2[e] 2048x768 -> WT2[e] (768x2048), 12nx x 16ky per e.  (~50 MB under the latency-bound PV loop.)
// LDS: one 51200B pool, arithmetic offsets (no LDS-pointer arrays):
//   K@0 (8KB) | Q0@8192 Q1@16384 | V0@24576 V1@32768 | S@40960 (9216B) | smx@50176 | sli@50688
__global__ __launch_bounds__(256)
void attn_pv(const bf16* __restrict__ qkB, const bf16* __restrict__ vT,
             const float* __restrict__ gM, const float* __restrict__ gL, float* __restrict__ aoH,
             const float* __restrict__ W2, bf16* __restrict__ WT2)
{
  __shared__ __align__(16) char smem[51200];
  int tid = threadIdx.x;
  if (blockIdx.z >= 2){
    int flat = (blockIdx.z - 2)*96 + blockIdx.y*8 + blockIdx.x;   // 0..1535
    int e = flat/192, r = flat - e*192;
    transp_tile_bf16(W2 + (long)e*2048*768, WT2 + (long)e*768*2048, 768, 2048,
                     (r % 12)*64, (r / 12)*128, tid, (float(*)[64])smem);
    return;
  }
  bf16* ldsK = (bf16*)smem;
  bf16* ldsS = (bf16*)(smem + 40960);
  float* smxB = (float*)(smem + 50176);   // [2][64]
  float* sliB = (float*)(smem + 50688);   // [2][64]
  int h = blockIdx.y, b = blockIdx.z;
  int bh = b*H_ + h;
  int w = tid >> 6, lane = tid & 63;
  int quad = lane >> 4, l16 = lane & 15;
  int x7 = l16 & 7;
  const bf16* qbase = qkB + ((long)(b*S_))*QKLD + h*DH_;
  const bf16* vbase = vT + ((long)bh*DH_)*S_;
  for (int half=0; half<2; half++){
    int t0 = (half ? (S_/64 - 1 - blockIdx.x) : blockIdx.x)*64;   // paired bands: uniform 17 tiles/block
    __syncthreads();                 // protect LDS reuse across bands
    const bf16* kbase = qkB + ((long)(b*S_ + t0))*QKLD + 768 + h*DH_;
    int sb0 = t0 >> 6;
#pragma unroll
    for (int j=0;j<2;j++){
      int c = j*256 + tid;
      int row = c >> 3;
      int gs = ((c & 7) ^ (row & 7))*8;
      stage16(kbase + (long)row*QKLD + gs, ldsK + c*8);
      stage16(qbase + (long)(sb0*64 + row)*QKLD + gs, (bf16*)(smem + 8192) + c*8);
      stage16(vbase + (long)row*S_ + sb0*64 + gs, (bf16*)(smem + 24576) + c*8);
    }
    if (tid < 64){
      smxB[tid] = gM[(long)bh*S_ + sb0*64 + tid];
      sliB[tid] = 1.0f / gL[(long)bh*S_ + sb0*64 + tid];
    }
    f32x4 accO[4] = {};
    int cur = 0;
    for (int sb = sb0; sb < S_/64; sb++){
      __syncthreads();
      if (sb+1 < S_/64){
        int nb = cur^1;
        bf16* Qn = (bf16*)(smem + 8192 + (nb << 13));
        bf16* Vn = (bf16*)(smem + 24576 + (nb << 13));
#pragma unroll
        for (int j=0;j<2;j++){
          int c = j*256 + tid;
          int row = c >> 3;
          int gs = ((c & 7) ^ (row & 7))*8;
          stage16(qbase + (long)((sb+1)*64 + row)*QKLD + gs, Qn + c*8);
          stage16(vbase + (long)row*S_ + (sb+1)*64 + gs, Vn + c*8);
        }
        if (tid < 64){
          smxB[nb*64 + tid] = gM[(long)bh*S_ + (sb+1)*64 + tid];
          sliB[nb*64 + tid] = 1.0f / gL[(long)bh*S_ + (sb+1)*64 + tid];
        }
      }
      const bf16* Qc = (const bf16*)(smem + 8192 + (cur << 13));
      const bf16* Vc = (const bf16*)(smem + 24576 + (cur << 13));
      bfrag af0 = *(const bfrag*)(ldsK + (w*16 + l16)*64 + ((quad     ^ x7)*8));
      bfrag af1 = *(const bfrag*)(ldsK + (w*16 + l16)*64 + (((quad+4) ^ x7)*8));
      f32x4 cs[4];
#pragma unroll
      for (int j=0;j<4;j++){
        bfrag b0 = *(const bfrag*)(Qc + (j*16 + l16)*64 + ((quad     ^ x7)*8));
        bfrag b1 = *(const bfrag*)(Qc + (j*16 + l16)*64 + (((quad+4) ^ x7)*8));
        f32x4 z = {};
        z = __builtin_amdgcn_mfma_f32_16x16x32_bf16(af0, b0, z, 0,0,0);
        z = __builtin_amdgcn_mfma_f32_16x16x32_bf16(af1, b1, z, 0,0,0);
        cs[j] = z;
      }
#pragma unroll
      for (int j=0;j<4;j++)
#pragma unroll
        for (int r=0;r<4;r++){
          int t_loc = w*16 + quad*4 + r;
          int s_loc = j*16 + l16;
          float wgt = ((t0 + t_loc) <= (sb*64 + s_loc))
                    ? __expf(cs[j][r]*0.125f - smxB[cur*64 + s_loc])*sliB[cur*64 + s_loc] : 0.f;
          ldsS[t_loc*72 + s_loc] = __float2bfloat16(wgt);
        }
      bfrag pa0 = *(const bfrag*)(ldsS + (w*16 + l16)*72 + quad*8);
      bfrag pa1 = *(const bfrag*)(ldsS + (w*16 + l16)*72 + 32 + quad*8);
#pragma unroll
      for (int j=0;j<4;j++){
        bfrag b0 = *(const bfrag*)(Vc + (j*16 + l16)*64 + ((quad     ^ x7)*8));
        bfrag b1 = *(const bfrag*)(Vc + (j*16 + l16)*64 + (((quad+4) ^ x7)*8));
        accO[j] = __builtin_amdgcn_mfma_f32_16x16x32_bf16(pa0, b0, accO[j], 0,0,0);
        accO[j] = __builtin_amdgcn_mfma_f32_16x16x32_bf16(pa1, b1, accO[j], 0,0,0);
      }
      cur ^= 1;
    }
#pragma unroll
    for (int j=0;j<4;j++)
#pragma unroll
      for (int r=0;r<4;r++){
        int t_loc = w*16 + quad*4 + r;
        int f = j*16 + l16;
        aoH[((long)bh*S_ + t0 + t_loc)*DH_ + f] = accO[j][r];
      }
  }
}

// ---------------- binned O projection + residual: one (h,e) per block.x, W in LDS ----------------
__global__ __launch_bounds__(256)
void oproj_b(const float* __restrict__ aoH, const float* __restrict__ Wo,
             const int* __restrict__ hCnt, const int* __restrict__ hList,
             const float* __restrict__ x, float* __restrict__ x1)
{
  int he = blockIdx.x;             // h*E + e
  int h = he >> 3;
  __shared__ float Ws[DH_*DH_];    // 16 KB
  __shared__ float xsh[4][DH_];
  int tid = threadIdx.x;
  const float* W = Wo + (long)he*DH_*DH_;
  for (int i=tid; i<DH_*DH_; i+=256) Ws[i] = W[i];
  int cnt = hCnt[he];
  __syncthreads();
  int w = tid >> 6, lane = tid & 63;
  const int* lst = hList + (long)he*NTOK;
  for (int i = blockIdx.y*4 + w; i < cnt; i += 32){
    int tok = lst[i];
    int b = tok >> 10, s = tok & 1023;
    xsh[w][lane] = aoH[((long)(b*H_+h)*S_ + s)*DH_ + lane];
    float acc = 0.f;
#pragma unroll 8
    for (int f=0; f<DH_; f++) acc += xsh[w][f]*Ws[f*DH_ + lane];
    long idx = (long)tok*D_ + h*DH_ + lane;
    x1[idx] = x[idx] + acc;
  }
}

// ---------------- MoE routing: top-2, WAVE-SCAN capacity assignment (2 barriers, no LDS atomics) ----------------
__global__ __launch_bounds__(1024)
void route_kernel(const float* __restrict__ glog2, const int* __restrict__ gHist,
                  int* __restrict__ gI0, int* __restrict__ gI1,
                  int* __restrict__ gPos0, int* __restrict__ gPos1,
                  int* __restrict__ listTok, float* __restrict__ listW,
                  int* __restrict__ gCnt, float* __restrict__ auxOut)
{
  __shared__ unsigned char sI0[NTOK], sI1[NTOK];
  __shared__ float sP0[NTOK], sP1[NTOK];
  __shared__ short sPos0[NTOK], sPos1[NTOK];
  __shared__ int   waveTot[16][E_];
  __shared__ float waveImp[16][E_];
  __shared__ float sImp[E_];
  __shared__ int   sHist[NHE];
  __shared__ int   sCnt[E_];
  int tid = threadIdx.x;
  int lane = tid & 63, wv = tid >> 6;
  if (tid < NHE) sHist[tid] = gHist[tid];
  for (int i=tid; i<NTOK; i+=1024){
    const float* p = glog2 + (long)i*E_;
    float b0 = p[0]; int e0 = 0;
#pragma unroll
    for (int e=1;e<E_;e++){ float vv=p[e]; if (vv > b0){ b0=vv; e0=e; } }
    float b1v = -1e30f; int e1 = 0;
#pragma unroll
    for (int e=0;e<E_;e++){ if (e==e0) continue; float vv=p[e]; if (vv > b1v){ b1v=vv; e1=e; } }
    float ex = __expf(b1v - b0);
    float inv = 1.f/(1.f + ex);
    sI0[i] = (unsigned char)e0; sI1[i] = (unsigned char)e1;
    sP0[i] = inv; sP1[i] = ex*inv;
    gI0[i] = e0; gI1[i] = e1;
  }
  __syncthreads();
  int myCnt[E_] = {};
  unsigned char ie[4];
  int base = tid*4;
#pragma unroll
  for (int j=0;j<4;j++){
    int i = base + j;
    int tok = i >> 1;
    int e = (i & 1) ? (int)sI1[tok] : (int)sI0[tok];
    ie[j] = (unsigned char)e;
#pragma unroll
    for (int ee=0;ee<E_;ee++) myCnt[ee] += (e == ee);
  }
  int inc[E_];
#pragma unroll
  for (int e=0;e<E_;e++) inc[e] = myCnt[e];
#pragma unroll
  for (int off=1; off<64; off<<=1){
#pragma unroll
    for (int e=0;e<E_;e++){
      int v = __shfl_up(inc[e], off);
      if (lane >= off) inc[e] += v;
    }
  }
  if (lane == 63)
#pragma unroll
    for (int e=0;e<E_;e++) waveTot[wv][e] = inc[e];
  __syncthreads();
  int pref[E_];
#pragma unroll
  for (int e=0;e<E_;e++) pref[e] = inc[e] - myCnt[e];
  for (int w2=0; w2<16; w2++){
    if (w2 < wv){
#pragma unroll
      for (int e=0;e<E_;e++) pref[e] += waveTot[w2][e];
    }
  }
#pragma unroll
  for (int j=0;j<4;j++){
    int i = base + j;
    int tok = i >> 1;
    int pos = 0;
#pragma unroll
    for (int ee=0;ee<E_;ee++) if (ie[j] == ee) pos = pref[ee]++;
    short p = (pos < CAP_) ? (short)pos : (short)-1;
    if (i & 1) sPos1[tok] = p; else sPos0[tok] = p;
  }
  if (tid < E_){
    int cnt = 0;
    for (int w2=0; w2<16; w2++) cnt += waveTot[w2][tid];
    sCnt[tid] = cnt < CAP_ ? cnt : CAP_;
    gCnt[tid] = sCnt[tid];
  }
  __syncthreads();
  float impLoc[E_] = {};
  for (int i=tid; i<NTOK; i+=1024){
    int e0 = sI0[i], e1 = sI1[i];
    int p0i = sPos0[i], p1i = sPos1[i];
    float k0 = p0i >= 0 ? 1.f : 0.f, k1 = p1i >= 0 ? 1.f : 0.f;
    float p0 = sP0[i], p1 = sP1[i];
    float denom = p0*k0 + p1*k1 + 1e-9f;
    float w0 = p0*k0/denom, w1 = p1*k1/denom;
    if (p0i >= 0){
      listTok[e0*CAP_+p0i] = i; listW[e0*CAP_+p0i] = w0;
#pragma unroll
      for (int ee=0;ee<E_;ee++) impLoc[ee] += (e0 == ee) ? w0 : 0.f;
    }
    if (p1i >= 0){
      listTok[e1*CAP_+p1i] = i; listW[e1*CAP_+p1i] = w1;
#pragma unroll
      for (int ee=0;ee<E_;ee++) impLoc[ee] += (e1 == ee) ? w1 : 0.f;
    }
    gPos0[i] = p0i; gPos1[i] = p1i;
  }
#pragma unroll
  for (int off=1; off<64; off<<=1)
#pragma unroll
    for (int e=0;e<E_;e++) impLoc[e] += __shfl_xor(impLoc[e], off);
  if (lane == 0)
#pragma unroll
    for (int e=0;e<E_;e++) waveImp[wv][e] = impLoc[e];
  __syncthreads();
  if (tid < E_){
    float s = 0.f;
    for (int w2=0; w2<16; w2++) s += waveImp[w2][tid];
    sImp[tid] = s;
  }
  __syncthreads();
  if (tid == 0){
    float tot = 0.f;
    for (int i=0;i<NHE;i++) tot += (float)sHist[i]*(1.0f/NTOK)*0.01f;
    float a1 = 0.f;
    for (int i=0;i<NHE;i++){
      float p = ((float)sHist[i]*(1.0f/NTOK)*0.01f)/(tot + 1e-9f);
      a1 += p*p;
    }
    a1 *= (float)(H_*E_);
    float tcs = 0.f, ims = 0.f;
    for (int e=0;e<E_;e++){ tcs += (float)sCnt[e]; ims += sImp[e]; }
    float a2 = 0.f;
    for (int e=0;e<E_;e++) a2 += ((float)sCnt[e]/tcs)*(sImp[e]/ims);
    a2 *= (float)E_;
    auxOut[0] = a1 + a2;
  }
}

// ---------------- final combine: out = x1 + expert contributions (2 split-K slices, fp32) ----------------
__global__ __launch_bounds__(256)
void combine_kernel(const float* __restrict__ x1,
                    const float* __restrict__ Ya, const float* __restrict__ Yb,
                    const int* __restrict__ gI0, const int* __restrict__ gI1,
                    const int* __restrict__ gPos0, const int* __restrict__ gPos1,
                    float* __restrict__ out)
{
  int i = blockIdx.x;
  int tid = threadIdx.x;
  int p0 = gPos0[i], p1 = gPos1[i];
  int e0 = gI0[i],  e1 = gI1[i];
  long off0 = (long)(e0*CAPP_ + (p0 >= 0 ? p0 : 0))*D_;
  long off1 = (long)(e1*CAPP_ + (p1 >= 0 ? p1 : 0))*D_;
  const float* y0a = Ya + off0; const float* y0b = Yb + off0;
  const float* y1a = Ya + off1; const float* y1b = Yb + off1;
  for (int d=tid; d<D_; d+=256){
    float v = x1[(long)i*D_+d];
    if (p0 >= 0) v += y0a[d] + y0b[d];
    if (p1 >= 0) v += y1a[d] + y1b[d];
    out[(long)i*D_+d] = v;
  }
}

extern "C" void kernel_launch(void* const* d_in, const int* in_sizes, int n_in,
                              void* d_out, int out_size, void* d_ws, size_t ws_size,
                              hipStream_t stream)
{
  const float* x    = (const float*)d_in[0];
  const float* W_q  = (const float*)d_in[2];
  const float* W_k  = (const float*)d_in[3];
  const float* W_v  = (const float*)d_in[4];
  const float* W_o  = (const float*)d_in[5];
  const float* W_r  = (const float*)d_in[6];
  const float* g1   = (const float*)d_in[7];
  const float* b1   = (const float*)d_in[8];
  const float* g2   = (const float*)d_in[9];
  const float* b2   = (const float*)d_in[10];
  const float* gate = (const float*)d_in[11];
  const float* W1   = (const float*)d_in[12];
  const float* W2   = (const float*)d_in[13];
  float* out = (float*)d_out;

  float* wsf = (float*)d_ws;
  // ---- workspace layout (float slots) ----
  const long oX1   = 0;          // 1,572,864
  const long oLnF  = 1572864;    // fp32 2048x768; live through gemm_ffn1, then reused as split-K slice 1
  const long oLnB  = 3145728;    // bf16 2048x768
  const long oWcat = 3932160;    // bf16 1536x768 (ends 4521984)
  const long oWrT  = 4521984;    // fp32 96x768 = 73,728 (ends 4595712)
  const long oHist = 4595712;    // int 96 (attention (h,e) histogram)
  const long oHCnt = 4595808;    // int 96 ((h,e) bin counters) - adjacent: one memset covers both
  const long oGM   = 4718592;    // 24,576
  const long oGL   = 4743168;    // 24,576
  const long oEidx = 4767744;    // int 24,576
  const long oGlg2 = 4792320;    // 16,384
  const long oI0   = 4808704;
  const long oI1   = 4810752;
  const long oP0   = 4812800;
  const long oP1   = 4814848;
  const long oLT   = 4816896;
  const long oLW   = 4819456;
  const long oCnt  = 4822016;    // 8 ints
  const long SB    = 4822528;    // shared overlay region
  // attention view: qkB bf16 @SB (1.57M) | vT bf16 @+1,572,864 | aoH fp32 @+2,359,296 |
  //                 hList int @+3,932,160 (96*2048)
  // FFN view:       Hid @+7,471,104 | Yexp fp32 @+10,616,832
  const long oWT1  = SB + 12976128;      // bf16 8 x 2048x768 (6,291,456 fl) - dedicated, no overlay
  const long oWT2  = oWT1 + 6291456;     // bf16 8 x 768x2048 (6,291,456 fl)
  const long TOTAL = oWT2 + 6291456;     // 30,381,568 floats = 121.5 MB
  if (ws_size < (size_t)TOTAL*4) return;

  float* x1    = wsf + oX1;
  float* lnbF  = wsf + oLnF;
  bf16*  lnbB  = (bf16*)(wsf + oLnB);
  bf16*  WcatB = (bf16*)(wsf + oWcat);
  float* WrT   = wsf + oWrT;
  int*   gHist = (int*)(wsf + oHist);
  int*   hCnt  = (int*)(wsf + oHCnt);
  float* gM    = wsf + oGM;
  float* gL    = wsf + oGL;
  int*   eidx  = (int*)(wsf + oEidx);
  float* glog2 = wsf + oGlg2;
  int*   gI0   = (int*)(wsf + oI0);
  int*   gI1   = (int*)(wsf + oI1);
  int*   gPos0 = (int*)(wsf + oP0);
  int*   gPos1 = (int*)(wsf + oP1);
  int*   lTok  = (int*)(wsf + oLT);
  float* lW    = wsf + oLW;
  int*   gCnt  = (int*)(wsf + oCnt);
  bf16*  qkB   = (bf16*)(wsf + SB);
  bf16*  vT    = (bf16*)(wsf + SB + 1572864);
  float* aoH   = wsf + SB + 2359296;
  int*   hList = (int*)(wsf + SB + 3932160);
  bf16*  Hid   = (bf16*)(wsf + SB + 7471104);
  float* Yexp  = wsf + SB + 10616832;
  float* YexpB = wsf + oLnF;     // split-K slice 1: lnF region, dead once gemm_ffn1 completes
  bf16*  WT1   = (bf16*)(wsf + oWT1);
  bf16*  WT2   = (bf16*)(wsf + oWT2);

  // ---- counter zero + immediate-needs weight prep (Wq/Wk/Wr; W1 hosted in attn_stats, W2 in attn_pv) ----
  (void)hipMemsetAsync(gHist, 0, 2*NHE*sizeof(int), stream);
  transp_qkr<<<180,256,0,stream>>>(W_q, W_k, W_r, WcatB, WrT);

  // ---- attention phase ----
  ln_kernel<<<NTOK,256,0,stream>>>(x, g1, b1, lnbF, lnbB, nullptr, nullptr);
  gemm_bn64<<<dim3(24,16,1),256,0,stream>>>(lnbB, WcatB, qkB, nullptr, 2048, QKLD, 768, 0,0,0, 0, 1, 1);
  router_argmax<<<NTOK/RTOK,768,0,stream>>>(lnbF, WrT, eidx, gHist, hCnt, hList);
  vsel_b<<<dim3(NHE,8,1),256,0,stream>>>(lnbF, W_v, hCnt, hList, vT);
  // z 0..1 = attention; z 2..17 = hosted W1 transposes (1536 blocks riding idle CUs)
  attn_stats_mfma<<<dim3(S_/128,H_,2+16),256,0,stream>>>(qkB, gM, gL, W1, WT1);
  // z 0..1 = attention; z 2..17 = hosted W2 transposes (1536 blocks under the PV latency)
  attn_pv<<<dim3(S_/128,H_,2+16),256,0,stream>>>(qkB, vT, gM, gL, aoH, W2, WT2);
  oproj_b<<<dim3(NHE,8,1),256,0,stream>>>(aoH, W_o, hCnt, hList, x, x1);

  // ---- FFN phase (gather fused into W1 GEMM; WT1 ready since attn_stats, WT2 since attn_pv) ----
  ln_kernel<<<NTOK,256,0,stream>>>(x1, g2, b2, lnbF, nullptr, gate, glog2);  // fused gate logits
  route_kernel<<<1,1024,0,stream>>>(glog2, gHist, gI0,gI1,gPos0,gPos1, lTok,lW,gCnt, out + (size_t)NTOK*D_);
  gemm_ffn1<<<dim3(32,3,8),256,0,stream>>>(lnbF, WT1, Hid, lTok, lW, gCnt);
  gemm_bn64<<<dim3(12,3,16),256,0,stream>>>(Hid, WT2, Yexp, YexpB, CAPP_, 768, 2048,
                                            (long)CAPP_*2048, (long)768*2048, (long)CAPP_*768, 0, 0, 2);
  combine_kernel<<<NTOK,256,0,stream>>>(x1, Yexp, YexpB, gI0,gI1,gPos0,gPos1, out);
}

// Round 11
// 362.853 us; speedup vs baseline: 1.0902x; 1.0430x over previous
//
#include <hip/hip_runtime.h>
#include <hip/hip_bf16.h>
#include <cstdint>

typedef __hip_bfloat16 bf16;
typedef __attribute__((ext_vector_type(8))) __bf16 bfrag;   // MFMA A/B operand (4 VGPRs)
typedef __attribute__((ext_vector_type(4))) float f32x4;    // MFMA C/D operand

#define B_    2
#define S_    1024
#define D_    768
#define H_    12
#define E_    8
#define DH_   64
#define DFF_  2048
#define CAP_  320            // ceil(1.25 * 2048 / 8)
#define CAPP_ 384            // CAP padded to 128-multiple for MFMA tiles
#define NTOK  (B_*S_)        // 2048
#define NTH   (NTOK*H_)      // 24576
#define QKLD  1536           // fused q|k row stride
#define NHE   (H_*E_)        // 96 (h,e) bins

// ---------------- async global->LDS 16B stage (per-lane global addr, lane-linear LDS) ----------------
__device__ __forceinline__ void stage16(const bf16* g, bf16* ldsLane){
#if __has_builtin(__builtin_amdgcn_global_load_lds)
  __builtin_amdgcn_global_load_lds((const __attribute__((address_space(1))) unsigned int*)g,
                                   (__attribute__((address_space(3))) unsigned int*)ldsLane, 16, 0, 0);
#else
  *(bfrag*)ldsLane = *(const bfrag*)g;
#endif
}

// ---------------- shared transpose tile body: 64n x 128k, XOR-swizzled LDS, 256B write runs ----------------
__device__ __forceinline__ void transp_tile_bf16(const float* __restrict__ src, bf16* __restrict__ dst,
                                                 int N, int K, int n0, int k0, int tid, float (*t)[64])
{
  int chunk = tid & 15, rgrp = tid >> 4;
#pragma unroll
  for (int rr=0; rr<8; rr++){
    int row = rr*16 + rgrp;
    float4 v = *(const float4*)(src + (long)(k0+row)*N + n0 + chunk*4);
    *(float4*)&t[row][((chunk ^ (row>>3)) & 15)*4] = v;
  }
  __syncthreads();
#pragma unroll
  for (int it=0; it<4; it++){
    int slot = it*256 + tid;
    int n = slot >> 4, kc = slot & 15;      // 16 lanes (kc 0..15) cover one full 128-bf16 output row
    union { bfrag f; bf16 h[8]; } o;
#pragma unroll
    for (int i=0;i<8;i++){
      int row = kc*8 + i;                   // (row>>3)&15 == kc
      o.h[i] = __float2bfloat16(t[row][n ^ (kc*4)]);
    }
    *(bfrag*)(dst + (long)(n0+n)*K + k0 + kc*8) = o.f;
  }
}

// ---------------- Wq|Wk|Wr prep (needed immediately): 180 blocks ----------------
__global__ __launch_bounds__(256)
void transp_qkr(const float* __restrict__ Wq, const float* __restrict__ Wk,
                const float* __restrict__ Wr, bf16* __restrict__ WcatB, float* __restrict__ WrT)
{
  __shared__ float t[128][64];
  int bid = blockIdx.x, tid = threadIdx.x;
  if (bid < 144){
    const float* src; bf16* dst; int r;
    if (bid < 72){ src = Wq; dst = WcatB; r = bid; }
    else         { src = Wk; dst = WcatB + (long)768*768; r = bid - 72; }
    transp_tile_bf16(src, dst, 768, 768, (r%12)*64, (r/12)*128, tid, t);
  } else {
    int r = bid - 144;
    int n0 = (r % 3)*32, k0 = (r / 3)*64;
    int chunk = tid & 7, row2 = tid >> 3;
#pragma unroll
    for (int rr=0; rr<2; rr++){
      int row = rr*32 + row2;
      float4 v = *(const float4*)(Wr + (long)(k0+row)*96 + n0 + chunk*4);
      *(float4*)&t[row][chunk*4] = v;
    }
    __syncthreads();
    int chunkw = tid & 15, ng = tid >> 4;
#pragma unroll
    for (int rr=0; rr<2; rr++){
      int n = rr*16 + ng;
      float4 o;
      o.x = t[chunkw*4+0][n]; o.y = t[chunkw*4+1][n];
      o.z = t[chunkw*4+2][n]; o.w = t[chunkw*4+3][n];
      *(float4*)(WrT + (long)(n0+n)*768 + k0 + chunkw*4) = o;
    }
  }
}

// ---------------- QK GEMM (2048x1536x768) + HOSTED router blocks ----------------
// grid (24,16,3): z=0 -> gemm tile (XCD swizzle over 384); z>=1 -> router flat=(z-1)*384+y*24+x,
// run if flat<512, tok0=flat*4.  Router and gemm both depend only on ln1 outputs (independent).
// LDS pool 24576B: gemm As[2]@0 (2x8KB), Bs[2]@16384 (2x4KB); router xrow@0 (12288B), logits@12288.
#define RTOK 4
__global__ __launch_bounds__(256)
void gemm_qk(const bf16* __restrict__ A, const bf16* __restrict__ Bt, bf16* __restrict__ C,
             const float* __restrict__ ln1, const float* __restrict__ WrT,
             int* __restrict__ eidx, int* __restrict__ gHist,
             int* __restrict__ hCnt, int* __restrict__ hList)
{
  __shared__ __align__(16) char smem[24576];
  int tid = threadIdx.x;
  if (blockIdx.z >= 1){
    int flat = (blockIdx.z - 1)*384 + blockIdx.y*24 + blockIdx.x;
    if (flat >= NTOK/RTOK) return;
    int tok0 = flat*RTOK;
    float* xrow = (float*)smem;                 // [RTOK][768]
    float* logits = (float*)(smem + 12288);     // [RTOK][96]
    // load 4 token rows (768 float4 total, 3 per thread)
#pragma unroll
    for (int k=0;k<3;k++){
      int idx = tid + k*256;                    // 0..767 float4 slots
      int t = idx / 192, dpos = (idx - t*192)*4;
      *(float4*)&xrow[t*768 + dpos] = *(const float4*)(ln1 + (long)(tok0+t)*D_ + dpos);
    }
    __syncthreads();
    int col = tid >> 1, seg = tid & 1;          // 96 cols x 2 segs (threads 192..255 idle)
    if (col < 96){
      const float* wrow = WrT + (long)col*D_;
      float acc[RTOK] = {};
#pragma unroll
      for (int j=0;j<96;j++){
        int dbase = j*8 + seg*4;
        float4 w = *(const float4*)(wrow + dbase);
#pragma unroll
        for (int t=0;t<RTOK;t++){
          float4 xv = *(const float4*)(&xrow[t*768 + dbase]);
          acc[t] += xv.x*w.x + xv.y*w.y + xv.z*w.z + xv.w*w.w;
        }
      }
#pragma unroll
      for (int t=0;t<RTOK;t++) acc[t] += __shfl_xor(acc[t], 1);
      if (seg == 0)
#pragma unroll
        for (int t=0;t<RTOK;t++) logits[t*96 + col] = acc[t];
    }
    __syncthreads();
    if (tid < RTOK*H_){
      int t = tid / H_, h = tid % H_;
      const float* p = &logits[t*96 + h*8];
      float best = p[0]; int bi = 0;
#pragma unroll
      for (int e=1;e<8;e++){ float v=p[e]; if (v > best){ best=v; bi=e; } }
      int tok = tok0 + t;
      eidx[tok*H_ + h] = bi;
      atomicAdd(&gHist[h*E_ + bi], 1);
      int he = h*E_ + bi;
      int pos = atomicAdd(&hCnt[he], 1);
      hList[he*NTOK + pos] = tok;
    }
    return;
  }
  // ---- gemm branch: M=2048 N=1536 K=768, bf16 out ----
  int bid = blockIdx.x + 24*blockIdx.y;
  int nid = (bid & 7)*48 + (bid >> 3);          // bijective over 384
  int bx = nid % 24, by = nid / 24;
  int m0 = by*128, n0 = bx*64;
  int w = tid >> 6, lane = tid & 63;
  int quad = lane >> 4, l16 = lane & 15;
  int wm = w*32;
  f32x4 acc[2][4] = {};
  int srow = (lane >> 2);
  int gsw  = ((lane & 3) ^ (srow & 3))*8;
  const bf16* aBase = A + (long)m0*768;
  const bf16* bBase = Bt + (long)n0*768;
  int xr = (l16 & 3);
  const int nIt = 24;
  {
#pragma unroll
    for (int j=0;j<2;j++){
      int c = w*2 + j, row = c*16 + srow;
      stage16(aBase + (long)row*768 + gsw, (bf16*)smem + c*512 + lane*8);
    }
    int rowb = w*16 + srow;
    stage16(bBase + (long)rowb*768 + gsw, (bf16*)(smem + 16384) + w*512 + lane*8);
  }
  int cur = 0;
  for (int it=0; it<nIt; ++it){
    __syncthreads();
    if (it+1 < nIt){
      int k0 = (it+1)*32;
      int nb = cur^1;
      bf16* An = (bf16*)(smem + (nb<<13));
      bf16* Bn = (bf16*)(smem + 16384 + (nb<<12));
#pragma unroll
      for (int j=0;j<2;j++){
        int c = w*2 + j, row = c*16 + srow;
        stage16(aBase + (long)row*768 + k0 + gsw, An + c*512 + lane*8);
      }
      int rowb = w*16 + srow;
      stage16(bBase + (long)rowb*768 + k0 + gsw, Bn + w*512 + lane*8);
    }
    const bf16* Ac = (const bf16*)(smem + (cur<<13));
    const bf16* Bc = (const bf16*)(smem + 16384 + (cur<<12));
    bfrag af[2], bfv[4];
#pragma unroll
    for (int t=0;t<2;t++) af[t]  = *(const bfrag*)(Ac + (wm + t*16 + l16)*32 + ((quad ^ xr)*8));
#pragma unroll
    for (int t=0;t<4;t++) bfv[t] = *(const bfrag*)(Bc + (t*16 + l16)*32 + ((quad ^ xr)*8));
#pragma unroll
    for (int ti=0;ti<2;ti++)
#pragma unroll
      for (int tj=0;tj<4;tj++)
        acc[ti][tj] = __builtin_amdgcn_mfma_f32_16x16x32_bf16(af[ti], bfv[tj], acc[ti][tj], 0, 0, 0);
    cur ^= 1;
  }
#pragma unroll
  for (int ti=0;ti<2;ti++)
#pragma unroll
    for (int tj=0;tj<4;tj++)
#pragma unroll
      for (int r=0;r<4;r++){
        int row = m0 + wm + ti*16 + quad*4 + r;
        int col = n0 + tj*16 + l16;
        C[(long)row*QKLD + col] = __float2bfloat16(acc[ti][tj][r]);
      }
}

// ---------------- generic MFMA GEMM (used for W2), split-K, 2-phase dbuf ----------------
__global__ __launch_bounds__(256)
void gemm_bn64(const bf16* __restrict__ A, const bf16* __restrict__ Bt,
               void* __restrict__ C, void* __restrict__ C2,
               int M, int N, int K, long sA, long sB, long sC, int relu, int outBf, int kSplit)
{
  int nwg = gridDim.x*gridDim.y*gridDim.z;
  int bid = blockIdx.x + gridDim.x*(blockIdx.y + gridDim.y*blockIdx.z);
  int nid = (bid & 7)*(nwg >> 3) + (bid >> 3);        // bijective: nwg % 8 == 0
  int bx = nid % gridDim.x;
  int t1 = nid / gridDim.x;
  int by = t1 % gridDim.y;
  int bz = t1 / gridDim.y;
  int e  = bz / kSplit, kc = bz - e*kSplit;
  A  += (long)e*sA;
  Bt += (long)e*sB;
  int kLen = K / kSplit, kBase = kc*kLen;
  int m0 = by*128, n0 = bx*64;
  __shared__ bf16 As[2][128*32];
  __shared__ bf16 Bs[2][64*32];
  int tid = threadIdx.x;
  int w = tid >> 6, lane = tid & 63;
  int quad = lane >> 4, l16 = lane & 15;
  int wm = w*32;
  f32x4 acc[2][4] = {};
  int srow = (lane >> 2);
  int gsw  = ((lane & 3) ^ (srow & 3))*8;
  const bf16* aBase = A + (long)m0*K;
  const bf16* bBase = Bt + (long)n0*K;
  int xr = (l16 & 3);
  int nIt = kLen >> 5;
  {
    int k0 = kBase;
#pragma unroll
    for (int j=0;j<2;j++){
      int c = w*2 + j, row = c*16 + srow;
      stage16(aBase + (long)row*K + k0 + gsw, As[0] + c*512 + lane*8);
    }
    int rowb = w*16 + srow;
    stage16(bBase + (long)rowb*K + k0 + gsw, Bs[0] + w*512 + lane*8);
  }
  int cur = 0;
  for (int it=0; it<nIt; ++it){
    __syncthreads();
    if (it+1 < nIt){
      int k0 = kBase + (it+1)*32;
      int nb = cur^1;
#pragma unroll
      for (int j=0;j<2;j++){
        int c = w*2 + j, row = c*16 + srow;
        stage16(aBase + (long)row*K + k0 + gsw, As[nb] + c*512 + lane*8);
      }
      int rowb = w*16 + srow;
      stage16(bBase + (long)rowb*K + k0 + gsw, Bs[nb] + w*512 + lane*8);
    }
    const bf16* Ac = As[cur];
    const bf16* Bc = Bs[cur];
    bfrag af[2], bfv[4];
#pragma unroll
    for (int t=0;t<2;t++) af[t]  = *(const bfrag*)(Ac + (wm + t*16 + l16)*32 + ((quad ^ xr)*8));
#pragma unroll
    for (int t=0;t<4;t++) bfv[t] = *(const bfrag*)(Bc + (t*16 + l16)*32 + ((quad ^ xr)*8));
#pragma unroll
    for (int ti=0;ti<2;ti++)
#pragma unroll
      for (int tj=0;tj<4;tj++)
        acc[ti][tj] = __builtin_amdgcn_mfma_f32_16x16x32_bf16(af[ti], bfv[tj], acc[ti][tj], 0, 0, 0);
    cur ^= 1;
  }
  long zoff = (long)e*sC;
  void* Cp = kc ? C2 : C;
  if (outBf){
    bf16* Cb = (bf16*)Cp + zoff;
#pragma unroll
    for (int ti=0;ti<2;ti++)
#pragma unroll
      for (int tj=0;tj<4;tj++)
#pragma unroll
        for (int r=0;r<4;r++){
          int row = m0 + wm + ti*16 + quad*4 + r;
          int col = n0 + tj*16 + l16;
          float v = acc[ti][tj][r];
          if (relu) v = fmaxf(v, 0.f);
          Cb[(long)row*N + col] = __float2bfloat16(v);
        }
  } else {
    float* Cf = (float*)Cp + zoff;
#pragma unroll
    for (int ti=0;ti<2;ti++)
#pragma unroll
      for (int tj=0;tj<4;tj++)
#pragma unroll
        for (int r=0;r<4;r++){
          int row = m0 + wm + ti*16 + quad*4 + r;
          int col = n0 + tj*16 + l16;
          float v = acc[ti][tj][r];
          if (relu) v = fmaxf(v, 0.f);
          Cf[(long)row*N + col] = v;
        }
  }
}

// ---------------- W1 GEMM with FUSED gather: A reg-staged from fp32 ln2 via token list ----------------
__global__ __launch_bounds__(256)
void gemm_ffn1(const float* __restrict__ ln2, const bf16* __restrict__ Bt, bf16* __restrict__ C,
               const int* __restrict__ lTok, const float* __restrict__ lW, const int* __restrict__ gCnt)
{
  int nwg = gridDim.x*gridDim.y*gridDim.z;   // 32*3*8 = 768
  int bid = blockIdx.x + gridDim.x*(blockIdx.y + gridDim.y*blockIdx.z);
  int nid = (bid & 7)*(nwg >> 3) + (bid >> 3);
  int bx = nid % gridDim.x;
  int t1 = nid / gridDim.x;
  int by = t1 % gridDim.y;
  int e  = t1 / gridDim.y;
  int m0 = by*128;
  const bf16* bBase = Bt + (long)e*2048*768 + (long)(bx*64)*768;
  __shared__ bf16 As[2][128*32];
  __shared__ bf16 Bs[2][64*32];
  int tid = threadIdx.x;
  int w = tid >> 6, lane = tid & 63;
  int quad = lane >> 4, l16 = lane & 15;
  int wm = w*32;
  f32x4 acc[2][4] = {};
  int srow = (lane >> 2);
  int gsw  = ((lane & 3) ^ (srow & 3))*8;
  int xr = (l16 & 3);
  int cnt = gCnt[e];
  int tokA[2]; float wA[2];
#pragma unroll
  for (int j=0;j<2;j++){
    int row = m0 + (w*2+j)*16 + srow;
    bool live = row < cnt;
    tokA[j] = live ? lTok[e*CAP_ + row] : 0;
    wA[j]   = live ? lW[e*CAP_ + row]   : 0.f;
  }
  const int nIt = 24;   // 768/32
  {
#pragma unroll
    for (int j=0;j<2;j++){
      const float* src = ln2 + (long)tokA[j]*D_ + gsw;
      float4 a0 = *(const float4*)(src);
      float4 a1 = *(const float4*)(src+4);
      union { bfrag f; bf16 h[8]; } o;
      o.h[0]=__float2bfloat16(a0.x*wA[j]); o.h[1]=__float2bfloat16(a0.y*wA[j]);
      o.h[2]=__float2bfloat16(a0.z*wA[j]); o.h[3]=__float2bfloat16(a0.w*wA[j]);
      o.h[4]=__float2bfloat16(a1.x*wA[j]); o.h[5]=__float2bfloat16(a1.y*wA[j]);
      o.h[6]=__float2bfloat16(a1.z*wA[j]); o.h[7]=__float2bfloat16(a1.w*wA[j]);
      *(bfrag*)(As[0] + (w*2+j)*512 + lane*8) = o.f;
    }
    int rowb = w*16 + srow;
    stage16(bBase + (long)rowb*768 + gsw, Bs[0] + w*512 + lane*8);
  }
  int cur = 0;
  for (int it=0; it<nIt; ++it){
    __syncthreads();
    float4 a0[2], a1[2];
    if (it+1 < nIt){
      int k0 = (it+1)*32;
#pragma unroll
      for (int j=0;j<2;j++){           // issue A loads early: latency hides under MFMA below
        const float* src = ln2 + (long)tokA[j]*D_ + k0 + gsw;
        a0[j] = *(const float4*)(src);
        a1[j] = *(const float4*)(src+4);
      }
      int rowb = w*16 + srow;
      stage16(bBase + (long)rowb*768 + k0 + gsw, Bs[cur^1] + w*512 + lane*8);
    }
    const bf16* Ac = As[cur];
    const bf16* Bc = Bs[cur];
    bfrag af[2], bfv[4];
#pragma unroll
    for (int t=0;t<2;t++) af[t]  = *(const bfrag*)(Ac + (wm + t*16 + l16)*32 + ((quad ^ xr)*8));
#pragma unroll
    for (int t=0;t<4;t++) bfv[t] = *(const bfrag*)(Bc + (t*16 + l16)*32 + ((quad ^ xr)*8));
#pragma unroll
    for (int ti=0;ti<2;ti++)
#pragma unroll
      for (int tj=0;tj<4;tj++)
        acc[ti][tj] = __builtin_amdgcn_mfma_f32_16x16x32_bf16(af[ti], bfv[tj], acc[ti][tj], 0, 0, 0);
    if (it+1 < nIt){
      int nb = cur^1;
#pragma unroll
      for (int j=0;j<2;j++){
        union { bfrag f; bf16 h[8]; } o;
        o.h[0]=__float2bfloat16(a0[j].x*wA[j]); o.h[1]=__float2bfloat16(a0[j].y*wA[j]);
        o.h[2]=__float2bfloat16(a0[j].z*wA[j]); o.h[3]=__float2bfloat16(a0[j].w*wA[j]);
        o.h[4]=__float2bfloat16(a1[j].x*wA[j]); o.h[5]=__float2bfloat16(a1[j].y*wA[j]);
        o.h[6]=__float2bfloat16(a1[j].z*wA[j]); o.h[7]=__float2bfloat16(a1[j].w*wA[j]);
        *(bfrag*)(As[nb] + (w*2+j)*512 + lane*8) = o.f;
      }
    }
    cur ^= 1;
  }
  bf16* Cb = C + (long)e*CAPP_*DFF_;
#pragma unroll
  for (int ti=0;ti<2;ti++)
#pragma unroll
    for (int tj=0;tj<4;tj++)
#pragma unroll
      for (int r=0;r<4;r++){
        int row = m0 + wm + ti*16 + quad*4 + r;
        int col = bx*64 + tj*16 + l16;
        Cb[(long)row*DFF_ + col] = __float2bfloat16(fmaxf(acc[ti][tj][r], 0.f));
      }
}

// ---------------- LayerNorm: fp32 in -> fp32 out (+ optional bf16 copy, + optional fused gate logits) ----------------
__global__ __launch_bounds__(256)
void ln_kernel(const float* __restrict__ src, const float* __restrict__ g, const float* __restrict__ bb,
               float* __restrict__ dstF, bf16* __restrict__ dstB,
               const float* __restrict__ gateW, float* __restrict__ glog2)
{
  int row = blockIdx.x, tid = threadIdx.x;
  __shared__ float red[256];
  __shared__ float gsum[4][E_];
  float v[3];
#pragma unroll
  for (int j=0;j<3;j++) v[j] = src[(long)row*D_ + tid + j*256];
  float s = v[0]+v[1]+v[2];
  red[tid]=s; __syncthreads();
  for (int o=128;o>0;o>>=1){ if(tid<o) red[tid]+=red[tid+o]; __syncthreads(); }
  float mean = red[0]*(1.0f/D_);
  __syncthreads();
  float sq = 0.f;
#pragma unroll
  for (int j=0;j<3;j++){ float d=v[j]-mean; sq += d*d; }
  red[tid]=sq; __syncthreads();
  for (int o=128;o>0;o>>=1){ if(tid<o) red[tid]+=red[tid+o]; __syncthreads(); }
  float rstd = rsqrtf(red[0]*(1.0f/D_) + 1e-5f);
  float ov[3];
#pragma unroll
  for (int j=0;j<3;j++){
    int d = tid + j*256;
    float o = (v[j]-mean)*rstd*g[d] + bb[d];
    ov[j] = o;
    dstF[(long)row*D_+d] = o;
    if (dstB) dstB[(long)row*D_+d] = __float2bfloat16(o);
  }
  if (gateW){
    float gp[E_] = {};
#pragma unroll
    for (int j=0;j<3;j++){
      int d = tid + j*256;
      const float* gw = gateW + (long)d*E_;
#pragma unroll
      for (int e=0;e<E_;e++) gp[e] += ov[j]*gw[e];
    }
#pragma unroll
    for (int off=1; off<64; off<<=1)
#pragma unroll
      for (int e=0;e<E_;e++) gp[e] += __shfl_xor(gp[e], off);
    if ((tid & 63) == 0)
#pragma unroll
      for (int e=0;e<E_;e++) gsum[tid>>6][e] = gp[e];
    __syncthreads();
    if (tid < E_)
      glog2[(long)row*E_ + tid] = gsum[0][tid]+gsum[1][tid]+gsum[2][tid]+gsum[3][tid];
  }
}

// ---------------- attention pass 1 (MFMA flash stats) + HOSTED W1 transposes + HOSTED vsel ----------------
// grid (8,12,26): z<2 = attention (b=z); z in [2,18) = W1 tile flat=(z-2)*96+y*8+x in [0,1536);
// z in [18,26) = vsel bin-block: he = y*8+x, chunk = z-18 (8 chunks x 4 waves stride 32).
__global__ __launch_bounds__(256)
void attn_stats_mfma(const bf16* __restrict__ qkB, float* __restrict__ gM, float* __restrict__ gL,
                     const float* __restrict__ W1, bf16* __restrict__ WT1,
                     const float* __restrict__ ln1, const float* __restrict__ Wv,
                     const int* __restrict__ hCnt, const int* __restrict__ hList,
                     bf16* __restrict__ vT)
{
  __shared__ __align__(16) char smem[32768];
  int tid = threadIdx.x;
  if (blockIdx.z >= 18){
    // ---- vsel branch: one (h,e) bin per (y*8+x), chunk = z-18 ----
    int vs = blockIdx.z - 18;
    int he = blockIdx.y*8 + blockIdx.x;
    int h = he >> 3;
    float* Ws  = (float*)smem;                 // 16 KB
    float* xsh = (float*)(smem + 16384);       // 4x64 floats
    const float* W = Wv + (long)he*DH_*DH_;
    for (int i=tid; i<DH_*DH_; i+=256) Ws[i] = W[i];
    int cnt = hCnt[he];
    __syncthreads();
    int w = tid >> 6, lane = tid & 63;
    const int* lst = hList + (long)he*NTOK;
    for (int i = vs*4 + w; i < cnt; i += 32){
      int tok = lst[i];
      int b = tok >> 10, s = tok & 1023;
      xsh[w*64 + lane] = ln1[(long)tok*D_ + h*DH_ + lane];
      float acc = 0.f;
#pragma unroll 8
      for (int d=0; d<DH_; d++) acc += xsh[w*64 + d]*Ws[d*DH_ + lane];
      vT[((long)(b*H_+h)*DH_ + lane)*S_ + s] = __float2bfloat16(acc);
    }
    return;
  }
  if (blockIdx.z >= 2){
    int flat = (blockIdx.z - 2)*96 + blockIdx.y*8 + blockIdx.x;   // 0..1535
    int e = flat/192, r = flat - e*192;
    transp_tile_bf16(W1 + (long)e*768*2048, WT1 + (long)e*2048*768, 2048, 768,
                     (r % 32)*64, (r / 32)*128, tid, (float(*)[64])smem);
    return;
  }
  bf16* ldsQ = (bf16*)smem;                 // 8 KB; K buffers at +8192, +16384
  int h = blockIdx.y, b = blockIdx.z;
  int w = tid >> 6, lane = tid & 63;
  int quad = lane >> 4, l16 = lane & 15;
  int x7 = l16 & 7;
  const bf16* kbase = qkB + ((long)(b*S_))*QKLD + 768 + h*DH_;
  for (int half=0; half<2; half++){
    int s0 = (half ? (S_/64 - 1 - blockIdx.x) : blockIdx.x)*64;   // paired bands: uniform 17 tiles
    __syncthreads();
    const bf16* qbase = qkB + ((long)(b*S_ + s0))*QKLD + h*DH_;
#pragma unroll
    for (int j=0;j<2;j++){
      int c = j*256 + tid;
      int row = c >> 3;
      int gs = ((c & 7) ^ (row & 7))*8;
      stage16(qbase + (long)row*QKLD + gs, ldsQ + c*8);
      stage16(kbase + (long)row*QKLD + gs, (bf16*)(smem + 8192) + c*8);
    }
    float m_ln[4] = {-1e30f,-1e30f,-1e30f,-1e30f};
    float l_ln[4] = {0.f,0.f,0.f,0.f};
    int ttEnd = s0 >> 6;
    int cur = 0;
    for (int tt=0; tt<=ttEnd; tt++){
      __syncthreads();
      if (tt < ttEnd){
        bf16* Kn = (bf16*)(smem + 8192 + ((cur^1) << 13));
#pragma unroll
        for (int j=0;j<2;j++){
          int c = j*256 + tid;
          int row = c >> 3;
          int gs = ((c & 7) ^ (row & 7))*8;
          stage16(kbase + (long)((tt+1)*64 + row)*QKLD + gs, Kn + c*8);
        }
      }
      const bf16* Kc = (const bf16*)(smem + 8192 + (cur << 13));
      bfrag af0 = *(const bfrag*)(ldsQ + (w*16 + l16)*64 + ((quad     ^ x7)*8));
      bfrag af1 = *(const bfrag*)(ldsQ + (w*16 + l16)*64 + (((quad+4) ^ x7)*8));
      f32x4 cfr[4];
#pragma unroll
      for (int j=0;j<4;j++){
        bfrag b0 = *(const bfrag*)(Kc + (j*16 + l16)*64 + ((quad     ^ x7)*8));
        bfrag b1 = *(const bfrag*)(Kc + (j*16 + l16)*64 + (((quad+4) ^ x7)*8));
        f32x4 z = {};
        z = __builtin_amdgcn_mfma_f32_16x16x32_bf16(af0, b0, z, 0,0,0);
        z = __builtin_amdgcn_mfma_f32_16x16x32_bf16(af1, b1, z, 0,0,0);
        cfr[j] = z;
      }
#pragma unroll
      for (int r=0;r<4;r++){
        int s_g = s0 + w*16 + quad*4 + r;
        float v0 = (tt*64      + l16 <= s_g) ? cfr[0][r]*0.125f : -1e30f;
        float v1 = (tt*64 + 16 + l16 <= s_g) ? cfr[1][r]*0.125f : -1e30f;
        float v2 = (tt*64 + 32 + l16 <= s_g) ? cfr[2][r]*0.125f : -1e30f;
        float v3 = (tt*64 + 48 + l16 <= s_g) ? cfr[3][r]*0.125f : -1e30f;
        float mt = fmaxf(fmaxf(v0,v1), fmaxf(v2,v3));
        float mn = fmaxf(m_ln[r], mt);
        l_ln[r] = l_ln[r]*__expf(m_ln[r]-mn)
                + ((__expf(v0-mn)+__expf(v1-mn)) + (__expf(v2-mn)+__expf(v3-mn)));
        m_ln[r] = mn;
      }
      cur ^= 1;
    }
#pragma unroll
    for (int r=0;r<4;r++){
      float mf = m_ln[r];
#pragma unroll
      for (int mm=1; mm<16; mm<<=1) mf = fmaxf(mf, __shfl_xor(mf, mm));
      float lf = l_ln[r]*__expf(m_ln[r]-mf);
#pragma unroll
      for (int mm=1; mm<16; mm<<=1) lf += __shfl_xor(lf, mm);
      if (l16 == 0){
        long basei = ((long)(b*H_ + h))*S_ + s0 + w*16 + quad*4 + r;
        gM[basei] = mf; gL[basei] = lf;
      }
    }
  }
}

// ---------------- attention pass 2 (fused MFMA, transposed einsum) + HOSTED W2 transpose blocks ----------------
__global__ __launch_bounds__(256)
void attn_pv(const bf16* __restrict__ qkB, const bf16* __restrict__ vT,
             const float* __restrict__ gM, const float* __restrict__ gL, float* __restrict__ aoH,
             const float* __restrict__ W2, bf16* __restrict__ WT2)
{
  __shared__ __align__(16) char smem[51200];
  int tid = threadIdx.x;
  if (blockIdx.z >= 2){
    int flat = (blockIdx.z - 2)*96 + blockIdx.y*8 + blockIdx.x;   // 0..1535
    int e = flat/192, r = flat - e*192;
    transp_tile_bf16(W2 + (long)e*2048*768, WT2 + (long)e*768*2048, 768, 2048,
                     (r % 12)*64, (r / 12)*128, tid, (float(*)[64])smem);
    return;
  }
  bf16* ldsK = (bf16*)smem;
  bf16* ldsS = (bf16*)(smem + 40960);
  float* smxB = (float*)(smem + 50176);   // [2][64]
  float* sliB = (float*)(smem + 50688);   // [2][64]
  int h = blockIdx.y, b = blockIdx.z;
  int bh = b*H_ + h;
  int w = tid >> 6, lane = tid & 63;
  int quad = lane >> 4, l16 = lane & 15;
  int x7 = l16 & 7;
  const bf16* qbase = qkB + ((long)(b*S_))*QKLD + h*DH_;
  const bf16* vbase = vT + ((long)bh*DH_)*S_;
  for (int half=0; half<2; half++){
    int t0 = (half ? (S_/64 - 1 - blockIdx.x) : blockIdx.x)*64;
    __syncthreads();
    const bf16* kbase = qkB + ((long)(b*S_ + t0))*QKLD + 768 + h*DH_;
    int sb0 = t0 >> 6;
#pragma unroll
    for (int j=0;j<2;j++){
      int c = j*256 + tid;
      int row = c >> 3;
      int gs = ((c & 7) ^ (row & 7))*8;
      stage16(kbase + (long)row*QKLD + gs, ldsK + c*8);
      stage16(qbase + (long)(sb0*64 + row)*QKLD + gs, (bf16*)(smem + 8192) + c*8);
      stage16(vbase + (long)row*S_ + sb0*64 + gs, (bf16*)(smem + 24576) + c*8);
    }
    if (tid < 64){
      smxB[tid] = gM[(long)bh*S_ + sb0*64 + tid];
      sliB[tid] = 1.0f / gL[(long)bh*S_ + sb0*64 + tid];
    }
    f32x4 accO[4] = {};
    int cur = 0;
    for (int sb = sb0; sb < S_/64; sb++){
      __syncthreads();
      if (sb+1 < S_/64){
        int nb = cur^1;
        bf16* Qn = (bf16*)(smem + 8192 + (nb << 13));
        bf16* Vn = (bf16*)(smem + 24576 + (nb << 13));
#pragma unroll
        for (int j=0;j<2;j++){
          int c = j*256 + tid;
          int row = c >> 3;
          int gs = ((c & 7) ^ (row & 7))*8;
          stage16(qbase + (long)((sb+1)*64 + row)*QKLD + gs, Qn + c*8);
          stage16(vbase + (long)row*S_ + (sb+1)*64 + gs, Vn + c*8);
        }
        if (tid < 64){
          smxB[nb*64 + tid] = gM[(long)bh*S_ + (sb+1)*64 + tid];
          sliB[nb*64 + tid] = 1.0f / gL[(long)bh*S_ + (sb+1)*64 + tid];
        }
      }
      const bf16* Qc = (const bf16*)(smem + 8192 + (cur << 13));
      const bf16* Vc = (const bf16*)(smem + 24576 + (cur << 13));
      bfrag af0 = *(const bfrag*)(ldsK + (w*16 + l16)*64 + ((quad     ^ x7)*8));
      bfrag af1 = *(const bfrag*)(ldsK + (w*16 + l16)*64 + (((quad+4) ^ x7)*8));
      f32x4 cs[4];
#pragma unroll
      for (int j=0;j<4;j++){
        bfrag b0 = *(const bfrag*)(Qc + (j*16 + l16)*64 + ((quad     ^ x7)*8));
        bfrag b1 = *(const bfrag*)(Qc + (j*16 + l16)*64 + (((quad+4) ^ x7)*8));
        f32x4 z = {};
        z = __builtin_amdgcn_mfma_f32_16x16x32_bf16(af0, b0, z, 0,0,0);
        z = __builtin_amdgcn_mfma_f32_16x16x32_bf16(af1, b1, z, 0,0,0);
        cs[j] = z;
      }
#pragma unroll
      for (int j=0;j<4;j++)
#pragma unroll
        for (int r=0;r<4;r++){
          int t_loc = w*16 + quad*4 + r;
          int s_loc = j*16 + l16;
          float wgt = ((t0 + t_loc) <= (sb*64 + s_loc))
                    ? __expf(cs[j][r]*0.125f - smxB[cur*64 + s_loc])*sliB[cur*64 + s_loc] : 0.f;
          ldsS[t_loc*72 + s_loc] = __float2bfloat16(wgt);
        }
      bfrag pa0 = *(const bfrag*)(ldsS + (w*16 + l16)*72 + quad*8);
      bfrag pa1 = *(const bfrag*)(ldsS + (w*16 + l16)*72 + 32 + quad*8);
#pragma unroll
      for (int j=0;j<4;j++){
        bfrag b0 = *(const bfrag*)(Vc + (j*16 + l16)*64 + ((quad     ^ x7)*8));
        bfrag b1 = *(const bfrag*)(Vc + (j*16 + l16)*64 + (((quad+4) ^ x7)*8));
        accO[j] = __builtin_amdgcn_mfma_f32_16x16x32_bf16(pa0, b0, accO[j], 0,0,0);
        accO[j] = __builtin_amdgcn_mfma_f32_16x16x32_bf16(pa1, b1, accO[j], 0,0,0);
      }
      cur ^= 1;
    }
#pragma unroll
    for (int j=0;j<4;j++)
#pragma unroll
      for (int r=0;r<4;r++){
        int t_loc = w*16 + quad*4 + r;
        int f = j*16 + l16;
        aoH[((long)bh*S_ + t0 + t_loc)*DH_ + f] = accO[j][r];
      }
  }
}

// ---------------- binned O projection + residual: one (h,e) per block.x, W in LDS ----------------
__global__ __launch_bounds__(256)
void oproj_b(const float* __restrict__ aoH, const float* __restrict__ Wo,
             const int* __restrict__ hCnt, const int* __restrict__ hList,
             const float* __restrict__ x, float* __restrict__ x1)
{
  int he = blockIdx.x;             // h*E + e
  int h = he >> 3;
  __shared__ float Ws[DH_*DH_];    // 16 KB
  __shared__ float xsh[4][DH_];
  int tid = threadIdx.x;
  const float* W = Wo + (long)he*DH_*DH_;
  for (int i=tid; i<DH_*DH_; i+=256) Ws[i] = W[i];
  int cnt = hCnt[he];
  __syncthreads();
  int w = tid >> 6, lane = tid & 63;
  const int* lst = hList + (long)he*NTOK;
  for (int i = blockIdx.y*4 + w; i < cnt; i += 32){
    int tok = lst[i];
    int b = tok >> 10, s = tok & 1023;
    xsh[w][lane] = aoH[((long)(b*H_+h)*S_ + s)*DH_ + lane];
    float acc = 0.f;
#pragma unroll 8
    for (int f=0; f<DH_; f++) acc += xsh[w][f]*Ws[f*DH_ + lane];
    long idx = (long)tok*D_ + h*DH_ + lane;
    x1[idx] = x[idx] + acc;
  }
}

// ---------------- MoE routing: top-2, WAVE-SCAN capacity assignment (2 barriers, no LDS atomics) ----------------
__global__ __launch_bounds__(1024)
void route_kernel(const float* __restrict__ glog2, const int* __restrict__ gHist,
                  int* __restrict__ gI0, int* __restrict__ gI1,
                  int* __restrict__ gPos0, int* __restrict__ gPos1,
                  int* __restrict__ listTok, float* __restrict__ listW,
                  int* __restrict__ gCnt, float* __restrict__ auxOut)
{
  __shared__ unsigned char sI0[NTOK], sI1[NTOK];
  __shared__ float sP0[NTOK], sP1[NTOK];
  __shared__ short sPos0[NTOK], sPos1[NTOK];
  __shared__ int   waveTot[16][E_];
  __shared__ float waveImp[16][E_];
  __shared__ float sImp[E_];
  __shared__ int   sHist[NHE];
  __shared__ int   sCnt[E_];
  int tid = threadIdx.x;
  int lane = tid & 63, wv = tid >> 6;
  if (tid < NHE) sHist[tid] = gHist[tid];
  for (int i=tid; i<NTOK; i+=1024){
    const float* p = glog2 + (long)i*E_;
    float b0 = p[0]; int e0 = 0;
#pragma unroll
    for (int e=1;e<E_;e++){ float vv=p[e]; if (vv > b0){ b0=vv; e0=e; } }
    float b1v = -1e30f; int e1 = 0;
#pragma unroll
    for (int e=0;e<E_;e++){ if (e==e0) continue; float vv=p[e]; if (vv > b1v){ b1v=vv; e1=e; } }
    float ex = __expf(b1v - b0);
    float inv = 1.f/(1.f + ex);
    sI0[i] = (unsigned char)e0; sI1[i] = (unsigned char)e1;
    sP0[i] = inv; sP1[i] = ex*inv;
    gI0[i] = e0; gI1[i] = e1;
  }
  __syncthreads();
  int myCnt[E_] = {};
  unsigned char ie[4];
  int base = tid*4;
#pragma unroll
  for (int j=0;j<4;j++){
    int i = base + j;
    int tok = i >> 1;
    int e = (i & 1) ? (int)sI1[tok] : (int)sI0[tok];
    ie[j] = (unsigned char)e;
#pragma unroll
    for (int ee=0;ee<E_;ee++) myCnt[ee] += (e == ee);
  }
  int inc[E_];
#pragma unroll
  for (int e=0;e<E_;e++) inc[e] = myCnt[e];
#pragma unroll
  for (int off=1; off<64; off<<=1){
#pragma unroll
    for (int e=0;e<E_;e++){
      int v = __shfl_up(inc[e], off);
      if (lane >= off) inc[e] += v;
    }
  }
  if (lane == 63)
#pragma unroll
    for (int e=0;e<E_;e++) waveTot[wv][e] = inc[e];
  __syncthreads();
  int pref[E_];
#pragma unroll
  for (int e=0;e<E_;e++) pref[e] = inc[e] - myCnt[e];
  for (int w2=0; w2<16; w2++){
    if (w2 < wv){
#pragma unroll
      for (int e=0;e<E_;e++) pref[e] += waveTot[w2][e];
    }
  }
#pragma unroll
  for (int j=0;j<4;j++){
    int i = base + j;
    int tok = i >> 1;
    int pos = 0;
#pragma unroll
    for (int ee=0;ee<E_;ee++) if (ie[j] == ee) pos = pref[ee]++;
    short p = (pos < CAP_) ? (short)pos : (short)-1;
    if (i & 1) sPos1[tok] = p; else sPos0[tok] = p;
  }
  if (tid < E_){
    int cnt = 0;
    for (int w2=0; w2<16; w2++) cnt += waveTot[w2][tid];
    sCnt[tid] = cnt < CAP_ ? cnt : CAP_;
    gCnt[tid] = sCnt[tid];
  }
  __syncthreads();
  float impLoc[E_] = {};
  for (int i=tid; i<NTOK; i+=1024){
    int e0 = sI0[i], e1 = sI1[i];
    int p0i = sPos0[i], p1i = sPos1[i];
    float k0 = p0i >= 0 ? 1.f : 0.f, k1 = p1i >= 0 ? 1.f : 0.f;
    float p0 = sP0[i], p1 = sP1[i];
    float denom = p0*k0 + p1*k1 + 1e-9f;
    float w0 = p0*k0/denom, w1 = p1*k1/denom;
    if (p0i >= 0){
      listTok[e0*CAP_+p0i] = i; listW[e0*CAP_+p0i] = w0;
#pragma unroll
      for (int ee=0;ee<E_;ee++) impLoc[ee] += (e0 == ee) ? w0 : 0.f;
    }
    if (p1i >= 0){
      listTok[e1*CAP_+p1i] = i; listW[e1*CAP_+p1i] = w1;
#pragma unroll
      for (int ee=0;ee<E_;ee++) impLoc[ee] += (e1 == ee) ? w1 : 0.f;
    }
    gPos0[i] = p0i; gPos1[i] = p1i;
  }
#pragma unroll
  for (int off=1; off<64; off<<=1)
#pragma unroll
    for (int e=0;e<E_;e++) impLoc[e] += __shfl_xor(impLoc[e], off);
  if (lane == 0)
#pragma unroll
    for (int e=0;e<E_;e++) waveImp[wv][e] = impLoc[e];
  __syncthreads();
  if (tid < E_){
    float s = 0.f;
    for (int w2=0; w2<16; w2++) s += waveImp[w2][tid];
    sImp[tid] = s;
  }
  __syncthreads();
  if (tid == 0){
    float tot = 0.f;
    for (int i=0;i<NHE;i++) tot += (float)sHist[i]*(1.0f/NTOK)*0.01f;
    float a1 = 0.f;
    for (int i=0;i<NHE;i++){
      float p = ((float)sHist[i]*(1.0f/NTOK)*0.01f)/(tot + 1e-9f);
      a1 += p*p;
    }
    a1 *= (float)(H_*E_);
    float tcs = 0.f, ims = 0.f;
    for (int e=0;e<E_;e++){ tcs += (float)sCnt[e]; ims += sImp[e]; }
    float a2 = 0.f;
    for (int e=0;e<E_;e++) a2 += ((float)sCnt[e]/tcs)*(sImp[e]/ims);
    a2 *= (float)E_;
    auxOut[0] = a1 + a2;
  }
}

// ---------------- final combine: out = x1 + expert contributions (2 split-K slices, fp32) ----------------
__global__ __launch_bounds__(256)
void combine_kernel(const float* __restrict__ x1,
                    const float* __restrict__ Ya, const float* __restrict__ Yb,
                    const int* __restrict__ gI0, const int* __restrict__ gI1,
                    const int* __restrict__ gPos0, const int* __restrict__ gPos1,
                    float* __restrict__ out)
{
  int i = blockIdx.x;
  int tid = threadIdx.x;
  int p0 = gPos0[i], p1 = gPos1[i];
  int e0 = gI0[i],  e1 = gI1[i];
  long off0 = (long)(e0*CAPP_ + (p0 >= 0 ? p0 : 0))*D_;
  long off1 = (long)(e1*CAPP_ + (p1 >= 0 ? p1 : 0))*D_;
  const float* y0a = Ya + off0; const float* y0b = Yb + off0;
  const float* y1a = Ya + off1; const float* y1b = Yb + off1;
  for (int d=tid; d<D_; d+=256){
    float v = x1[(long)i*D_+d];
    if (p0 >= 0) v += y0a[d] + y0b[d];
    if (p1 >= 0) v += y1a[d] + y1b[d];
    out[(long)i*D_+d] = v;
  }
}

extern "C" void kernel_launch(void* const* d_in, const int* in_sizes, int n_in,
                              void* d_out, int out_size, void* d_ws, size_t ws_size,
                              hipStream_t stream)
{
  const float* x    = (const float*)d_in[0];
  const float* W_q  = (const float*)d_in[2];
  const float* W_k  = (const float*)d_in[3];
  const float* W_v  = (const float*)d_in[4];
  const float* W_o  = (const float*)d_in[5];
  const float* W_r  = (const float*)d_in[6];
  const float* g1   = (const float*)d_in[7];
  const float* b1   = (const float*)d_in[8];
  const float* g2   = (const float*)d_in[9];
  const float* b2   = (const float*)d_in[10];
  const float* gate = (const float*)d_in[11];
  const float* W1   = (const float*)d_in[12];
  const float* W2   = (const float*)d_in[13];
  float* out = (float*)d_out;

  float* wsf = (float*)d_ws;
  // ---- workspace layout (float slots) ----
  const long oX1   = 0;          // 1,572,864
  const long oLnF  = 1572864;    // fp32 2048x768; live through gemm_ffn1, then reused as split-K slice 1
  const long oLnB  = 3145728;    // bf16 2048x768
  const long oWcat = 3932160;    // bf16 1536x768 (ends 4521984)
  const long oWrT  = 4521984;    // fp32 96x768 = 73,728 (ends 4595712)
  const long oHist = 4595712;    // int 96 (attention (h,e) histogram)
  const long oHCnt = 4595808;    // int 96 ((h,e) bin counters) - adjacent: one memset covers both
  const long oGM   = 4718592;    // 24,576
  const long oGL   = 4743168;    // 24,576
  const long oEidx = 4767744;    // int 24,576
  const long oGlg2 = 4792320;    // 16,384
  const long oI0   = 4808704;
  const long oI1   = 4810752;
  const long oP0   = 4812800;
  const long oP1   = 4814848;
  const long oLT   = 4816896;
  const long oLW   = 4819456;
  const long oCnt  = 4822016;    // 8 ints
  const long SB    = 4822528;    // shared overlay region
  // attention view: qkB bf16 @SB (1.57M) | vT bf16 @+1,572,864 | aoH fp32 @+2,359,296 |
  //                 hList int @+3,932,160 (96*2048)
  // FFN view:       Hid @+7,471,104 | Yexp fp32 @+10,616,832
  const long oWT1  = SB + 12976128;      // bf16 8 x 2048x768 (6,291,456 fl)
  const long oWT2  = oWT1 + 6291456;     // bf16 8 x 768x2048 (6,291,456 fl)
  const long TOTAL = oWT2 + 6291456;     // 30,381,568 floats = 121.5 MB
  if (ws_size < (size_t)TOTAL*4) return;

  float* x1    = wsf + oX1;
  float* lnbF  = wsf + oLnF;
  bf16*  lnbB  = (bf16*)(wsf + oLnB);
  bf16*  WcatB = (bf16*)(wsf + oWcat);
  float* WrT   = wsf + oWrT;
  int*   gHist = (int*)(wsf + oHist);
  int*   hCnt  = (int*)(wsf + oHCnt);
  float* gM    = wsf + oGM;
  float* gL    = wsf + oGL;
  int*   eidx  = (int*)(wsf + oEidx);
  float* glog2 = wsf + oGlg2;
  int*   gI0   = (int*)(wsf + oI0);
  int*   gI1   = (int*)(wsf + oI1);
  int*   gPos0 = (int*)(wsf + oP0);
  int*   gPos1 = (int*)(wsf + oP1);
  int*   lTok  = (int*)(wsf + oLT);
  float* lW    = wsf + oLW;
  int*   gCnt  = (int*)(wsf + oCnt);
  bf16*  qkB   = (bf16*)(wsf + SB);
  bf16*  vT    = (bf16*)(wsf + SB + 1572864);
  float* aoH   = wsf + SB + 2359296;
  int*   hList = (int*)(wsf + SB + 3932160);
  bf16*  Hid   = (bf16*)(wsf + SB + 7471104);
  float* Yexp  = wsf + SB + 10616832;
  float* YexpB = wsf + oLnF;     // split-K slice 1: lnF region, dead once gemm_ffn1 completes
  bf16*  WT1   = (bf16*)(wsf + oWT1);
  bf16*  WT2   = (bf16*)(wsf + oWT2);

  // ---- counter zero + immediate-needs weight prep ----
  (void)hipMemsetAsync(gHist, 0, 2*NHE*sizeof(int), stream);
  transp_qkr<<<180,256,0,stream>>>(W_q, W_k, W_r, WcatB, WrT);

  // ---- attention phase ----
  ln_kernel<<<NTOK,256,0,stream>>>(x, g1, b1, lnbF, lnbB, nullptr, nullptr);
  // z=0: QK GEMM (384 blocks); z=1,2: 512 hosted router blocks (independent of the gemm)
  gemm_qk<<<dim3(24,16,3),256,0,stream>>>(lnbB, WcatB, qkB, lnbF, WrT, eidx, gHist, hCnt, hList);
  // z 0..1 = attention; z 2..17 = hosted W1 transposes; z 18..25 = hosted vsel bins
  attn_stats_mfma<<<dim3(S_/128,H_,26),256,0,stream>>>(qkB, gM, gL, W1, WT1, lnbF, W_v, hCnt, hList, vT);
  // z 0..1 = attention; z 2..17 = hosted W2 transposes
  attn_pv<<<dim3(S_/128,H_,18),256,0,stream>>>(qkB, vT, gM, gL, aoH, W2, WT2);
  oproj_b<<<dim3(NHE,8,1),256,0,stream>>>(aoH, W_o, hCnt, hList, x, x1);

  // ---- FFN phase ----
  ln_kernel<<<NTOK,256,0,stream>>>(x1, g2, b2, lnbF, nullptr, gate, glog2);  // fused gate logits
  route_kernel<<<1,1024,0,stream>>>(glog2, gHist, gI0,gI1,gPos0,gPos1, lTok,lW,gCnt, out + (size_t)NTOK*D_);
  gemm_ffn1<<<dim3(32,3,8),256,0,stream>>>(lnbF, WT1, Hid, lTok, lW, gCnt);
  gemm_bn64<<<dim3(12,3,16),256,0,stream>>>(Hid, WT2, Yexp, YexpB, CAPP_, 768, 2048,
                                            (long)CAPP_*2048, (long)768*2048, (long)CAPP_*768, 0, 0, 2);
  combine_kernel<<<NTOK,256,0,stream>>>(x1, Yexp, YexpB, gI0,gI1,gPos0,gPos1, out);
}